// Round 11
// baseline (915.492 us; speedup 1.0000x reference)
//
#include <hip/hip_runtime.h>
#include <hip/hip_bf16.h>

// ---------------- types / helpers ----------------
typedef __attribute__((ext_vector_type(8))) short   vshort8;   // 8 x bf16 bits (4 VGPRs)
typedef __attribute__((ext_vector_type(8))) unsigned short vushort8;
typedef __attribute__((ext_vector_type(4))) float   vfloat4;
typedef __attribute__((ext_vector_type(2))) float   vfloat2;

__device__ __forceinline__ float bf2f(unsigned short h) {
    union { unsigned u; float f; } x; x.u = ((unsigned)h) << 16; return x.f;
}
__device__ __forceinline__ unsigned short f2bf(float f) {
    union { float f; unsigned u; } x; x.f = f;
    unsigned r = x.u + 0x7fffu + ((x.u >> 16) & 1u);
    return (unsigned short)(r >> 16);
}
__device__ __forceinline__ void cp16_async(const void* g, void* l) {
    __builtin_amdgcn_global_load_lds(
        (const __attribute__((address_space(1))) unsigned int*)g,
        (__attribute__((address_space(3))) unsigned int*)l, 16, 0, 0);
}

// ---------------- constants ----------------
#define Bc 4
#define Tc 2048
#define Dc 2048
#define Hc 32
#define KHc 64
#define BTc (Bc*Tc)              // 8192
#define BTDc ((size_t)BTc*Dc)    // 16,777,216
#define LP 72                    // LDS row stride (shorts) for scan kernels

struct EpiP {
    float* of;                 // f32 out
    unsigned short* ob;        // bf16 out
    const float* a0;           // aux f32 (decay)
    const float* a1;           // aux f32 (unused)
    const unsigned short* ab;  // aux bf16 (v2 partial)
    const float* vec;          // per-col vector (time_decay)
};

template<int EPI>
__device__ __forceinline__ void epi_store(float a, int row, int col, int N, const EpiP& ep)
{
    size_t o = (size_t)row * N + col;
    if (EPI == 0) {
        ep.of[o] = a;
    } else if (EPI == 1) {
        ep.ob[o] = f2bf(a);
    } else if (EPI == 2) {
        ep.ob[o] = f2bf(tanhf(a));
    } else if (EPI == 4) {                // KD: acc * (1 - decay)
        ep.ob[o] = f2bf(a * (1.f - ep.a0[o]));
    } else if (EPI == 5) {                // DECAY: exp(-exp(vec[col]+acc)) f32
        ep.of[o] = expf(-expf(ep.vec[col] + a));
    } else if (EPI == 6) {                // ADDB: acc + bf16 aux -> bf16
        ep.ob[o] = f2bf(a + bf2f(ep.ab[o]));
    }
}

// ============ GEMM-128 (m97-style, fully-drained), used for odd shapes (N=160/64) ============
template<int EPI>
__global__ __launch_bounds__(256) void gemm_bt(
    const unsigned short* __restrict__ A, int lda,
    const unsigned short* __restrict__ BT, int ldbt,
    int M, int N, int K, EpiP ep)
{
    __shared__ unsigned short lA[128 * 32];
    __shared__ unsigned short lB[128 * 32];
    const int tid  = threadIdx.x;
    const int lane = tid & 63;
    const int w    = tid >> 6;
    const int mt   = blockIdx.y, nt = blockIdx.x;
    const int wm = (w >> 1) * 64, wn = (w & 1) * 64;
    const int frow = lane & 15, fk = (lane >> 4) * 8;

    vfloat4 acc[4][4];
#pragma unroll
    for (int i = 0; i < 4; i++)
#pragma unroll
        for (int j = 0; j < 4; j++) acc[i][j] = vfloat4{0.f, 0.f, 0.f, 0.f};

    for (int k0 = 0; k0 < K; k0 += 32) {
        __syncthreads();
#pragma unroll
        for (int p = 0; p < 2; p++) {
            int idx = p * 256 + tid;
            int row = idx >> 2, colh = (idx & 3) * 8;
            cp16_async(A + (size_t)(mt * 128 + row) * lda + k0 + colh, &lA[idx * 8]);
        }
#pragma unroll
        for (int p = 0; p < 2; p++) {
            int idx = p * 256 + tid;
            int row = idx >> 2, colh = (idx & 3) * 8;
            cp16_async(BT + (size_t)(nt * 128 + row) * ldbt + k0 + colh, &lB[idx * 8]);
        }
        __syncthreads();

        vshort8 af[4], bfr[4];
#pragma unroll
        for (int m = 0; m < 4; m++) af[m]  = *(const vshort8*)&lA[(wm + m * 16 + frow) * 32 + fk];
#pragma unroll
        for (int n = 0; n < 4; n++) bfr[n] = *(const vshort8*)&lB[(wn + n * 16 + frow) * 32 + fk];
#pragma unroll
        for (int m = 0; m < 4; m++)
#pragma unroll
            for (int n = 0; n < 4; n++)
                acc[m][n] = __builtin_amdgcn_mfma_f32_16x16x32_bf16(af[m], bfr[n], acc[m][n], 0, 0, 0);
    }

    const int crow0 = mt * 128 + wm, ccol0 = nt * 128 + wn;
#pragma unroll
    for (int m = 0; m < 4; m++)
#pragma unroll
        for (int n = 0; n < 4; n++) {
            int col = ccol0 + n * 16 + (lane & 15);
            if (col >= N) continue;
#pragma unroll
            for (int q = 0; q < 4; q++) {
                int row = crow0 + m * 16 + (lane >> 4) * 4 + q;
                epi_store<EPI>(acc[m][n][q], row, col, N, ep);
            }
        }
}

// ============ GEMM-128t: 128x128, BK=32, triple-buffer, counted vmcnt, 3 blocks/CU ============
// Same ledger as gemm256s (4 loads/thread/stage, vmcnt(4) retires previous stage);
// 48 KB LDS -> 3 blocks/CU so barrier stalls hide under co-resident blocks (m114).
// Swizzle: physical 16B slot = logical ^ ((row>>1)&3) -> uniform 2-way (free).
template<int EPI>
__global__ __launch_bounds__(256) void gemm128t(
    const unsigned short* __restrict__ A, int lda,
    const unsigned short* __restrict__ BT, int ldbt,
    int M, int N, int K, EpiP ep)
{
    __shared__ unsigned short sh[3 * 8192];   // 3 bufs x (A 4096 + B 4096 shorts) = 48 KB
    const int tid  = threadIdx.x;
    const int lane = tid & 63;
    const int w    = tid >> 6;

    // XCD-aware bijective block swizzle (nwg % 8 == 0 for our shapes)
    int bid = blockIdx.y * gridDim.x + blockIdx.x;
    {
        int nwg = gridDim.x * gridDim.y;
        if ((nwg & 7) == 0) bid = (bid & 7) * (nwg >> 3) + (bid >> 3);
    }
    const int mt = bid / gridDim.x, nt = bid % gridDim.x;

    const int wm = (w >> 1) * 64, wn = (w & 1) * 64;
    const int frow = lane & 15;
    const int cswz = ((lane >> 4) ^ ((frow >> 1) & 3)) * 8;
    const int arow0 = mt * 128, brow0 = nt * 128;

    vfloat4 acc[4][4];
#pragma unroll
    for (int i = 0; i < 4; i++)
#pragma unroll
        for (int j = 0; j < 4; j++) acc[i][j] = vfloat4{0.f, 0.f, 0.f, 0.f};

    const int NT = K >> 5;

    auto stage = [&](int kt, int sbuf) {   // 4 loads/thread: 2 A + 2 B
        int k0 = kt << 5;
        unsigned short* dst = &sh[sbuf * 8192];
#pragma unroll
        for (int i = 0; i < 2; i++) {
            int idx = i * 256 + tid;
            int row = idx >> 2;
            int ch  = (idx & 3) ^ ((row >> 1) & 3);
            cp16_async(A + (size_t)(arow0 + row) * lda + k0 + ch * 8, dst + idx * 8);
        }
#pragma unroll
        for (int i = 0; i < 2; i++) {
            int idx = i * 256 + tid;
            int row = idx >> 2;
            int ch  = (idx & 3) ^ ((row >> 1) & 3);
            cp16_async(BT + (size_t)(brow0 + row) * ldbt + k0 + ch * 8, dst + 4096 + idx * 8);
        }
    };

    stage(0, 0);
    if (NT > 1) {
        stage(1, 1);
        asm volatile("s_waitcnt vmcnt(4)" ::: "memory");
    } else {
        asm volatile("s_waitcnt vmcnt(0)" ::: "memory");
    }
    __builtin_amdgcn_s_barrier();

    int buf = 0, sb = 2;
    for (int kt = 0; kt < NT; kt++) {
        if (kt + 2 < NT) stage(kt + 2, sb);
        const unsigned short* Ab = &sh[buf * 8192];
        const unsigned short* Bb = Ab + 4096;

        vshort8 af[4], bfr[4];
#pragma unroll
        for (int m = 0; m < 4; m++)
            af[m] = *(const vshort8*)&Ab[(wm + m * 16 + frow) * 32 + cswz];
#pragma unroll
        for (int n = 0; n < 4; n++)
            bfr[n] = *(const vshort8*)&Bb[(wn + n * 16 + frow) * 32 + cswz];

        __builtin_amdgcn_s_setprio(1);
#pragma unroll
        for (int m = 0; m < 4; m++)
#pragma unroll
            for (int n = 0; n < 4; n++)
                acc[m][n] = __builtin_amdgcn_mfma_f32_16x16x32_bf16(af[m], bfr[n], acc[m][n], 0, 0, 0);
        __builtin_amdgcn_s_setprio(0);

        if (kt + 1 < NT) {
            if (kt + 2 < NT) asm volatile("s_waitcnt vmcnt(4)" ::: "memory");
            else             asm volatile("s_waitcnt vmcnt(0)" ::: "memory");
            asm volatile("s_waitcnt lgkmcnt(0)" ::: "memory");
            __builtin_amdgcn_s_barrier();
        }
        buf = (buf == 2) ? 0 : buf + 1;
        sb  = (sb  == 2) ? 0 : sb  + 1;
    }

    const int crow0 = arow0 + wm, ccol0 = brow0 + wn;
#pragma unroll
    for (int m = 0; m < 4; m++)
#pragma unroll
        for (int n = 0; n < 4; n++) {
            int col = ccol0 + n * 16 + (lane & 15);
#pragma unroll
            for (int q = 0; q < 4; q++) {
                int row = crow0 + m * 16 + (lane >> 4) * 4 + q;
                epi_store<EPI>(acc[m][n][q], row, col, N, ep);
            }
        }
}

// ============ GEMM-256s: 256x256, BK=32, triple-buffer (for small K: 32/64) ============
template<int EPI>
__global__ __launch_bounds__(512, 1) void gemm256s(
    const unsigned short* __restrict__ A, int lda,
    const unsigned short* __restrict__ BT, int ldbt,
    int M, int N, int K, EpiP ep)
{
    __shared__ unsigned short sh[3 * 16384];   // 96 KB
    const int tid  = threadIdx.x;
    const int lane = tid & 63;
    const int w    = tid >> 6;

    int bid = blockIdx.y * gridDim.x + blockIdx.x;
    {
        int nwg = gridDim.x * gridDim.y;
        if ((nwg & 7) == 0) bid = (bid & 7) * (nwg >> 3) + (bid >> 3);
    }
    const int mt = bid / gridDim.x, nt = bid % gridDim.x;

    const int wm = (w >> 2) * 128, wn = (w & 3) * 64;
    const int frow = lane & 15;
    const int cswz = ((lane >> 4) ^ ((frow >> 1) & 3)) * 8;
    const int arow0 = mt * 256, brow0 = nt * 256;

    vfloat4 acc[8][4];
#pragma unroll
    for (int i = 0; i < 8; i++)
#pragma unroll
        for (int j = 0; j < 4; j++) acc[i][j] = vfloat4{0.f, 0.f, 0.f, 0.f};

    const int NT = K >> 5;

    auto stage = [&](int kt, int sbuf) {
        int k0 = kt << 5;
        unsigned short* dst = &sh[sbuf * 16384];
#pragma unroll
        for (int i = 0; i < 2; i++) {
            int idx = i * 512 + tid;
            int row = idx >> 2;
            int ch  = (idx & 3) ^ ((row >> 1) & 3);
            cp16_async(A + (size_t)(arow0 + row) * lda + k0 + ch * 8, dst + idx * 8);
        }
#pragma unroll
        for (int i = 0; i < 2; i++) {
            int idx = i * 512 + tid;
            int row = idx >> 2;
            int ch  = (idx & 3) ^ ((row >> 1) & 3);
            cp16_async(BT + (size_t)(brow0 + row) * ldbt + k0 + ch * 8, dst + 8192 + idx * 8);
        }
    };

    stage(0, 0);
    if (NT > 1) {
        stage(1, 1);
        asm volatile("s_waitcnt vmcnt(4)" ::: "memory");
    } else {
        asm volatile("s_waitcnt vmcnt(0)" ::: "memory");
    }
    __builtin_amdgcn_s_barrier();

    int buf = 0, sb = 2;
    for (int kt = 0; kt < NT; kt++) {
        if (kt + 2 < NT) stage(kt + 2, sb);
        const unsigned short* Ab = &sh[buf * 16384];
        const unsigned short* Bb = Ab + 8192;

        vshort8 af[8], bfv[4];
#pragma unroll
        for (int m = 0; m < 8; m++)
            af[m] = *(const vshort8*)&Ab[(wm + m * 16 + frow) * 32 + cswz];
#pragma unroll
        for (int n = 0; n < 4; n++)
            bfv[n] = *(const vshort8*)&Bb[(wn + n * 16 + frow) * 32 + cswz];

        __builtin_amdgcn_s_setprio(1);
#pragma unroll
        for (int m = 0; m < 8; m++)
#pragma unroll
            for (int n = 0; n < 4; n++)
                acc[m][n] = __builtin_amdgcn_mfma_f32_16x16x32_bf16(af[m], bfv[n], acc[m][n], 0, 0, 0);
        __builtin_amdgcn_s_setprio(0);

        if (kt + 1 < NT) {
            if (kt + 2 < NT) asm volatile("s_waitcnt vmcnt(4)" ::: "memory");
            else             asm volatile("s_waitcnt vmcnt(0)" ::: "memory");
            asm volatile("s_waitcnt lgkmcnt(0)" ::: "memory");
            __builtin_amdgcn_s_barrier();
        }
        buf = (buf == 2) ? 0 : buf + 1;
        sb  = (sb  == 2) ? 0 : sb  + 1;
    }

    const int crow0 = arow0 + wm, ccol0 = brow0 + wn;
#pragma unroll
    for (int m = 0; m < 8; m++)
#pragma unroll
        for (int n = 0; n < 4; n++) {
            int col = ccol0 + n * 16 + (lane & 15);
#pragma unroll
            for (int q = 0; q < 4; q++) {
                int row = crow0 + m * 16 + (lane >> 4) * 4 + q;
                epi_store<EPI>(acc[m][n][q], row, col, N, ep);
            }
        }
}

// ============ mix5: fused five mix GEMMs (K=32), x/DX read once ============
struct Mix5P {
    const float* vec[5];
    unsigned short* out[5];
};

__global__ __launch_bounds__(256) void mix5(
    const unsigned short* __restrict__ MP,   // MIXPRE [BTc][160]
    const unsigned short* __restrict__ W2T,  // [Dc][160]
    const float* __restrict__ x,
    const unsigned short* __restrict__ DXb,
    Mix5P p)
{
    __shared__ unsigned short lA[64 * 32];    // 4 KB
    __shared__ unsigned short lB[128 * 32];   // 8 KB
    const int tid = threadIdx.x, lane = tid & 63, w = tid >> 6;
    const int mt = blockIdx.y, nt = blockIdx.x;   // grid (16, 128)
    const int wm = (w >> 1) * 32, wn = (w & 1) * 64;
    const int frow = lane & 15, fk = (lane >> 4) * 8;
    const int row0 = mt * 64, col0 = nt * 128;

    float xr[8][4], dxr[8][4];
#pragma unroll
    for (int mi = 0; mi < 2; mi++)
#pragma unroll
        for (int q = 0; q < 4; q++) {
            int rl = wm + mi * 16 + (lane >> 4) * 4 + q;
            size_t rb = (size_t)(row0 + rl) * Dc + col0;
#pragma unroll
            for (int ni = 0; ni < 4; ni++) {
                int cl = wn + ni * 16 + (lane & 15);
                xr[mi * 4 + q][ni]  = x[rb + cl];
                dxr[mi * 4 + q][ni] = bf2f(DXb[rb + cl]);
            }
        }

    for (int f = 0; f < 5; f++) {
        __syncthreads();
        {
            int row = tid >> 2, ch = tid & 3;
            cp16_async(MP + (size_t)(row0 + row) * 160 + f * 32 + ch * 8, &lA[(row * 4 + ch) * 8]);
        }
#pragma unroll
        for (int p2 = 0; p2 < 2; p2++) {
            int idx = p2 * 256 + tid;
            int row = idx >> 2, ch = idx & 3;
            cp16_async(W2T + (size_t)(col0 + row) * 160 + f * 32 + ch * 8, &lB[(row * 4 + ch) * 8]);
        }
        __syncthreads();

        vshort8 af[2], bfr[4];
#pragma unroll
        for (int mi = 0; mi < 2; mi++) af[mi]  = *(const vshort8*)&lA[(wm + mi * 16 + frow) * 32 + fk];
#pragma unroll
        for (int ni = 0; ni < 4; ni++) bfr[ni] = *(const vshort8*)&lB[(wn + ni * 16 + frow) * 32 + fk];

        vfloat4 acc[2][4];
#pragma unroll
        for (int mi = 0; mi < 2; mi++)
#pragma unroll
            for (int ni = 0; ni < 4; ni++) {
                acc[mi][ni] = vfloat4{0.f, 0.f, 0.f, 0.f};
                acc[mi][ni] = __builtin_amdgcn_mfma_f32_16x16x32_bf16(af[mi], bfr[ni], acc[mi][ni], 0, 0, 0);
            }

        const float* vec = p.vec[f];
        unsigned short* ob = p.out[f];
        float vc[4];
#pragma unroll
        for (int ni = 0; ni < 4; ni++) vc[ni] = vec[col0 + wn + ni * 16 + (lane & 15)];
#pragma unroll
        for (int mi = 0; mi < 2; mi++)
#pragma unroll
            for (int q = 0; q < 4; q++) {
                int rl = wm + mi * 16 + (lane >> 4) * 4 + q;
                size_t rb = (size_t)(row0 + rl) * Dc + col0;
#pragma unroll
                for (int ni = 0; ni < 4; ni++) {
                    int cl = wn + ni * 16 + (lane & 15);
                    ob[rb + cl] = f2bf(xr[mi * 4 + q][ni] + dxr[mi * 4 + q][ni] * (vc[ni] + acc[mi][ni][q]));
                }
            }
    }
}

// ---------------- prep: xxx = x + dx*time_maa_x, dx = xprev - x  -> bf16 ----------------
__global__ __launch_bounds__(256) void prep_xxx(
    const float* __restrict__ x, const float* __restrict__ shift_in,
    const float* __restrict__ tmx, unsigned short* __restrict__ xxx,
    unsigned short* __restrict__ dxb)
{
    int row = blockIdx.x, tid = threadIdx.x;
    int t = row & (Tc - 1), b = row >> 11;
    size_t base = (size_t)row * Dc + tid * 8;
    const float* xp = t ? x + base - Dc : shift_in + (size_t)b * Dc + tid * 8;
    vushort8 o, dxo;
#pragma unroll
    for (int j = 0; j < 8; j++) {
        float xv = x[base + j];
        float dx = xp[j] - xv;
        o[j]   = f2bf(xv + dx * tmx[tid * 8 + j]);
        dxo[j] = f2bf(dx);
    }
    *(vushort8*)(xxx + base) = o;
    *(vushort8*)(dxb + base) = dxo;
}

__global__ __launch_bounds__(256) void shift_copy(const float* __restrict__ x, float* __restrict__ out)
{
    int i = blockIdx.x * 256 + threadIdx.x;   // B*D = 8192
    int b = i >> 11, d = i & (Dc - 1);
    out[i] = x[((size_t)b * Tc + (Tc - 1)) * Dc + d];
}

// ---------------- transpose + cast f32 -> bf16 : out[C][R] = in[R][C] ----------------
__global__ __launch_bounds__(256) void transpose_cast(
    const float* __restrict__ in, unsigned short* __restrict__ out, int R, int C)
{
    __shared__ float tile[32][33];
    int ct = blockIdx.x, rt = blockIdx.y;
    int lx = threadIdx.x & 31, ly = threadIdx.x >> 5;
#pragma unroll
    for (int i = 0; i < 4; i++)
        tile[ly + i * 8][lx] = in[(size_t)(rt * 32 + ly + i * 8) * C + ct * 32 + lx];
    __syncthreads();
#pragma unroll
    for (int i = 0; i < 4; i++)
        out[(size_t)(ct * 32 + ly + i * 8) * R + rt * 32 + lx] = f2bf(tile[lx][ly + i * 8]);
}

// =========== WKV chunked scan as chunked linear attention (MFMA) ===========
__global__ __launch_bounds__(256) void wkv_summary(
    const unsigned short* __restrict__ kd, const unsigned short* __restrict__ vv,
    const float* __restrict__ dec, float* __restrict__ P, float* __restrict__ aL)
{
    __shared__ unsigned short kb2T[64][LP];
    __shared__ unsigned short vT[64][LP];
    __shared__ float gp[4][64];
    const int blk = blockIdx.x;
    const int c = blk & 31, bh = blk >> 5, b = bh >> 5, h = bh & 31;
    const int tid = threadIdx.x;
    const size_t rowbase = ((size_t)(b * Tc + c * 64)) * Dc + h * 64;

    {
        int t = tid >> 2, q = tid & 3;
        const unsigned short* src = vv + rowbase + (size_t)t * Dc + q * 16;
        vushort8 a = *(const vushort8*)src;
        vushort8 b2 = *(const vushort8*)(src + 8);
#pragma unroll
        for (int j = 0; j < 8; j++) vT[q * 16 + j][t] = a[j];
#pragma unroll
        for (int j = 0; j < 8; j++) vT[q * 16 + 8 + j][t] = b2[j];
    }

    const int k = tid & 63, grp = tid >> 6;
    const float* decp = dec + rowbase + k;
    const unsigned short* kp = kd + rowbase + k;
    float suf_local[16];
    float pgrp = 1.f;
#pragma unroll
    for (int i = 15; i >= 0; i--) {
        int t = grp * 16 + i;
        float d = decp[(size_t)t * Dc];
        suf_local[i] = pgrp;
        pgrp *= d;
    }
    gp[grp][k] = pgrp;
    __syncthreads();
    float suff = 1.f;
#pragma unroll
    for (int g2 = 0; g2 < 4; g2++) if (g2 > grp) suff *= gp[g2][k];
    if (grp == 0) aL[(size_t)blk * 64 + k] = pgrp * suff;
    {
        vushort8 p0, p1;
#pragma unroll
        for (int i = 0; i < 8; i++) {
            int t = grp * 16 + i;
            p0[i] = f2bf(bf2f(kp[(size_t)t * Dc]) * (suf_local[i] * suff));
        }
#pragma unroll
        for (int i = 0; i < 8; i++) {
            int t = grp * 16 + 8 + i;
            p1[i] = f2bf(bf2f(kp[(size_t)t * Dc]) * (suf_local[8 + i] * suff));
        }
        *(vushort8*)&kb2T[k][grp * 16] = p0;
        *(vushort8*)&kb2T[k][grp * 16 + 8] = p1;
    }
    __syncthreads();

    const int lane = tid & 63, w = tid >> 6;
    const int wm = (w >> 1) * 32, wn = (w & 1) * 32;
    const int frow = lane & 15, fk = (lane >> 4) * 8;
    vfloat4 acc[2][2];
#pragma unroll
    for (int m = 0; m < 2; m++)
#pragma unroll
        for (int n = 0; n < 2; n++) acc[m][n] = vfloat4{0.f, 0.f, 0.f, 0.f};
#pragma unroll
    for (int kk = 0; kk < 2; kk++) {
        vshort8 af[2], bfr[2];
#pragma unroll
        for (int m = 0; m < 2; m++) af[m]  = *(const vshort8*)&kb2T[wm + m * 16 + frow][kk * 32 + fk];
#pragma unroll
        for (int n = 0; n < 2; n++) bfr[n] = *(const vshort8*)&vT[wn + n * 16 + frow][kk * 32 + fk];
#pragma unroll
        for (int m = 0; m < 2; m++)
#pragma unroll
            for (int n = 0; n < 2; n++)
                acc[m][n] = __builtin_amdgcn_mfma_f32_16x16x32_bf16(af[m], bfr[n], acc[m][n], 0, 0, 0);
    }
    float* Pp = P + (size_t)blk * 4096;
#pragma unroll
    for (int m = 0; m < 2; m++)
#pragma unroll
        for (int n = 0; n < 2; n++) {
            int col = wn + n * 16 + (lane & 15);
#pragma unroll
            for (int q = 0; q < 4; q++) {
                int row = wm + m * 16 + (lane >> 4) * 4 + q;
                Pp[row * 64 + col] = acc[m][n][q];
            }
        }
}

__global__ __launch_bounds__(256) void wkv_states(
    const float* __restrict__ wkv_in, float* __restrict__ P /* -> Sb */,
    const float* __restrict__ aL, float* __restrict__ wkv_out)
{
    int idx = blockIdx.x * 256 + threadIdx.x;   // 524288
    int bh = idx >> 12, kv = idx & 4095, k = kv >> 6;
    float S = wkv_in[idx];
    for (int c = 0; c < 32; c++) {
        size_t off = (size_t)bh * 32 + c;
        float p = P[off * 4096 + kv];
        float a = aL[off * 64 + k];
        P[off * 4096 + kv] = S;   // Sb[c]
        S = S * a + p;
    }
    wkv_out[idx] = S;
}

__global__ __launch_bounds__(256) void wkv_y(
    const unsigned short* __restrict__ rr, const unsigned short* __restrict__ kd,
    const unsigned short* __restrict__ vv, const float* __restrict__ dec,
    const float* __restrict__ Sb, unsigned short* __restrict__ ya)
{
    __shared__ unsigned short rA[64][LP];
    __shared__ unsigned short kbL[64][LP];
    __shared__ unsigned short vT[64][LP];
    __shared__ unsigned short SbT[64][LP];
    __shared__ unsigned short QiM[64][LP];
    __shared__ float gp[4][64];
    const int blk = blockIdx.x;
    const int c = blk & 31, bh = blk >> 5, b = bh >> 5, h = bh & 31;
    const int tid = threadIdx.x;
    const size_t rowbase = ((size_t)(b * Tc + c * 64)) * Dc + h * 64;

    {
        int t = tid >> 2, q = tid & 3;
        const unsigned short* src = vv + rowbase + (size_t)t * Dc + q * 16;
        vushort8 a = *(const vushort8*)src;
        vushort8 b2 = *(const vushort8*)(src + 8);
#pragma unroll
        for (int j = 0; j < 8; j++) vT[q * 16 + j][t] = a[j];
#pragma unroll
        for (int j = 0; j < 8; j++) vT[q * 16 + 8 + j][t] = b2[j];
        const float* sp = Sb + (size_t)blk * 4096 + t * 64 + q * 16;
#pragma unroll
        for (int j = 0; j < 16; j++) SbT[q * 16 + j][t] = f2bf(sp[j]);
    }

    const int k = tid & 63, grp = tid >> 6;
    const float* decp = dec + rowbase + k;
    const unsigned short* rp = rr + rowbase + k;
    const unsigned short* kp = kd + rowbase + k;
    float pref_local[16];
    float pgrp = 1.f;
#pragma unroll
    for (int i = 0; i < 16; i++) {
        int t = grp * 16 + i;
        float d = decp[(size_t)t * Dc];
        pref_local[i] = pgrp;
        pgrp *= d;
    }
    gp[grp][k] = pgrp;
    __syncthreads();
    float pref = 1.f;
#pragma unroll
    for (int g2 = 0; g2 < 4; g2++) if (g2 < grp) pref *= gp[g2][k];
#pragma unroll
    for (int i = 0; i < 16; i++) {
        int t = grp * 16 + i;
        float Aex  = pref * pref_local[i];
        float Ainc = pref * (i < 15 ? pref_local[i + 1] : pgrp);
        rA[t][k]  = f2bf(bf2f(rp[(size_t)t * Dc]) * Aex);
        kbL[t][k] = f2bf(bf2f(kp[(size_t)t * Dc]) / Ainc);
    }
    __syncthreads();

    const int lane = tid & 63, w = tid >> 6;
    const int wm = (w >> 1) * 32, wn = (w & 1) * 32;
    const int frow = lane & 15, fk = (lane >> 4) * 8;

    vfloat4 acc[2][2];
#pragma unroll
    for (int m = 0; m < 2; m++)
#pragma unroll
        for (int n = 0; n < 2; n++) acc[m][n] = vfloat4{0.f, 0.f, 0.f, 0.f};
#pragma unroll
    for (int kk = 0; kk < 2; kk++) {
        vshort8 af[2], bfr[2];
#pragma unroll
        for (int m = 0; m < 2; m++) af[m]  = *(const vshort8*)&rA[wm + m * 16 + frow][kk * 32 + fk];
#pragma unroll
        for (int n = 0; n < 2; n++) bfr[n] = *(const vshort8*)&kbL[wn + n * 16 + frow][kk * 32 + fk];
#pragma unroll
        for (int m = 0; m < 2; m++)
#pragma unroll
            for (int n = 0; n < 2; n++)
                acc[m][n] = __builtin_amdgcn_mfma_f32_16x16x32_bf16(af[m], bfr[n], acc[m][n], 0, 0, 0);
    }
#pragma unroll
    for (int m = 0; m < 2; m++)
#pragma unroll
        for (int n = 0; n < 2; n++) {
            int s = wn + n * 16 + (lane & 15);
#pragma unroll
            for (int q = 0; q < 4; q++) {
                int t = wm + m * 16 + (lane >> 4) * 4 + q;
                QiM[t][s] = f2bf(s < t ? acc[m][n][q] : 0.f);
            }
        }
    __syncthreads();

#pragma unroll
    for (int m = 0; m < 2; m++)
#pragma unroll
        for (int n = 0; n < 2; n++) acc[m][n] = vfloat4{0.f, 0.f, 0.f, 0.f};
#pragma unroll
    for (int kk = 0; kk < 2; kk++) {
        vshort8 af[2], bfr[2];
#pragma unroll
        for (int m = 0; m < 2; m++) af[m]  = *(const vshort8*)&QiM[wm + m * 16 + frow][kk * 32 + fk];
#pragma unroll
        for (int n = 0; n < 2; n++) bfr[n] = *(const vshort8*)&vT[wn + n * 16 + frow][kk * 32 + fk];
#pragma unroll
        for (int m = 0; m < 2; m++)
#pragma unroll
            for (int n = 0; n < 2; n++)
                acc[m][n] = __builtin_amdgcn_mfma_f32_16x16x32_bf16(af[m], bfr[n], acc[m][n], 0, 0, 0);
    }
#pragma unroll
    for (int kk = 0; kk < 2; kk++) {
        vshort8 af[2], bfr[2];
#pragma unroll
        for (int m = 0; m < 2; m++) af[m]  = *(const vshort8*)&rA[wm + m * 16 + frow][kk * 32 + fk];
#pragma unroll
        for (int n = 0; n < 2; n++) bfr[n] = *(const vshort8*)&SbT[wn + n * 16 + frow][kk * 32 + fk];
#pragma unroll
        for (int m = 0; m < 2; m++)
#pragma unroll
            for (int n = 0; n < 2; n++)
                acc[m][n] = __builtin_amdgcn_mfma_f32_16x16x32_bf16(af[m], bfr[n], acc[m][n], 0, 0, 0);
    }
#pragma unroll
    for (int m = 0; m < 2; m++)
#pragma unroll
        for (int n = 0; n < 2; n++) {
            int col = wn + n * 16 + (lane & 15);
#pragma unroll
            for (int q = 0; q < 4; q++) {
                int t = wm + m * 16 + (lane >> 4) * 4 + q;
                ya[rowbase + (size_t)t * Dc + col] = f2bf(acc[m][n][q]);
            }
        }
}

// ---------------- LayerNorm(ya + v2) -> bf16 ----------------
__global__ __launch_bounds__(256) void ln_fuse(
    const unsigned short* __restrict__ ya, const unsigned short* __restrict__ v2,
    const float* __restrict__ lnw, const float* __restrict__ lnb,
    unsigned short* __restrict__ out)
{
    int row = blockIdx.x, tid = threadIdx.x;
    size_t base = (size_t)row * Dc + tid * 8;
    vushort8 a = *(const vushort8*)(ya + base);
    vushort8 b = *(const vushort8*)(v2 + base);
    float v[8]; float s = 0.f, s2 = 0.f;
#pragma unroll
    for (int j = 0; j < 8; j++) { float t = bf2f(a[j]) + bf2f(b[j]); v[j] = t; s += t; s2 += t * t; }
#pragma unroll
    for (int o = 32; o; o >>= 1) { s += __shfl_xor(s, o); s2 += __shfl_xor(s2, o); }
    __shared__ float rs[8];
    int w = tid >> 6;
    if ((tid & 63) == 0) { rs[w] = s; rs[w + 4] = s2; }
    __syncthreads();
    s  = rs[0] + rs[1] + rs[2] + rs[3];
    s2 = rs[4] + rs[5] + rs[6] + rs[7];
    float mu = s * (1.f / Dc);
    float var = s2 * (1.f / Dc) - mu * mu;
    float inv = rsqrtf(var + 1e-5f);
#pragma unroll
    for (int j = 0; j < 8; j++) {
        int d = tid * 8 + j;
        out[base + j] = f2bf((v[j] - mu) * inv * lnw[d] + lnb[d]);
    }
}

// ---------------- host ----------------
static inline void launch_gemm(int epi, const unsigned short* A, int lda,
                               const unsigned short* BT, int ldbt,
                               int M, int N, int K, EpiP ep, hipStream_t s)
{
    if ((M & 127) == 0 && (N & 127) == 0 && (K & 31) == 0 && K >= 128) {
        dim3 g(N / 128, M / 128), b(256);
        switch (epi) {
            case 0: gemm128t<0><<<g, b, 0, s>>>(A, lda, BT, ldbt, M, N, K, ep); break;
            case 1: gemm128t<1><<<g, b, 0, s>>>(A, lda, BT, ldbt, M, N, K, ep); break;
            case 2: gemm128t<2><<<g, b, 0, s>>>(A, lda, BT, ldbt, M, N, K, ep); break;
            case 4: gemm128t<4><<<g, b, 0, s>>>(A, lda, BT, ldbt, M, N, K, ep); break;
            case 5: gemm128t<5><<<g, b, 0, s>>>(A, lda, BT, ldbt, M, N, K, ep); break;
            case 6: gemm128t<6><<<g, b, 0, s>>>(A, lda, BT, ldbt, M, N, K, ep); break;
        }
        return;
    }
    if ((M & 255) == 0 && (N & 255) == 0 && (K & 31) == 0) {
        dim3 g(N / 256, M / 256), b(512);
        switch (epi) {
            case 0: gemm256s<0><<<g, b, 0, s>>>(A, lda, BT, ldbt, M, N, K, ep); break;
            case 1: gemm256s<1><<<g, b, 0, s>>>(A, lda, BT, ldbt, M, N, K, ep); break;
            case 2: gemm256s<2><<<g, b, 0, s>>>(A, lda, BT, ldbt, M, N, K, ep); break;
            case 4: gemm256s<4><<<g, b, 0, s>>>(A, lda, BT, ldbt, M, N, K, ep); break;
            case 5: gemm256s<5><<<g, b, 0, s>>>(A, lda, BT, ldbt, M, N, K, ep); break;
            case 6: gemm256s<6><<<g, b, 0, s>>>(A, lda, BT, ldbt, M, N, K, ep); break;
        }
        return;
    }
    dim3 g((N + 127) / 128, M / 128), b(256);
    switch (epi) {
        case 0: gemm_bt<0><<<g, b, 0, s>>>(A, lda, BT, ldbt, M, N, K, ep); break;
        case 1: gemm_bt<1><<<g, b, 0, s>>>(A, lda, BT, ldbt, M, N, K, ep); break;
        case 2: gemm_bt<2><<<g, b, 0, s>>>(A, lda, BT, ldbt, M, N, K, ep); break;
        case 4: gemm_bt<4><<<g, b, 0, s>>>(A, lda, BT, ldbt, M, N, K, ep); break;
        case 5: gemm_bt<5><<<g, b, 0, s>>>(A, lda, BT, ldbt, M, N, K, ep); break;
        case 6: gemm_bt<6><<<g, b, 0, s>>>(A, lda, BT, ldbt, M, N, K, ep); break;
    }
}

extern "C" void kernel_launch(void* const* d_in, const int* in_sizes, int n_in,
                              void* d_out, int out_size, void* d_ws, size_t ws_size,
                              hipStream_t stream)
{
    (void)in_sizes; (void)n_in; (void)out_size; (void)ws_size;
    const float* x      = (const float*)d_in[0];
    const float* shift  = (const float*)d_in[1];
    const float* wkv_in = (const float*)d_in[2];
    const float* tmx    = (const float*)d_in[3];
    const float* tmr    = (const float*)d_in[4];
    const float* tmk    = (const float*)d_in[5];
    const float* tmv    = (const float*)d_in[6];
    const float* tmw    = (const float*)d_in[7];
    const float* tmv2   = (const float*)d_in[8];
    const float* w1     = (const float*)d_in[9];
    const float* w2     = (const float*)d_in[10];
    const float* tdecay = (const float*)d_in[11];
    const float* tdw1   = (const float*)d_in[12];
    const float* tdw2   = (const float*)d_in[13];
    const float* tv2w1  = (const float*)d_in[14];
    const float* tv2w2  = (const float*)d_in[15];
    const float* Wr     = (const float*)d_in[16];
    const float* Wk     = (const float*)d_in[17];
    const float* Wv     = (const float*)d_in[18];
    const float* Wo     = (const float*)d_in[19];
    const float* lnw    = (const float*)d_in[20];
    const float* lnb    = (const float*)d_in[21];

    // ---- workspace layout (lifetimes aliased; 5 big slots S0..S4) ----
    char* ws = (char*)d_ws;
    const size_t BF = 2 * BTDc;
    size_t o = 0;
    auto take = [&](size_t bytes) { size_t r = o; o += (bytes + 255) & ~(size_t)255; return r; };
    unsigned short* WrT    = (unsigned short*)(ws + take((size_t)Dc * Dc * 2));
    unsigned short* WkT    = (unsigned short*)(ws + take((size_t)Dc * Dc * 2));
    unsigned short* WvT    = (unsigned short*)(ws + take((size_t)Dc * Dc * 2));
    unsigned short* WoT    = (unsigned short*)(ws + take((size_t)Dc * Dc * 2));
    unsigned short* w1T    = (unsigned short*)(ws + take((size_t)160 * Dc * 2));
    unsigned short* w2T    = (unsigned short*)(ws + take((size_t)Dc * 160 * 2));
    unsigned short* tdw1T  = (unsigned short*)(ws + take((size_t)64 * Dc * 2));
    unsigned short* tdw2T  = (unsigned short*)(ws + take((size_t)Dc * 64 * 2));
    unsigned short* tv2w1T = (unsigned short*)(ws + take((size_t)64 * Dc * 2));
    unsigned short* tv2w2T = (unsigned short*)(ws + take((size_t)Dc * 64 * 2));
    take(1 << 18);
    unsigned short* S0     = (unsigned short*)(ws + take(BF));   // XXX -> XR -> YA
    unsigned short* MIXPRE = (unsigned short*)(ws + take((size_t)BTc * 160 * 2));
    unsigned short* S1     = (unsigned short*)(ws + take(BF));   // XK -> Vb -> YLN
    unsigned short* WT     = (unsigned short*)(ws + take((size_t)BTc * 64 * 2));
    unsigned short* T1     = (unsigned short*)(ws + take((size_t)BTc * 64 * 2));
    unsigned short* S2     = (unsigned short*)(ws + take(BF));   // XV -> Rb
    unsigned short* S3     = (unsigned short*)(ws + take(BF));   // XW -> KDb -> V2
    unsigned short* S4     = (unsigned short*)(ws + take(BF));   // DX -> XV2 (in-place)
    float*          Pb     = (float*)(ws + take((size_t)128 * 32 * 4096 * 4));
    float*          ALb    = (float*)(ws + take((size_t)128 * 32 * 64 * 4));

    float* out_f     = (float*)d_out;
    float* shift_out = out_f + BTDc;
    float* wkv_out   = shift_out + (size_t)Bc * Dc;
    float* DEC       = out_f;   // f32 decay in d_out region (dead before final GEMM)

    unsigned short* XXX = S0;
    unsigned short* DX  = S4;
    unsigned short* XR  = S0;
    unsigned short* XK  = S1;
    unsigned short* XV  = S2;
    unsigned short* XW  = S3;
    unsigned short* XV2 = S4;
    unsigned short* KDb = S3;   // after WT gemm (XW dead)
    unsigned short* Vb  = S1;   // after KDb gemm (XK dead)
    unsigned short* Rb  = S2;   // after Vb gemm (XV dead)
    unsigned short* YA  = S0;   // after Rb gemm + wkv (XR dead)
    unsigned short* V2  = S3;   // after wkv (KDb dead)
    unsigned short* YLN = S1;   // after wkv (Vb dead)

    dim3 tb(256);
    transpose_cast<<<dim3(64, 64), tb, 0, stream>>>(Wr, WrT, Dc, Dc);
    transpose_cast<<<dim3(64, 64), tb, 0, stream>>>(Wk, WkT, Dc, Dc);
    transpose_cast<<<dim3(64, 64), tb, 0, stream>>>(Wv, WvT, Dc, Dc);
    transpose_cast<<<dim3(64, 64), tb, 0, stream>>>(Wo, WoT, Dc, Dc);
    transpose_cast<<<dim3(5, 64),  tb, 0, stream>>>(w1, w1T, Dc, 160);
    transpose_cast<<<dim3(64, 5),  tb, 0, stream>>>(w2, w2T, 160, Dc);
    transpose_cast<<<dim3(2, 64),  tb, 0, stream>>>(tdw1, tdw1T, Dc, 64);
    transpose_cast<<<dim3(64, 2),  tb, 0, stream>>>(tdw2, tdw2T, 64, Dc);
    transpose_cast<<<dim3(2, 64),  tb, 0, stream>>>(tv2w1, tv2w1T, Dc, 64);
    transpose_cast<<<dim3(64, 2),  tb, 0, stream>>>(tv2w2, tv2w2T, 64, Dc);

    prep_xxx<<<BTc, tb, 0, stream>>>(x, shift, tmx, XXX, DX);
    shift_copy<<<32, tb, 0, stream>>>(x, shift_out);

    EpiP ep{};
    // mixpre = tanh(xxx @ w1); XXX (S0) dead afterwards
    ep = EpiP{}; ep.ob = MIXPRE;
    launch_gemm(2, XXX, Dc, w1T, Dc, BTc, 160, Dc, ep, stream);

    // fused five mix GEMMs
    {
        Mix5P mp;
        mp.vec[0] = tmr; mp.vec[1] = tmk; mp.vec[2] = tmv; mp.vec[3] = tmw; mp.vec[4] = tmv2;
        mp.out[0] = XR;  mp.out[1] = XK;  mp.out[2] = XV;  mp.out[3] = XW;  mp.out[4] = XV2;
        mix5<<<dim3(16, 128), tb, 0, stream>>>(MIXPRE, w2T, x, DX, mp);
    }

    // decay path: XW -> WT -> DEC
    ep = EpiP{}; ep.ob = WT;
    launch_gemm(2, XW, Dc, tdw1T, Dc, BTc, 64, Dc, ep, stream);
    ep = EpiP{}; ep.of = DEC; ep.vec = tdecay;
    launch_gemm(5, WT, 64, tdw2T, 64, BTc, Dc, 64, ep, stream);
    // k*(1-decay): XK -> KDb (S3; XW dead)
    ep = EpiP{}; ep.ob = KDb; ep.a0 = DEC;
    launch_gemm(4, XK, Dc, WkT, Dc, BTc, Dc, Dc, ep, stream);
    // v: XV -> Vb (S1; XK dead)
    ep = EpiP{}; ep.ob = Vb;
    launch_gemm(1, XV, Dc, WvT, Dc, BTc, Dc, Dc, ep, stream);
    // r: XR -> Rb (S2; XV dead)
    ep = EpiP{}; ep.ob = Rb;
    launch_gemm(1, XR, Dc, WrT, Dc, BTc, Dc, Dc, ep, stream);

    // chunked WKV scan (MFMA)
    wkv_summary<<<4096, tb, 0, stream>>>(KDb, Vb, DEC, Pb, ALb);
    wkv_states<<<2048, tb, 0, stream>>>(wkv_in, Pb, ALb, wkv_out);
    wkv_y<<<4096, tb, 0, stream>>>(Rb, KDb, Vb, DEC, Pb, YA);   // YA = S0 (XR dead)

    // v2 path: XV2 (S4) still live
    ep = EpiP{}; ep.ob = V2;                                     // V2 = S3 (KDb dead)
    launch_gemm(1, XV2, Dc, WvT, Dc, BTc, Dc, Dc, ep, stream);
    ep = EpiP{}; ep.ob = T1;
    launch_gemm(2, XV2, Dc, tv2w1T, Dc, BTc, 64, Dc, ep, stream);
    ep = EpiP{}; ep.ob = V2; ep.ab = V2;                         // in-place add
    launch_gemm(6, T1, 64, tv2w2T, 64, BTc, Dc, 64, ep, stream);

    // layernorm + output projection
    ln_fuse<<<BTc, tb, 0, stream>>>(YA, V2, lnw, lnb, YLN);      // YLN = S1 (Vb dead)
    ep = EpiP{}; ep.of = out_f;
    launch_gemm(0, YLN, Dc, WoT, Dc, BTc, Dc, Dc, ep, stream);
}

// Round 12
// 699.620 us; speedup vs baseline: 1.3086x; 1.3086x over previous
//
#include <hip/hip_runtime.h>
#include <hip/hip_bf16.h>

// ---------------- types / helpers ----------------
typedef __attribute__((ext_vector_type(8))) short   vshort8;   // 8 x bf16 bits (4 VGPRs)
typedef __attribute__((ext_vector_type(8))) unsigned short vushort8;
typedef __attribute__((ext_vector_type(4))) float   vfloat4;
typedef __attribute__((ext_vector_type(2))) float   vfloat2;

__device__ __forceinline__ float bf2f(unsigned short h) {
    union { unsigned u; float f; } x; x.u = ((unsigned)h) << 16; return x.f;
}
__device__ __forceinline__ unsigned short f2bf(float f) {
    union { float f; unsigned u; } x; x.f = f;
    unsigned r = x.u + 0x7fffu + ((x.u >> 16) & 1u);
    return (unsigned short)(r >> 16);
}
__device__ __forceinline__ void cp16_async(const void* g, void* l) {
    __builtin_amdgcn_global_load_lds(
        (const __attribute__((address_space(1))) unsigned int*)g,
        (__attribute__((address_space(3))) unsigned int*)l, 16, 0, 0);
}

#define FBAR() do { asm volatile("" ::: "memory"); __builtin_amdgcn_s_barrier(); asm volatile("" ::: "memory"); } while (0)

// ---------------- constants ----------------
#define Bc 4
#define Tc 2048
#define Dc 2048
#define Hc 32
#define KHc 64
#define BTc (Bc*Tc)              // 8192
#define BTDc ((size_t)BTc*Dc)    // 16,777,216
#define LP 72                    // LDS row stride (shorts) for scan kernels

struct EpiP {
    float* of;                 // f32 out
    unsigned short* ob;        // bf16 out
    const float* a0;           // aux f32 (decay)
    const float* a1;           // aux f32 (unused)
    const unsigned short* ab;  // aux bf16 (v2 partial)
    const float* vec;          // per-col vector (time_decay)
};

template<int EPI>
__device__ __forceinline__ void epi_store(float a, int row, int col, int N, const EpiP& ep)
{
    size_t o = (size_t)row * N + col;
    if (EPI == 0) {
        ep.of[o] = a;
    } else if (EPI == 1) {
        ep.ob[o] = f2bf(a);
    } else if (EPI == 2) {
        ep.ob[o] = f2bf(tanhf(a));
    } else if (EPI == 4) {                // KD: acc * (1 - decay)
        ep.ob[o] = f2bf(a * (1.f - ep.a0[o]));
    } else if (EPI == 5) {                // DECAY: exp(-exp(vec[col]+acc)) f32
        ep.of[o] = expf(-expf(ep.vec[col] + a));
    } else if (EPI == 6) {                // ADDB: acc + bf16 aux -> bf16
        ep.ob[o] = f2bf(a + bf2f(ep.ab[o]));
    }
}

// ============ GEMM-128 (m97-style, fully-drained), fallback for odd shapes ============
template<int EPI>
__global__ __launch_bounds__(256) void gemm_bt(
    const unsigned short* __restrict__ A, int lda,
    const unsigned short* __restrict__ BT, int ldbt,
    int M, int N, int K, EpiP ep)
{
    __shared__ unsigned short lA[128 * 32];
    __shared__ unsigned short lB[128 * 32];
    const int tid  = threadIdx.x;
    const int lane = tid & 63;
    const int w    = tid >> 6;
    const int mt   = blockIdx.y, nt = blockIdx.x;
    const int wm = (w >> 1) * 64, wn = (w & 1) * 64;
    const int frow = lane & 15, fk = (lane >> 4) * 8;

    vfloat4 acc[4][4];
#pragma unroll
    for (int i = 0; i < 4; i++)
#pragma unroll
        for (int j = 0; j < 4; j++) acc[i][j] = vfloat4{0.f, 0.f, 0.f, 0.f};

    for (int k0 = 0; k0 < K; k0 += 32) {
        __syncthreads();
#pragma unroll
        for (int p = 0; p < 2; p++) {
            int idx = p * 256 + tid;
            int row = idx >> 2, colh = (idx & 3) * 8;
            cp16_async(A + (size_t)(mt * 128 + row) * lda + k0 + colh, &lA[idx * 8]);
        }
#pragma unroll
        for (int p = 0; p < 2; p++) {
            int idx = p * 256 + tid;
            int row = idx >> 2, colh = (idx & 3) * 8;
            cp16_async(BT + (size_t)(nt * 128 + row) * ldbt + k0 + colh, &lB[idx * 8]);
        }
        __syncthreads();

        vshort8 af[4], bfr[4];
#pragma unroll
        for (int m = 0; m < 4; m++) af[m]  = *(const vshort8*)&lA[(wm + m * 16 + frow) * 32 + fk];
#pragma unroll
        for (int n = 0; n < 4; n++) bfr[n] = *(const vshort8*)&lB[(wn + n * 16 + frow) * 32 + fk];
#pragma unroll
        for (int m = 0; m < 4; m++)
#pragma unroll
            for (int n = 0; n < 4; n++)
                acc[m][n] = __builtin_amdgcn_mfma_f32_16x16x32_bf16(af[m], bfr[n], acc[m][n], 0, 0, 0);
    }

    const int crow0 = mt * 128 + wm, ccol0 = nt * 128 + wn;
#pragma unroll
    for (int m = 0; m < 4; m++)
#pragma unroll
        for (int n = 0; n < 4; n++) {
            int col = ccol0 + n * 16 + (lane & 15);
            if (col >= N) continue;
#pragma unroll
            for (int q = 0; q < 4; q++) {
                int row = crow0 + m * 16 + (lane >> 4) * 4 + q;
                epi_store<EPI>(acc[m][n][q], row, col, N, ep);
            }
        }
}

// ============ split-K tall-skinny GEMM: f32 partials, grid (ntN*KS, M/128) ============
__global__ __launch_bounds__(256) void gemm_splitk(
    const unsigned short* __restrict__ A, int lda,
    const unsigned short* __restrict__ BT, int ldbt,
    int M, int N, int KS, int Ksl, float* __restrict__ part)
{
    __shared__ unsigned short lA[128 * 32];
    __shared__ unsigned short lB[128 * 32];
    const int tid  = threadIdx.x;
    const int lane = tid & 63;
    const int w    = tid >> 6;
    const int nt = blockIdx.x / KS, ks = blockIdx.x % KS;
    const int mt = blockIdx.y;
    const int wm = (w >> 1) * 64, wn = (w & 1) * 64;
    const int frow = lane & 15, fk = (lane >> 4) * 8;

    vfloat4 acc[4][4];
#pragma unroll
    for (int i = 0; i < 4; i++)
#pragma unroll
        for (int j = 0; j < 4; j++) acc[i][j] = vfloat4{0.f, 0.f, 0.f, 0.f};

    const int kend = ks * Ksl + Ksl;
    for (int k0 = ks * Ksl; k0 < kend; k0 += 32) {
        __syncthreads();
#pragma unroll
        for (int p = 0; p < 2; p++) {
            int idx = p * 256 + tid;
            int row = idx >> 2, colh = (idx & 3) * 8;
            cp16_async(A + (size_t)(mt * 128 + row) * lda + k0 + colh, &lA[idx * 8]);
        }
#pragma unroll
        for (int p = 0; p < 2; p++) {
            int idx = p * 256 + tid;
            int row = idx >> 2, colh = (idx & 3) * 8;
            cp16_async(BT + (size_t)(nt * 128 + row) * ldbt + k0 + colh, &lB[idx * 8]);
        }
        __syncthreads();

        vshort8 af[4], bfr[4];
#pragma unroll
        for (int m = 0; m < 4; m++) af[m]  = *(const vshort8*)&lA[(wm + m * 16 + frow) * 32 + fk];
#pragma unroll
        for (int n = 0; n < 4; n++) bfr[n] = *(const vshort8*)&lB[(wn + n * 16 + frow) * 32 + fk];
#pragma unroll
        for (int m = 0; m < 4; m++)
#pragma unroll
            for (int n = 0; n < 4; n++)
                acc[m][n] = __builtin_amdgcn_mfma_f32_16x16x32_bf16(af[m], bfr[n], acc[m][n], 0, 0, 0);
    }

    const int crow0 = mt * 128 + wm, ccol0 = nt * 128 + wn;
    float* pbase = part + (size_t)ks * M * N;
#pragma unroll
    for (int m = 0; m < 4; m++)
#pragma unroll
        for (int n = 0; n < 4; n++) {
            int col = ccol0 + n * 16 + (lane & 15);
            if (col >= N) continue;
#pragma unroll
            for (int q = 0; q < 4; q++) {
                int row = crow0 + m * 16 + (lane >> 4) * 4 + q;
                pbase[(size_t)row * N + col] = acc[m][n][q];
            }
        }
}

__global__ __launch_bounds__(256) void splitk_reduce_tanh(
    const float* __restrict__ part, int KS, size_t MN, unsigned short* __restrict__ out)
{
    size_t i = (size_t)blockIdx.x * 256 + threadIdx.x;
    if (i >= MN) return;
    float s = 0.f;
    for (int k = 0; k < KS; k++) s += part[(size_t)k * MN + i];
    out[i] = f2bf(tanhf(s));
}

// ============ GEMM-256s: 256x256, BK=32, triple-buffer (for small K: 32/64) ============
template<int EPI>
__global__ __launch_bounds__(512, 1) void gemm256s(
    const unsigned short* __restrict__ A, int lda,
    const unsigned short* __restrict__ BT, int ldbt,
    int M, int N, int K, EpiP ep)
{
    __shared__ unsigned short sh[3 * 16384];   // 96 KB
    const int tid  = threadIdx.x;
    const int lane = tid & 63;
    const int w    = tid >> 6;

    int bid = blockIdx.y * gridDim.x + blockIdx.x;
    {
        int nwg = gridDim.x * gridDim.y;
        if ((nwg & 7) == 0) bid = (bid & 7) * (nwg >> 3) + (bid >> 3);
    }
    const int mt = bid / gridDim.x, nt = bid % gridDim.x;

    const int wm = (w >> 2) * 128, wn = (w & 3) * 64;
    const int frow = lane & 15;
    const int cswz = ((lane >> 4) ^ ((frow >> 1) & 3)) * 8;
    const int arow0 = mt * 256, brow0 = nt * 256;

    vfloat4 acc[8][4];
#pragma unroll
    for (int i = 0; i < 8; i++)
#pragma unroll
        for (int j = 0; j < 4; j++) acc[i][j] = vfloat4{0.f, 0.f, 0.f, 0.f};

    const int NT = K >> 5;

    auto stage = [&](int kt, int sbuf) {
        int k0 = kt << 5;
        unsigned short* dst = &sh[sbuf * 16384];
#pragma unroll
        for (int i = 0; i < 2; i++) {
            int idx = i * 512 + tid;
            int row = idx >> 2;
            int ch  = (idx & 3) ^ ((row >> 1) & 3);
            cp16_async(A + (size_t)(arow0 + row) * lda + k0 + ch * 8, dst + idx * 8);
        }
#pragma unroll
        for (int i = 0; i < 2; i++) {
            int idx = i * 512 + tid;
            int row = idx >> 2;
            int ch  = (idx & 3) ^ ((row >> 1) & 3);
            cp16_async(BT + (size_t)(brow0 + row) * ldbt + k0 + ch * 8, dst + 8192 + idx * 8);
        }
    };

    stage(0, 0);
    if (NT > 1) {
        stage(1, 1);
        asm volatile("s_waitcnt vmcnt(4)" ::: "memory");
    } else {
        asm volatile("s_waitcnt vmcnt(0)" ::: "memory");
    }
    __builtin_amdgcn_s_barrier();

    int buf = 0, sb = 2;
    for (int kt = 0; kt < NT; kt++) {
        if (kt + 2 < NT) stage(kt + 2, sb);
        const unsigned short* Ab = &sh[buf * 16384];
        const unsigned short* Bb = Ab + 8192;

        vshort8 af[8], bfv[4];
#pragma unroll
        for (int m = 0; m < 8; m++)
            af[m] = *(const vshort8*)&Ab[(wm + m * 16 + frow) * 32 + cswz];
#pragma unroll
        for (int n = 0; n < 4; n++)
            bfv[n] = *(const vshort8*)&Bb[(wn + n * 16 + frow) * 32 + cswz];

        __builtin_amdgcn_s_setprio(1);
#pragma unroll
        for (int m = 0; m < 8; m++)
#pragma unroll
            for (int n = 0; n < 4; n++)
                acc[m][n] = __builtin_amdgcn_mfma_f32_16x16x32_bf16(af[m], bfv[n], acc[m][n], 0, 0, 0);
        __builtin_amdgcn_s_setprio(0);

        if (kt + 1 < NT) {
            if (kt + 2 < NT) asm volatile("s_waitcnt vmcnt(4)" ::: "memory");
            else             asm volatile("s_waitcnt vmcnt(0)" ::: "memory");
            asm volatile("s_waitcnt lgkmcnt(0)" ::: "memory");
            __builtin_amdgcn_s_barrier();
        }
        buf = (buf == 2) ? 0 : buf + 1;
        sb  = (sb  == 2) ? 0 : sb  + 1;
    }

    const int crow0 = arow0 + wm, ccol0 = brow0 + wn;
#pragma unroll
    for (int m = 0; m < 8; m++)
#pragma unroll
        for (int n = 0; n < 4; n++) {
            int col = ccol0 + n * 16 + (lane & 15);
#pragma unroll
            for (int q = 0; q < 4; q++) {
                int row = crow0 + m * 16 + (lane >> 4) * 4 + q;
                epi_store<EPI>(acc[m][n][q], row, col, N, ep);
            }
        }
}

// ============ GEMM-256p8: 256x256, BK=64, 8-phase schedule, counted vmcnt(6) ============
// (round-8/9 variant — best measured: 86 us/dispatch)
template<int EPI>
__global__ __launch_bounds__(512, 1) void gemm256p8(
    const unsigned short* __restrict__ A, int lda,
    const unsigned short* __restrict__ BT, int ldbt,
    int M, int N, int K, EpiP ep)
{
    __shared__ unsigned short sh[65536];   // 128 KB
    const int tid  = threadIdx.x;
    const int lane = tid & 63;
    const int w    = tid >> 6;

    int bid = blockIdx.y * gridDim.x + blockIdx.x;
    {
        int nwg = gridDim.x * gridDim.y;
        if ((nwg & 7) == 0) bid = (bid & 7) * (nwg >> 3) + (bid >> 3);
    }
    const int mt = bid / gridDim.x, nt = bid % gridDim.x;

    const int wm = (w >> 2) * 128, wn = (w & 3) * 64;
    const int frow = lane & 15;
    const int g    = lane >> 4;
    const int arow0 = mt * 256, brow0 = nt * 256;

    vfloat4 acc[8][4];
#pragma unroll
    for (int i = 0; i < 8; i++)
#pragma unroll
        for (int j = 0; j < 4; j++) acc[i][j] = vfloat4{0.f, 0.f, 0.f, 0.f};

    const int NT = K >> 6;   // even, >= 2 (router guarantees K % 128 == 0)

    auto stageA = [&](int kt, int p) {
        int k0 = kt << 6;
        unsigned short* dst = &sh[(kt & 1) * 32768];
#pragma unroll
        for (int l = 0; l < 2; l++) {
            int idx  = l * 512 + tid;
            int rl   = idx >> 3, slot = idx & 7;
            int rg   = (rl & 63) + p * 64 + ((rl >> 6) << 7);
            int ch   = slot ^ (rg & 7);
            cp16_async(A + (size_t)(arow0 + rg) * lda + k0 + ch * 8, dst + rg * 64 + slot * 8);
        }
    };
    auto stageB = [&](int kt, int p) {
        int k0 = kt << 6;
        unsigned short* dst = &sh[(kt & 1) * 32768 + 16384];
#pragma unroll
        for (int l = 0; l < 2; l++) {
            int idx  = l * 512 + tid;
            int rl   = idx >> 3, slot = idx & 7;
            int rg   = (rl & 31) + p * 32 + ((rl >> 5) << 6);
            int ch   = slot ^ (rg & 7);
            cp16_async(BT + (size_t)(brow0 + rg) * ldbt + k0 + ch * 8, dst + rg * 64 + slot * 8);
        }
    };

    vshort8 af[4][2], bf0[2][2], bf1[2][2];

    auto readA = [&](const unsigned short* Ab, int mh) {
#pragma unroll
        for (int mi = 0; mi < 4; mi++) {
            int r = wm + mh * 64 + mi * 16 + frow;
#pragma unroll
            for (int kk = 0; kk < 2; kk++)
                af[mi][kk] = *(const vshort8*)&Ab[r * 64 + (((kk * 4 + g) ^ (r & 7)) * 8)];
        }
    };
    auto readB = [&](const unsigned short* Bb, int nh, vshort8 (&bfr)[2][2]) {
#pragma unroll
        for (int ni = 0; ni < 2; ni++) {
            int r = wn + nh * 32 + ni * 16 + frow;
#pragma unroll
            for (int kk = 0; kk < 2; kk++)
                bfr[ni][kk] = *(const vshort8*)&Bb[r * 64 + (((kk * 4 + g) ^ (r & 7)) * 8)];
        }
    };
    auto domfma = [&](int mh, int nh, vshort8 (&bfr)[2][2]) {
        __builtin_amdgcn_s_setprio(1);
#pragma unroll
        for (int mi = 0; mi < 4; mi++)
#pragma unroll
            for (int ni = 0; ni < 2; ni++)
#pragma unroll
                for (int kk = 0; kk < 2; kk++)
                    acc[mh * 4 + mi][nh * 2 + ni] = __builtin_amdgcn_mfma_f32_16x16x32_bf16(
                        af[mi][kk], bfr[ni][kk], acc[mh * 4 + mi][nh * 2 + ni], 0, 0, 0);
        __builtin_amdgcn_s_setprio(0);
    };

    // prologue: T0 full + T1.Am0, T1.Bn1  (6 halves = 12 loads in flight)
    stageA(0, 0); stageB(0, 1); stageA(0, 1); stageB(0, 0);
    stageA(1, 0); stageB(1, 1);

    const unsigned short* A0 = sh;
    const unsigned short* B0 = sh + 16384;
    const unsigned short* A1 = sh + 32768;
    const unsigned short* B1 = sh + 49152;

    for (int i2 = 0; i2 < NT; i2 += 2) {
        const bool s2 = (i2 + 2 < NT), s3 = (i2 + 3 < NT);
        // ph0
        stageA(i2 + 1, 1);
        asm volatile("s_waitcnt vmcnt(6)" ::: "memory");
        FBAR();
        readA(A0, 0); readB(B0, 0, bf0);
        domfma(0, 0, bf0);
        asm volatile("s_waitcnt lgkmcnt(0)" ::: "memory");
        FBAR();
        // ph1
        stageB(i2 + 1, 0);
        FBAR();
        readB(B0, 1, bf1);
        domfma(0, 1, bf1);
        asm volatile("s_waitcnt lgkmcnt(0)" ::: "memory");
        FBAR();
        // ph2
        if (s2) stageA(i2 + 2, 0);
        FBAR();
        readA(A0, 1);
        domfma(1, 1, bf1);
        asm volatile("s_waitcnt lgkmcnt(0)" ::: "memory");
        FBAR();
        // ph3
        if (s2) stageB(i2 + 2, 1);
        FBAR();
        domfma(1, 0, bf0);
        FBAR();
        // ph4
        if (s2) {
            stageA(i2 + 2, 1);
            asm volatile("s_waitcnt vmcnt(6)" ::: "memory");
        } else {
            asm volatile("s_waitcnt vmcnt(0)" ::: "memory");
        }
        FBAR();
        readA(A1, 0); readB(B1, 0, bf0);
        domfma(0, 0, bf0);
        asm volatile("s_waitcnt lgkmcnt(0)" ::: "memory");
        FBAR();
        // ph5
        if (s2) stageB(i2 + 2, 0);
        FBAR();
        readB(B1, 1, bf1);
        domfma(0, 1, bf1);
        asm volatile("s_waitcnt lgkmcnt(0)" ::: "memory");
        FBAR();
        // ph6
        if (s3) stageA(i2 + 3, 0);
        FBAR();
        readA(A1, 1);
        domfma(1, 1, bf1);
        asm volatile("s_waitcnt lgkmcnt(0)" ::: "memory");
        FBAR();
        // ph7
        if (s3) stageB(i2 + 3, 1);
        FBAR();
        domfma(1, 0, bf0);
        FBAR();
    }

    const int crow0 = arow0 + wm, ccol0 = brow0 + wn;
#pragma unroll
    for (int m = 0; m < 8; m++)
#pragma unroll
        for (int n = 0; n < 4; n++) {
            int col = ccol0 + n * 16 + (lane & 15);
#pragma unroll
            for (int q = 0; q < 4; q++) {
                int row = crow0 + m * 16 + (lane >> 4) * 4 + q;
                epi_store<EPI>(acc[m][n][q], row, col, N, ep);
            }
        }
}

// ============ mix5: fused five mix GEMMs (K=32), x/DX read once ============
struct Mix5P {
    const float* vec[5];
    unsigned short* out[5];
};

__global__ __launch_bounds__(256) void mix5(
    const unsigned short* __restrict__ MP,   // MIXPRE [BTc][160]
    const unsigned short* __restrict__ W2T,  // [Dc][160]
    const float* __restrict__ x,
    const unsigned short* __restrict__ DXb,
    Mix5P p)
{
    __shared__ unsigned short lA[64 * 32];    // 4 KB
    __shared__ unsigned short lB[128 * 32];   // 8 KB
    const int tid = threadIdx.x, lane = tid & 63, w = tid >> 6;
    const int mt = blockIdx.y, nt = blockIdx.x;   // grid (16, 128)
    const int wm = (w >> 1) * 32, wn = (w & 1) * 64;
    const int frow = lane & 15, fk = (lane >> 4) * 8;
    const int row0 = mt * 64, col0 = nt * 128;

    float xr[8][4], dxr[8][4];
#pragma unroll
    for (int mi = 0; mi < 2; mi++)
#pragma unroll
        for (int q = 0; q < 4; q++) {
            int rl = wm + mi * 16 + (lane >> 4) * 4 + q;
            size_t rb = (size_t)(row0 + rl) * Dc + col0;
#pragma unroll
            for (int ni = 0; ni < 4; ni++) {
                int cl = wn + ni * 16 + (lane & 15);
                xr[mi * 4 + q][ni]  = x[rb + cl];
                dxr[mi * 4 + q][ni] = bf2f(DXb[rb + cl]);
            }
        }

    for (int f = 0; f < 5; f++) {
        __syncthreads();
        {
            int row = tid >> 2, ch = tid & 3;
            cp16_async(MP + (size_t)(row0 + row) * 160 + f * 32 + ch * 8, &lA[(row * 4 + ch) * 8]);
        }
#pragma unroll
        for (int p2 = 0; p2 < 2; p2++) {
            int idx = p2 * 256 + tid;
            int row = idx >> 2, ch = idx & 3;
            cp16_async(W2T + (size_t)(col0 + row) * 160 + f * 32 + ch * 8, &lB[(row * 4 + ch) * 8]);
        }
        __syncthreads();

        vshort8 af[2], bfr[4];
#pragma unroll
        for (int mi = 0; mi < 2; mi++) af[mi]  = *(const vshort8*)&lA[(wm + mi * 16 + frow) * 32 + fk];
#pragma unroll
        for (int ni = 0; ni < 4; ni++) bfr[ni] = *(const vshort8*)&lB[(wn + ni * 16 + frow) * 32 + fk];

        vfloat4 acc[2][4];
#pragma unroll
        for (int mi = 0; mi < 2; mi++)
#pragma unroll
            for (int ni = 0; ni < 4; ni++) {
                acc[mi][ni] = vfloat4{0.f, 0.f, 0.f, 0.f};
                acc[mi][ni] = __builtin_amdgcn_mfma_f32_16x16x32_bf16(af[mi], bfr[ni], acc[mi][ni], 0, 0, 0);
            }

        const float* vec = p.vec[f];
        unsigned short* ob = p.out[f];
        float vc[4];
#pragma unroll
        for (int ni = 0; ni < 4; ni++) vc[ni] = vec[col0 + wn + ni * 16 + (lane & 15)];
#pragma unroll
        for (int mi = 0; mi < 2; mi++)
#pragma unroll
            for (int q = 0; q < 4; q++) {
                int rl = wm + mi * 16 + (lane >> 4) * 4 + q;
                size_t rb = (size_t)(row0 + rl) * Dc + col0;
#pragma unroll
                for (int ni = 0; ni < 4; ni++) {
                    int cl = wn + ni * 16 + (lane & 15);
                    ob[rb + cl] = f2bf(xr[mi * 4 + q][ni] + dxr[mi * 4 + q][ni] * (vc[ni] + acc[mi][ni][q]));
                }
            }
    }
}

// ---------------- prep: xxx = x + dx*time_maa_x, dx = xprev - x  -> bf16 ----------------
__global__ __launch_bounds__(256) void prep_xxx(
    const float* __restrict__ x, const float* __restrict__ shift_in,
    const float* __restrict__ tmx, unsigned short* __restrict__ xxx,
    unsigned short* __restrict__ dxb)
{
    int row = blockIdx.x, tid = threadIdx.x;
    int t = row & (Tc - 1), b = row >> 11;
    size_t base = (size_t)row * Dc + tid * 8;
    const float* xp = t ? x + base - Dc : shift_in + (size_t)b * Dc + tid * 8;
    vushort8 o, dxo;
#pragma unroll
    for (int j = 0; j < 8; j++) {
        float xv = x[base + j];
        float dx = xp[j] - xv;
        o[j]   = f2bf(xv + dx * tmx[tid * 8 + j]);
        dxo[j] = f2bf(dx);
    }
    *(vushort8*)(xxx + base) = o;
    *(vushort8*)(dxb + base) = dxo;
}

__global__ __launch_bounds__(256) void shift_copy(const float* __restrict__ x, float* __restrict__ out)
{
    int i = blockIdx.x * 256 + threadIdx.x;   // B*D = 8192
    int b = i >> 11, d = i & (Dc - 1);
    out[i] = x[((size_t)b * Tc + (Tc - 1)) * Dc + d];
}

// ---------------- transpose + cast f32 -> bf16 : out[C][R] = in[R][C] ----------------
__global__ __launch_bounds__(256) void transpose_cast(
    const float* __restrict__ in, unsigned short* __restrict__ out, int R, int C)
{
    __shared__ float tile[32][33];
    int ct = blockIdx.x, rt = blockIdx.y;
    int lx = threadIdx.x & 31, ly = threadIdx.x >> 5;
#pragma unroll
    for (int i = 0; i < 4; i++)
        tile[ly + i * 8][lx] = in[(size_t)(rt * 32 + ly + i * 8) * C + ct * 32 + lx];
    __syncthreads();
#pragma unroll
    for (int i = 0; i < 4; i++)
        out[(size_t)(ct * 32 + ly + i * 8) * R + rt * 32 + lx] = f2bf(tile[lx][ly + i * 8]);
}

// =========== WKV chunked scan as chunked linear attention (MFMA) ===========
__global__ __launch_bounds__(256) void wkv_summary(
    const unsigned short* __restrict__ kd, const unsigned short* __restrict__ vv,
    const float* __restrict__ dec, float* __restrict__ P, float* __restrict__ aL)
{
    __shared__ unsigned short kb2T[64][LP];
    __shared__ unsigned short vT[64][LP];
    __shared__ float gp[4][64];
    const int blk = blockIdx.x;
    const int c = blk & 31, bh = blk >> 5, b = bh >> 5, h = bh & 31;
    const int tid = threadIdx.x;
    const size_t rowbase = ((size_t)(b * Tc + c * 64)) * Dc + h * 64;

    {
        int t = tid >> 2, q = tid & 3;
        const unsigned short* src = vv + rowbase + (size_t)t * Dc + q * 16;
        vushort8 a = *(const vushort8*)src;
        vushort8 b2 = *(const vushort8*)(src + 8);
#pragma unroll
        for (int j = 0; j < 8; j++) vT[q * 16 + j][t] = a[j];
#pragma unroll
        for (int j = 0; j < 8; j++) vT[q * 16 + 8 + j][t] = b2[j];
    }

    const int k = tid & 63, grp = tid >> 6;
    const float* decp = dec + rowbase + k;
    const unsigned short* kp = kd + rowbase + k;
    float suf_local[16];
    float pgrp = 1.f;
#pragma unroll
    for (int i = 15; i >= 0; i--) {
        int t = grp * 16 + i;
        float d = decp[(size_t)t * Dc];
        suf_local[i] = pgrp;
        pgrp *= d;
    }
    gp[grp][k] = pgrp;
    __syncthreads();
    float suff = 1.f;
#pragma unroll
    for (int g2 = 0; g2 < 4; g2++) if (g2 > grp) suff *= gp[g2][k];
    if (grp == 0) aL[(size_t)blk * 64 + k] = pgrp * suff;
    {
        vushort8 p0, p1;
#pragma unroll
        for (int i = 0; i < 8; i++) {
            int t = grp * 16 + i;
            p0[i] = f2bf(bf2f(kp[(size_t)t * Dc]) * (suf_local[i] * suff));
        }
#pragma unroll
        for (int i = 0; i < 8; i++) {
            int t = grp * 16 + 8 + i;
            p1[i] = f2bf(bf2f(kp[(size_t)t * Dc]) * (suf_local[8 + i] * suff));
        }
        *(vushort8*)&kb2T[k][grp * 16] = p0;
        *(vushort8*)&kb2T[k][grp * 16 + 8] = p1;
    }
    __syncthreads();

    const int lane = tid & 63, w = tid >> 6;
    const int wm = (w >> 1) * 32, wn = (w & 1) * 32;
    const int frow = lane & 15, fk = (lane >> 4) * 8;
    vfloat4 acc[2][2];
#pragma unroll
    for (int m = 0; m < 2; m++)
#pragma unroll
        for (int n = 0; n < 2; n++) acc[m][n] = vfloat4{0.f, 0.f, 0.f, 0.f};
#pragma unroll
    for (int kk = 0; kk < 2; kk++) {
        vshort8 af[2], bfr[2];
#pragma unroll
        for (int m = 0; m < 2; m++) af[m]  = *(const vshort8*)&kb2T[wm + m * 16 + frow][kk * 32 + fk];
#pragma unroll
        for (int n = 0; n < 2; n++) bfr[n] = *(const vshort8*)&vT[wn + n * 16 + frow][kk * 32 + fk];
#pragma unroll
        for (int m = 0; m < 2; m++)
#pragma unroll
            for (int n = 0; n < 2; n++)
                acc[m][n] = __builtin_amdgcn_mfma_f32_16x16x32_bf16(af[m], bfr[n], acc[m][n], 0, 0, 0);
    }
    float* Pp = P + (size_t)blk * 4096;
#pragma unroll
    for (int m = 0; m < 2; m++)
#pragma unroll
        for (int n = 0; n < 2; n++) {
            int col = wn + n * 16 + (lane & 15);
#pragma unroll
            for (int q = 0; q < 4; q++) {
                int row = wm + m * 16 + (lane >> 4) * 4 + q;
                Pp[row * 64 + col] = acc[m][n][q];
            }
        }
}

__global__ __launch_bounds__(256) void wkv_states(
    const float* __restrict__ wkv_in, float* __restrict__ P /* -> Sb */,
    const float* __restrict__ aL, float* __restrict__ wkv_out)
{
    int idx = blockIdx.x * 256 + threadIdx.x;   // 524288
    int bh = idx >> 12, kv = idx & 4095, k = kv >> 6;
    float S = wkv_in[idx];
    for (int c = 0; c < 32; c++) {
        size_t off = (size_t)bh * 32 + c;
        float p = P[off * 4096 + kv];
        float a = aL[off * 64 + k];
        P[off * 4096 + kv] = S;   // Sb[c]
        S = S * a + p;
    }
    wkv_out[idx] = S;
}

__global__ __launch_bounds__(256) void wkv_y(
    const unsigned short* __restrict__ rr, const unsigned short* __restrict__ kd,
    const unsigned short* __restrict__ vv, const float* __restrict__ dec,
    const float* __restrict__ Sb, unsigned short* __restrict__ ya)
{
    __shared__ unsigned short rA[64][LP];
    __shared__ unsigned short kbL[64][LP];
    __shared__ unsigned short vT[64][LP];
    __shared__ unsigned short SbT[64][LP];
    __shared__ unsigned short QiM[64][LP];
    __shared__ float gp[4][64];
    const int blk = blockIdx.x;
    const int c = blk & 31, bh = blk >> 5, b = bh >> 5, h = bh & 31;
    const int tid = threadIdx.x;
    const size_t rowbase = ((size_t)(b * Tc + c * 64)) * Dc + h * 64;

    {
        int t = tid >> 2, q = tid & 3;
        const unsigned short* src = vv + rowbase + (size_t)t * Dc + q * 16;
        vushort8 a = *(const vushort8*)src;
        vushort8 b2 = *(const vushort8*)(src + 8);
#pragma unroll
        for (int j = 0; j < 8; j++) vT[q * 16 + j][t] = a[j];
#pragma unroll
        for (int j = 0; j < 8; j++) vT[q * 16 + 8 + j][t] = b2[j];
        const float* sp = Sb + (size_t)blk * 4096 + t * 64 + q * 16;
#pragma unroll
        for (int j = 0; j < 16; j++) SbT[q * 16 + j][t] = f2bf(sp[j]);
    }

    const int k = tid & 63, grp = tid >> 6;
    const float* decp = dec + rowbase + k;
    const unsigned short* rp = rr + rowbase + k;
    const unsigned short* kp = kd + rowbase + k;
    float pref_local[16];
    float pgrp = 1.f;
#pragma unroll
    for (int i = 0; i < 16; i++) {
        int t = grp * 16 + i;
        float d = decp[(size_t)t * Dc];
        pref_local[i] = pgrp;
        pgrp *= d;
    }
    gp[grp][k] = pgrp;
    __syncthreads();
    float pref = 1.f;
#pragma unroll
    for (int g2 = 0; g2 < 4; g2++) if (g2 < grp) pref *= gp[g2][k];
#pragma unroll
    for (int i = 0; i < 16; i++) {
        int t = grp * 16 + i;
        float Aex  = pref * pref_local[i];
        float Ainc = pref * (i < 15 ? pref_local[i + 1] : pgrp);
        rA[t][k]  = f2bf(bf2f(rp[(size_t)t * Dc]) * Aex);
        kbL[t][k] = f2bf(bf2f(kp[(size_t)t * Dc]) / Ainc);
    }
    __syncthreads();

    const int lane = tid & 63, w = tid >> 6;
    const int wm = (w >> 1) * 32, wn = (w & 1) * 32;
    const int frow = lane & 15, fk = (lane >> 4) * 8;

    vfloat4 acc[2][2];
#pragma unroll
    for (int m = 0; m < 2; m++)
#pragma unroll
        for (int n = 0; n < 2; n++) acc[m][n] = vfloat4{0.f, 0.f, 0.f, 0.f};
#pragma unroll
    for (int kk = 0; kk < 2; kk++) {
        vshort8 af[2], bfr[2];
#pragma unroll
        for (int m = 0; m < 2; m++) af[m]  = *(const vshort8*)&rA[wm + m * 16 + frow][kk * 32 + fk];
#pragma unroll
        for (int n = 0; n < 2; n++) bfr[n] = *(const vshort8*)&kbL[wn + n * 16 + frow][kk * 32 + fk];
#pragma unroll
        for (int m = 0; m < 2; m++)
#pragma unroll
            for (int n = 0; n < 2; n++)
                acc[m][n] = __builtin_amdgcn_mfma_f32_16x16x32_bf16(af[m], bfr[n], acc[m][n], 0, 0, 0);
    }
#pragma unroll
    for (int m = 0; m < 2; m++)
#pragma unroll
        for (int n = 0; n < 2; n++) {
            int s = wn + n * 16 + (lane & 15);
#pragma unroll
            for (int q = 0; q < 4; q++) {
                int t = wm + m * 16 + (lane >> 4) * 4 + q;
                QiM[t][s] = f2bf(s < t ? acc[m][n][q] : 0.f);
            }
        }
    __syncthreads();

#pragma unroll
    for (int m = 0; m < 2; m++)
#pragma unroll
        for (int n = 0; n < 2; n++) acc[m][n] = vfloat4{0.f, 0.f, 0.f, 0.f};
#pragma unroll
    for (int kk = 0; kk < 2; kk++) {
        vshort8 af[2], bfr[2];
#pragma unroll
        for (int m = 0; m < 2; m++) af[m]  = *(const vshort8*)&QiM[wm + m * 16 + frow][kk * 32 + fk];
#pragma unroll
        for (int n = 0; n < 2; n++) bfr[n] = *(const vshort8*)&vT[wn + n * 16 + frow][kk * 32 + fk];
#pragma unroll
        for (int m = 0; m < 2; m++)
#pragma unroll
            for (int n = 0; n < 2; n++)
                acc[m][n] = __builtin_amdgcn_mfma_f32_16x16x32_bf16(af[m], bfr[n], acc[m][n], 0, 0, 0);
    }
#pragma unroll
    for (int kk = 0; kk < 2; kk++) {
        vshort8 af[2], bfr[2];
#pragma unroll
        for (int m = 0; m < 2; m++) af[m]  = *(const vshort8*)&rA[wm + m * 16 + frow][kk * 32 + fk];
#pragma unroll
        for (int n = 0; n < 2; n++) bfr[n] = *(const vshort8*)&SbT[wn + n * 16 + frow][kk * 32 + fk];
#pragma unroll
        for (int m = 0; m < 2; m++)
#pragma unroll
            for (int n = 0; n < 2; n++)
                acc[m][n] = __builtin_amdgcn_mfma_f32_16x16x32_bf16(af[m], bfr[n], acc[m][n], 0, 0, 0);
    }
#pragma unroll
    for (int m = 0; m < 2; m++)
#pragma unroll
        for (int n = 0; n < 2; n++) {
            int col = wn + n * 16 + (lane & 15);
#pragma unroll
            for (int q = 0; q < 4; q++) {
                int t = wm + m * 16 + (lane >> 4) * 4 + q;
                ya[rowbase + (size_t)t * Dc + col] = f2bf(acc[m][n][q]);
            }
        }
}

// ---------------- LayerNorm(ya + v2) -> bf16 ----------------
__global__ __launch_bounds__(256) void ln_fuse(
    const unsigned short* __restrict__ ya, const unsigned short* __restrict__ v2,
    const float* __restrict__ lnw, const float* __restrict__ lnb,
    unsigned short* __restrict__ out)
{
    int row = blockIdx.x, tid = threadIdx.x;
    size_t base = (size_t)row * Dc + tid * 8;
    vushort8 a = *(const vushort8*)(ya + base);
    vushort8 b = *(const vushort8*)(v2 + base);
    float v[8]; float s = 0.f, s2 = 0.f;
#pragma unroll
    for (int j = 0; j < 8; j++) { float t = bf2f(a[j]) + bf2f(b[j]); v[j] = t; s += t; s2 += t * t; }
#pragma unroll
    for (int o = 32; o; o >>= 1) { s += __shfl_xor(s, o); s2 += __shfl_xor(s2, o); }
    __shared__ float rs[8];
    int w = tid >> 6;
    if ((tid & 63) == 0) { rs[w] = s; rs[w + 4] = s2; }
    __syncthreads();
    s  = rs[0] + rs[1] + rs[2] + rs[3];
    s2 = rs[4] + rs[5] + rs[6] + rs[7];
    float mu = s * (1.f / Dc);
    float var = s2 * (1.f / Dc) - mu * mu;
    float inv = rsqrtf(var + 1e-5f);
#pragma unroll
    for (int j = 0; j < 8; j++) {
        int d = tid * 8 + j;
        out[base + j] = f2bf((v[j] - mu) * inv * lnw[d] + lnb[d]);
    }
}

// ---------------- host ----------------
static inline void launch_gemm(int epi, const unsigned short* A, int lda,
                               const unsigned short* BT, int ldbt,
                               int M, int N, int K, EpiP ep, hipStream_t s)
{
    if ((M & 255) == 0 && (N & 255) == 0) {
        if ((K & 127) == 0 && K >= 128 && (epi == 0 || epi == 1 || epi == 4)) {
            dim3 g(N / 256, M / 256), b(512);
            switch (epi) {
                case 0: gemm256p8<0><<<g, b, 0, s>>>(A, lda, BT, ldbt, M, N, K, ep); break;
                case 1: gemm256p8<1><<<g, b, 0, s>>>(A, lda, BT, ldbt, M, N, K, ep); break;
                case 4: gemm256p8<4><<<g, b, 0, s>>>(A, lda, BT, ldbt, M, N, K, ep); break;
            }
            return;
        }
        if ((K & 31) == 0) {
            dim3 g(N / 256, M / 256), b(512);
            switch (epi) {
                case 0: gemm256s<0><<<g, b, 0, s>>>(A, lda, BT, ldbt, M, N, K, ep); break;
                case 1: gemm256s<1><<<g, b, 0, s>>>(A, lda, BT, ldbt, M, N, K, ep); break;
                case 2: gemm256s<2><<<g, b, 0, s>>>(A, lda, BT, ldbt, M, N, K, ep); break;
                case 4: gemm256s<4><<<g, b, 0, s>>>(A, lda, BT, ldbt, M, N, K, ep); break;
                case 5: gemm256s<5><<<g, b, 0, s>>>(A, lda, BT, ldbt, M, N, K, ep); break;
                case 6: gemm256s<6><<<g, b, 0, s>>>(A, lda, BT, ldbt, M, N, K, ep); break;
            }
            return;
        }
    }
    dim3 g((N + 127) / 128, M / 128), b(256);
    switch (epi) {
        case 0: gemm_bt<0><<<g, b, 0, s>>>(A, lda, BT, ldbt, M, N, K, ep); break;
        case 1: gemm_bt<1><<<g, b, 0, s>>>(A, lda, BT, ldbt, M, N, K, ep); break;
        case 2: gemm_bt<2><<<g, b, 0, s>>>(A, lda, BT, ldbt, M, N, K, ep); break;
        case 4: gemm_bt<4><<<g, b, 0, s>>>(A, lda, BT, ldbt, M, N, K, ep); break;
        case 5: gemm_bt<5><<<g, b, 0, s>>>(A, lda, BT, ldbt, M, N, K, ep); break;
        case 6: gemm_bt<6><<<g, b, 0, s>>>(A, lda, BT, ldbt, M, N, K, ep); break;
    }
}

extern "C" void kernel_launch(void* const* d_in, const int* in_sizes, int n_in,
                              void* d_out, int out_size, void* d_ws, size_t ws_size,
                              hipStream_t stream)
{
    (void)in_sizes; (void)n_in; (void)out_size; (void)ws_size;
    const float* x      = (const float*)d_in[0];
    const float* shift  = (const float*)d_in[1];
    const float* wkv_in = (const float*)d_in[2];
    const float* tmx    = (const float*)d_in[3];
    const float* tmr    = (const float*)d_in[4];
    const float* tmk    = (const float*)d_in[5];
    const float* tmv    = (const float*)d_in[6];
    const float* tmw    = (const float*)d_in[7];
    const float* tmv2   = (const float*)d_in[8];
    const float* w1     = (const float*)d_in[9];
    const float* w2     = (const float*)d_in[10];
    const float* tdecay = (const float*)d_in[11];
    const float* tdw1   = (const float*)d_in[12];
    const float* tdw2   = (const float*)d_in[13];
    const float* tv2w1  = (const float*)d_in[14];
    const float* tv2w2  = (const float*)d_in[15];
    const float* Wr     = (const float*)d_in[16];
    const float* Wk     = (const float*)d_in[17];
    const float* Wv     = (const float*)d_in[18];
    const float* Wo     = (const float*)d_in[19];
    const float* lnw    = (const float*)d_in[20];
    const float* lnb    = (const float*)d_in[21];

    // ---- workspace layout (lifetimes aliased; 5 big slots S0..S4) ----
    char* ws = (char*)d_ws;
    const size_t BF = 2 * BTDc;
    size_t o = 0;
    auto take = [&](size_t bytes) { size_t r = o; o += (bytes + 255) & ~(size_t)255; return r; };
    unsigned short* WrT    = (unsigned short*)(ws + take((size_t)Dc * Dc * 2));
    unsigned short* WkT    = (unsigned short*)(ws + take((size_t)Dc * Dc * 2));
    unsigned short* WvT    = (unsigned short*)(ws + take((size_t)Dc * Dc * 2));
    unsigned short* WoT    = (unsigned short*)(ws + take((size_t)Dc * Dc * 2));
    unsigned short* w1T    = (unsigned short*)(ws + take((size_t)160 * Dc * 2));
    unsigned short* w2T    = (unsigned short*)(ws + take((size_t)Dc * 160 * 2));
    unsigned short* tdw1T  = (unsigned short*)(ws + take((size_t)64 * Dc * 2));
    unsigned short* tdw2T  = (unsigned short*)(ws + take((size_t)Dc * 64 * 2));
    unsigned short* tv2w1T = (unsigned short*)(ws + take((size_t)64 * Dc * 2));
    unsigned short* tv2w2T = (unsigned short*)(ws + take((size_t)Dc * 64 * 2));
    take(1 << 18);
    unsigned short* S0     = (unsigned short*)(ws + take(BF));   // XXX -> XR -> YA
    unsigned short* MIXPRE = (unsigned short*)(ws + take((size_t)BTc * 160 * 2));
    unsigned short* S1     = (unsigned short*)(ws + take(BF));   // XK -> Vb -> YLN
    unsigned short* WT     = (unsigned short*)(ws + take((size_t)BTc * 64 * 2));
    unsigned short* T1     = (unsigned short*)(ws + take((size_t)BTc * 64 * 2));
    unsigned short* S2     = (unsigned short*)(ws + take(BF));   // XV -> Rb
    unsigned short* S3     = (unsigned short*)(ws + take(BF));   // XW -> KDb -> V2
    unsigned short* S4     = (unsigned short*)(ws + take(BF));   // DX -> XV2 (in-place)
    float*          Pb     = (float*)(ws + take((size_t)128 * 32 * 4096 * 4));
    float*          ALb    = (float*)(ws + take((size_t)128 * 32 * 64 * 4));

    float* out_f     = (float*)d_out;
    float* shift_out = out_f + BTDc;
    float* wkv_out   = shift_out + (size_t)Bc * Dc;
    float* DEC       = out_f;   // f32 decay in d_out region (dead before final GEMM)
    float* PART      = Pb;      // split-K partials alias Pb (dead until wkv_summary / after wkv_y)

    unsigned short* XXX = S0;
    unsigned short* DX  = S4;
    unsigned short* XR  = S0;
    unsigned short* XK  = S1;
    unsigned short* XV  = S2;
    unsigned short* XW  = S3;
    unsigned short* XV2 = S4;
    unsigned short* KDb = S3;   // after WT gemm (XW dead)
    unsigned short* Vb  = S1;   // after KDb gemm (XK dead)
    unsigned short* Rb  = S2;   // after Vb gemm (XV dead)
    unsigned short* YA  = S0;   // after Rb gemm + wkv (XR dead)
    unsigned short* V2  = S3;   // after wkv (KDb dead)
    unsigned short* YLN = S1;   // after wkv (Vb dead)

    dim3 tb(256);
    transpose_cast<<<dim3(64, 64), tb, 0, stream>>>(Wr, WrT, Dc, Dc);
    transpose_cast<<<dim3(64, 64), tb, 0, stream>>>(Wk, WkT, Dc, Dc);
    transpose_cast<<<dim3(64, 64), tb, 0, stream>>>(Wv, WvT, Dc, Dc);
    transpose_cast<<<dim3(64, 64), tb, 0, stream>>>(Wo, WoT, Dc, Dc);
    transpose_cast<<<dim3(5, 64),  tb, 0, stream>>>(w1, w1T, Dc, 160);
    transpose_cast<<<dim3(64, 5),  tb, 0, stream>>>(w2, w2T, 160, Dc);
    transpose_cast<<<dim3(2, 64),  tb, 0, stream>>>(tdw1, tdw1T, Dc, 64);
    transpose_cast<<<dim3(64, 2),  tb, 0, stream>>>(tdw2, tdw2T, 64, Dc);
    transpose_cast<<<dim3(2, 64),  tb, 0, stream>>>(tv2w1, tv2w1T, Dc, 64);
    transpose_cast<<<dim3(64, 2),  tb, 0, stream>>>(tv2w2, tv2w2T, 64, Dc);

    prep_xxx<<<BTc, tb, 0, stream>>>(x, shift, tmx, XXX, DX);
    shift_copy<<<32, tb, 0, stream>>>(x, shift_out);

    EpiP ep{};
    // mixpre = tanh(xxx @ w1)  — split-K (KS=4), partials in PART (=Pb)
    gemm_splitk<<<dim3(2 * 4, 64), tb, 0, stream>>>(XXX, Dc, w1T, Dc, BTc, 160, 4, 512, PART);
    splitk_reduce_tanh<<<(BTc * 160 + 255) / 256, tb, 0, stream>>>(PART, 4, (size_t)BTc * 160, MIXPRE);

    // fused five mix GEMMs
    {
        Mix5P mp;
        mp.vec[0] = tmr; mp.vec[1] = tmk; mp.vec[2] = tmv; mp.vec[3] = tmw; mp.vec[4] = tmv2;
        mp.out[0] = XR;  mp.out[1] = XK;  mp.out[2] = XV;  mp.out[3] = XW;  mp.out[4] = XV2;
        mix5<<<dim3(16, 128), tb, 0, stream>>>(MIXPRE, w2T, x, DX, mp);
    }

    // decay path: WT = tanh(XW @ tdw1T) — split-K (KS=8)
    gemm_splitk<<<dim3(8, 64), tb, 0, stream>>>(XW, Dc, tdw1T, Dc, BTc, 64, 8, 256, PART);
    splitk_reduce_tanh<<<(BTc * 64 + 255) / 256, tb, 0, stream>>>(PART, 8, (size_t)BTc * 64, WT);
    ep = EpiP{}; ep.of = DEC; ep.vec = tdecay;
    launch_gemm(5, WT, 64, tdw2T, 64, BTc, Dc, 64, ep, stream);
    // k*(1-decay): XK -> KDb (S3; XW dead)
    ep = EpiP{}; ep.ob = KDb; ep.a0 = DEC;
    launch_gemm(4, XK, Dc, WkT, Dc, BTc, Dc, Dc, ep, stream);
    // v: XV -> Vb (S1; XK dead)
    ep = EpiP{}; ep.ob = Vb;
    launch_gemm(1, XV, Dc, WvT, Dc, BTc, Dc, Dc, ep, stream);
    // r: XR -> Rb (S2; XV dead)
    ep = EpiP{}; ep.ob = Rb;
    launch_gemm(1, XR, Dc, WrT, Dc, BTc, Dc, Dc, ep, stream);

    // chunked WKV scan (MFMA)
    wkv_summary<<<4096, tb, 0, stream>>>(KDb, Vb, DEC, Pb, ALb);
    wkv_states<<<2048, tb, 0, stream>>>(wkv_in, Pb, ALb, wkv_out);
    wkv_y<<<4096, tb, 0, stream>>>(Rb, KDb, Vb, DEC, Pb, YA);   // YA = S0 (XR dead)

    // v2 path: XV2 (S4) still live
    ep = EpiP{}; ep.ob = V2;                                     // V2 = S3 (KDb dead)
    launch_gemm(1, XV2, Dc, WvT, Dc, BTc, Dc, Dc, ep, stream);
    // T1 = tanh(XV2 @ tv2w1T) — split-K (KS=8), Pb dead after wkv_y
    gemm_splitk<<<dim3(8, 64), tb, 0, stream>>>(XV2, Dc, tv2w1T, Dc, BTc, 64, 8, 256, PART);
    splitk_reduce_tanh<<<(BTc * 64 + 255) / 256, tb, 0, stream>>>(PART, 8, (size_t)BTc * 64, T1);
    ep = EpiP{}; ep.ob = V2; ep.ab = V2;                         // in-place add
    launch_gemm(6, T1, 64, tv2w2T, 64, BTc, Dc, 64, ep, stream);

    // layernorm + output projection
    ln_fuse<<<BTc, tb, 0, stream>>>(YA, V2, lnw, lnb, YLN);      // YLN = S1 (Vb dead)
    ep = EpiP{}; ep.of = out_f;
    launch_gemm(0, YLN, Dc, WoT, Dc, BTc, Dc, Dc, ep, stream);
}

// Round 14
// 694.169 us; speedup vs baseline: 1.3188x; 1.0079x over previous
//
#include <hip/hip_runtime.h>
#include <hip/hip_bf16.h>

// ---------------- types / helpers ----------------
typedef __attribute__((ext_vector_type(8))) short   vshort8;   // 8 x bf16 bits (4 VGPRs)
typedef __attribute__((ext_vector_type(8))) unsigned short vushort8;
typedef __attribute__((ext_vector_type(4))) float   vfloat4;
typedef __attribute__((ext_vector_type(2))) float   vfloat2;

__device__ __forceinline__ float bf2f(unsigned short h) {
    union { unsigned u; float f; } x; x.u = ((unsigned)h) << 16; return x.f;
}
__device__ __forceinline__ unsigned short f2bf(float f) {
    union { float f; unsigned u; } x; x.f = f;
    unsigned r = x.u + 0x7fffu + ((x.u >> 16) & 1u);
    return (unsigned short)(r >> 16);
}
__device__ __forceinline__ void cp16_async(const void* g, void* l) {
    __builtin_amdgcn_global_load_lds(
        (const __attribute__((address_space(1))) unsigned int*)g,
        (__attribute__((address_space(3))) unsigned int*)l, 16, 0, 0);
}

#define FBAR() do { asm volatile("" ::: "memory"); __builtin_amdgcn_s_barrier(); asm volatile("" ::: "memory"); } while (0)

// ---------------- constants ----------------
#define Bc 4
#define Tc 2048
#define Dc 2048
#define Hc 32
#define KHc 64
#define BTc (Bc*Tc)              // 8192
#define BTDc ((size_t)BTc*Dc)    // 16,777,216
#define LP 72                    // LDS row stride (shorts) for scan kernels

struct EpiP {
    float* of;                 // f32 out
    unsigned short* ob;        // bf16 out
    const float* a0;           // aux f32 (decay)
    const float* a1;           // aux f32 (unused)
    const unsigned short* ab;  // aux bf16 (v2 partial)
    const float* vec;          // per-col vector (time_decay)
};

template<int EPI>
__device__ __forceinline__ void epi_store(float a, int row, int col, int N, const EpiP& ep)
{
    size_t o = (size_t)row * N + col;
    if (EPI == 0) {
        ep.of[o] = a;
    } else if (EPI == 1) {
        ep.ob[o] = f2bf(a);
    } else if (EPI == 2) {
        ep.ob[o] = f2bf(tanhf(a));
    } else if (EPI == 4) {                // KD: acc * (1 - decay)
        ep.ob[o] = f2bf(a * (1.f - ep.a0[o]));
    } else if (EPI == 5) {                // DECAY: exp(-exp(vec[col]+acc)) f32
        ep.of[o] = expf(-expf(ep.vec[col] + a));
    } else if (EPI == 6) {                // ADDB: acc + bf16 aux -> bf16
        ep.ob[o] = f2bf(a + bf2f(ep.ab[o]));
    }
}

// ============ GEMM-128 (m97-style, fully-drained), fallback for odd shapes ============
template<int EPI>
__global__ __launch_bounds__(256) void gemm_bt(
    const unsigned short* __restrict__ A, int lda,
    const unsigned short* __restrict__ BT, int ldbt,
    int M, int N, int K, EpiP ep)
{
    __shared__ unsigned short lA[128 * 32];
    __shared__ unsigned short lB[128 * 32];
    const int tid  = threadIdx.x;
    const int lane = tid & 63;
    const int w    = tid >> 6;
    const int mt   = blockIdx.y, nt = blockIdx.x;
    const int wm = (w >> 1) * 64, wn = (w & 1) * 64;
    const int frow = lane & 15, fk = (lane >> 4) * 8;

    vfloat4 acc[4][4];
#pragma unroll
    for (int i = 0; i < 4; i++)
#pragma unroll
        for (int j = 0; j < 4; j++) acc[i][j] = vfloat4{0.f, 0.f, 0.f, 0.f};

    for (int k0 = 0; k0 < K; k0 += 32) {
        __syncthreads();
#pragma unroll
        for (int p = 0; p < 2; p++) {
            int idx = p * 256 + tid;
            int row = idx >> 2, colh = (idx & 3) * 8;
            cp16_async(A + (size_t)(mt * 128 + row) * lda + k0 + colh, &lA[idx * 8]);
        }
#pragma unroll
        for (int p = 0; p < 2; p++) {
            int idx = p * 256 + tid;
            int row = idx >> 2, colh = (idx & 3) * 8;
            cp16_async(BT + (size_t)(nt * 128 + row) * ldbt + k0 + colh, &lB[idx * 8]);
        }
        __syncthreads();

        vshort8 af[4], bfr[4];
#pragma unroll
        for (int m = 0; m < 4; m++) af[m]  = *(const vshort8*)&lA[(wm + m * 16 + frow) * 32 + fk];
#pragma unroll
        for (int n = 0; n < 4; n++) bfr[n] = *(const vshort8*)&lB[(wn + n * 16 + frow) * 32 + fk];
#pragma unroll
        for (int m = 0; m < 4; m++)
#pragma unroll
            for (int n = 0; n < 4; n++)
                acc[m][n] = __builtin_amdgcn_mfma_f32_16x16x32_bf16(af[m], bfr[n], acc[m][n], 0, 0, 0);
    }

    const int crow0 = mt * 128 + wm, ccol0 = nt * 128 + wn;
#pragma unroll
    for (int m = 0; m < 4; m++)
#pragma unroll
        for (int n = 0; n < 4; n++) {
            int col = ccol0 + n * 16 + (lane & 15);
            if (col >= N) continue;
#pragma unroll
            for (int q = 0; q < 4; q++) {
                int row = crow0 + m * 16 + (lane >> 4) * 4 + q;
                epi_store<EPI>(acc[m][n][q], row, col, N, ep);
            }
        }
}

// ============ split-K tall-skinny GEMM: f32 partials, grid (ntN*KS, M/128) ============
__global__ __launch_bounds__(256) void gemm_splitk(
    const unsigned short* __restrict__ A, int lda,
    const unsigned short* __restrict__ BT, int ldbt,
    int M, int N, int KS, int Ksl, float* __restrict__ part)
{
    __shared__ unsigned short lA[128 * 32];
    __shared__ unsigned short lB[128 * 32];
    const int tid  = threadIdx.x;
    const int lane = tid & 63;
    const int w    = tid >> 6;
    const int nt = blockIdx.x / KS, ks = blockIdx.x % KS;
    const int mt = blockIdx.y;
    const int wm = (w >> 1) * 64, wn = (w & 1) * 64;
    const int frow = lane & 15, fk = (lane >> 4) * 8;

    vfloat4 acc[4][4];
#pragma unroll
    for (int i = 0; i < 4; i++)
#pragma unroll
        for (int j = 0; j < 4; j++) acc[i][j] = vfloat4{0.f, 0.f, 0.f, 0.f};

    const int kend = ks * Ksl + Ksl;
    for (int k0 = ks * Ksl; k0 < kend; k0 += 32) {
        __syncthreads();
#pragma unroll
        for (int p = 0; p < 2; p++) {
            int idx = p * 256 + tid;
            int row = idx >> 2, colh = (idx & 3) * 8;
            cp16_async(A + (size_t)(mt * 128 + row) * lda + k0 + colh, &lA[idx * 8]);
        }
#pragma unroll
        for (int p = 0; p < 2; p++) {
            int idx = p * 256 + tid;
            int row = idx >> 2, colh = (idx & 3) * 8;
            cp16_async(BT + (size_t)(nt * 128 + row) * ldbt + k0 + colh, &lB[idx * 8]);
        }
        __syncthreads();

        vshort8 af[4], bfr[4];
#pragma unroll
        for (int m = 0; m < 4; m++) af[m]  = *(const vshort8*)&lA[(wm + m * 16 + frow) * 32 + fk];
#pragma unroll
        for (int n = 0; n < 4; n++) bfr[n] = *(const vshort8*)&lB[(wn + n * 16 + frow) * 32 + fk];
#pragma unroll
        for (int m = 0; m < 4; m++)
#pragma unroll
            for (int n = 0; n < 4; n++)
                acc[m][n] = __builtin_amdgcn_mfma_f32_16x16x32_bf16(af[m], bfr[n], acc[m][n], 0, 0, 0);
    }

    const int crow0 = mt * 128 + wm, ccol0 = nt * 128 + wn;
    float* pbase = part + (size_t)ks * M * N;
#pragma unroll
    for (int m = 0; m < 4; m++)
#pragma unroll
        for (int n = 0; n < 4; n++) {
            int col = ccol0 + n * 16 + (lane & 15);
            if (col >= N) continue;
#pragma unroll
            for (int q = 0; q < 4; q++) {
                int row = crow0 + m * 16 + (lane >> 4) * 4 + q;
                pbase[(size_t)row * N + col] = acc[m][n][q];
            }
        }
}

__global__ __launch_bounds__(256) void splitk_reduce_tanh(
    const float* __restrict__ part, int KS, size_t MN, unsigned short* __restrict__ out)
{
    size_t i = (size_t)blockIdx.x * 256 + threadIdx.x;
    if (i >= MN) return;
    float s = 0.f;
    for (int k = 0; k < KS; k++) s += part[(size_t)k * MN + i];
    out[i] = f2bf(tanhf(s));
}

// ============ GEMM-256s: 256x256, BK=32, triple-buffer (for small K: 32/64) ============
template<int EPI>
__global__ __launch_bounds__(512, 1) void gemm256s(
    const unsigned short* __restrict__ A, int lda,
    const unsigned short* __restrict__ BT, int ldbt,
    int M, int N, int K, EpiP ep)
{
    __shared__ unsigned short sh[3 * 16384];   // 96 KB
    const int tid  = threadIdx.x;
    const int lane = tid & 63;
    const int w    = tid >> 6;

    int bid = blockIdx.y * gridDim.x + blockIdx.x;
    {
        int nwg = gridDim.x * gridDim.y;
        if ((nwg & 7) == 0) bid = (bid & 7) * (nwg >> 3) + (bid >> 3);
    }
    const int mt = bid / gridDim.x, nt = bid % gridDim.x;

    const int wm = (w >> 2) * 128, wn = (w & 3) * 64;
    const int frow = lane & 15;
    const int cswz = ((lane >> 4) ^ ((frow >> 1) & 3)) * 8;
    const int arow0 = mt * 256, brow0 = nt * 256;

    vfloat4 acc[8][4];
#pragma unroll
    for (int i = 0; i < 8; i++)
#pragma unroll
        for (int j = 0; j < 4; j++) acc[i][j] = vfloat4{0.f, 0.f, 0.f, 0.f};

    const int NT = K >> 5;

    auto stage = [&](int kt, int sbuf) {
        int k0 = kt << 5;
        unsigned short* dst = &sh[sbuf * 16384];
#pragma unroll
        for (int i = 0; i < 2; i++) {
            int idx = i * 512 + tid;
            int row = idx >> 2;
            int ch  = (idx & 3) ^ ((row >> 1) & 3);
            cp16_async(A + (size_t)(arow0 + row) * lda + k0 + ch * 8, dst + idx * 8);
        }
#pragma unroll
        for (int i = 0; i < 2; i++) {
            int idx = i * 512 + tid;
            int row = idx >> 2;
            int ch  = (idx & 3) ^ ((row >> 1) & 3);
            cp16_async(BT + (size_t)(brow0 + row) * ldbt + k0 + ch * 8, dst + 8192 + idx * 8);
        }
    };

    stage(0, 0);
    if (NT > 1) {
        stage(1, 1);
        asm volatile("s_waitcnt vmcnt(4)" ::: "memory");
    } else {
        asm volatile("s_waitcnt vmcnt(0)" ::: "memory");
    }
    __builtin_amdgcn_s_barrier();

    int buf = 0, sb = 2;
    for (int kt = 0; kt < NT; kt++) {
        if (kt + 2 < NT) stage(kt + 2, sb);
        const unsigned short* Ab = &sh[buf * 16384];
        const unsigned short* Bb = Ab + 8192;

        vshort8 af[8], bfv[4];
#pragma unroll
        for (int m = 0; m < 8; m++)
            af[m] = *(const vshort8*)&Ab[(wm + m * 16 + frow) * 32 + cswz];
#pragma unroll
        for (int n = 0; n < 4; n++)
            bfv[n] = *(const vshort8*)&Bb[(wn + n * 16 + frow) * 32 + cswz];

        __builtin_amdgcn_s_setprio(1);
#pragma unroll
        for (int m = 0; m < 8; m++)
#pragma unroll
            for (int n = 0; n < 4; n++)
                acc[m][n] = __builtin_amdgcn_mfma_f32_16x16x32_bf16(af[m], bfv[n], acc[m][n], 0, 0, 0);
        __builtin_amdgcn_s_setprio(0);

        if (kt + 1 < NT) {
            if (kt + 2 < NT) asm volatile("s_waitcnt vmcnt(4)" ::: "memory");
            else             asm volatile("s_waitcnt vmcnt(0)" ::: "memory");
            asm volatile("s_waitcnt lgkmcnt(0)" ::: "memory");
            __builtin_amdgcn_s_barrier();
        }
        buf = (buf == 2) ? 0 : buf + 1;
        sb  = (sb  == 2) ? 0 : sb  + 1;
    }

    const int crow0 = arow0 + wm, ccol0 = brow0 + wn;
#pragma unroll
    for (int m = 0; m < 8; m++)
#pragma unroll
        for (int n = 0; n < 4; n++) {
            int col = ccol0 + n * 16 + (lane & 15);
#pragma unroll
            for (int q = 0; q < 4; q++) {
                int row = crow0 + m * 16 + (lane >> 4) * 4 + q;
                epi_store<EPI>(acc[m][n][q], row, col, N, ep);
            }
        }
}

// ============ GEMM-256p8: 256x256, BK=64, 8-phase schedule, counted vmcnt(6) ============
// (round-9/12 variant — best measured: ~85 us/dispatch; FROZEN)
template<int EPI>
__global__ __launch_bounds__(512, 1) void gemm256p8(
    const unsigned short* __restrict__ A, int lda,
    const unsigned short* __restrict__ BT, int ldbt,
    int M, int N, int K, EpiP ep)
{
    __shared__ unsigned short sh[65536];   // 128 KB
    const int tid  = threadIdx.x;
    const int lane = tid & 63;
    const int w    = tid >> 6;

    int bid = blockIdx.y * gridDim.x + blockIdx.x;
    {
        int nwg = gridDim.x * gridDim.y;
        if ((nwg & 7) == 0) bid = (bid & 7) * (nwg >> 3) + (bid >> 3);
    }
    const int mt = bid / gridDim.x, nt = bid % gridDim.x;

    const int wm = (w >> 2) * 128, wn = (w & 3) * 64;
    const int frow = lane & 15;
    const int g    = lane >> 4;
    const int arow0 = mt * 256, brow0 = nt * 256;

    vfloat4 acc[8][4];
#pragma unroll
    for (int i = 0; i < 8; i++)
#pragma unroll
        for (int j = 0; j < 4; j++) acc[i][j] = vfloat4{0.f, 0.f, 0.f, 0.f};

    const int NT = K >> 6;   // even, >= 2 (router guarantees K % 128 == 0)

    auto stageA = [&](int kt, int p) {
        int k0 = kt << 6;
        unsigned short* dst = &sh[(kt & 1) * 32768];
#pragma unroll
        for (int l = 0; l < 2; l++) {
            int idx  = l * 512 + tid;
            int rl   = idx >> 3, slot = idx & 7;
            int rg   = (rl & 63) + p * 64 + ((rl >> 6) << 7);
            int ch   = slot ^ (rg & 7);
            cp16_async(A + (size_t)(arow0 + rg) * lda + k0 + ch * 8, dst + rg * 64 + slot * 8);
        }
    };
    auto stageB = [&](int kt, int p) {
        int k0 = kt << 6;
        unsigned short* dst = &sh[(kt & 1) * 32768 + 16384];
#pragma unroll
        for (int l = 0; l < 2; l++) {
            int idx  = l * 512 + tid;
            int rl   = idx >> 3, slot = idx & 7;
            int rg   = (rl & 31) + p * 32 + ((rl >> 5) << 6);
            int ch   = slot ^ (rg & 7);
            cp16_async(BT + (size_t)(brow0 + rg) * ldbt + k0 + ch * 8, dst + rg * 64 + slot * 8);
        }
    };

    vshort8 af[4][2], bf0[2][2], bf1[2][2];

    auto readA = [&](const unsigned short* Ab, int mh) {
#pragma unroll
        for (int mi = 0; mi < 4; mi++) {
            int r = wm + mh * 64 + mi * 16 + frow;
#pragma unroll
            for (int kk = 0; kk < 2; kk++)
                af[mi][kk] = *(const vshort8*)&Ab[r * 64 + (((kk * 4 + g) ^ (r & 7)) * 8)];
        }
    };
    auto readB = [&](const unsigned short* Bb, int nh, vshort8 (&bfr)[2][2]) {
#pragma unroll
        for (int ni = 0; ni < 2; ni++) {
            int r = wn + nh * 32 + ni * 16 + frow;
#pragma unroll
            for (int kk = 0; kk < 2; kk++)
                bfr[ni][kk] = *(const vshort8*)&Bb[r * 64 + (((kk * 4 + g) ^ (r & 7)) * 8)];
        }
    };
    auto domfma = [&](int mh, int nh, vshort8 (&bfr)[2][2]) {
        __builtin_amdgcn_s_setprio(1);
#pragma unroll
        for (int mi = 0; mi < 4; mi++)
#pragma unroll
            for (int ni = 0; ni < 2; ni++)
#pragma unroll
                for (int kk = 0; kk < 2; kk++)
                    acc[mh * 4 + mi][nh * 2 + ni] = __builtin_amdgcn_mfma_f32_16x16x32_bf16(
                        af[mi][kk], bfr[ni][kk], acc[mh * 4 + mi][nh * 2 + ni], 0, 0, 0);
        __builtin_amdgcn_s_setprio(0);
    };

    // prologue: T0 full + T1.Am0, T1.Bn1  (6 halves = 12 loads in flight)
    stageA(0, 0); stageB(0, 1); stageA(0, 1); stageB(0, 0);
    stageA(1, 0); stageB(1, 1);

    const unsigned short* A0 = sh;
    const unsigned short* B0 = sh + 16384;
    const unsigned short* A1 = sh + 32768;
    const unsigned short* B1 = sh + 49152;

    for (int i2 = 0; i2 < NT; i2 += 2) {
        const bool s2 = (i2 + 2 < NT), s3 = (i2 + 3 < NT);
        // ph0
        stageA(i2 + 1, 1);
        asm volatile("s_waitcnt vmcnt(6)" ::: "memory");
        FBAR();
        readA(A0, 0); readB(B0, 0, bf0);
        domfma(0, 0, bf0);
        asm volatile("s_waitcnt lgkmcnt(0)" ::: "memory");
        FBAR();
        // ph1
        stageB(i2 + 1, 0);
        FBAR();
        readB(B0, 1, bf1);
        domfma(0, 1, bf1);
        asm volatile("s_waitcnt lgkmcnt(0)" ::: "memory");
        FBAR();
        // ph2
        if (s2) stageA(i2 + 2, 0);
        FBAR();
        readA(A0, 1);
        domfma(1, 1, bf1);
        asm volatile("s_waitcnt lgkmcnt(0)" ::: "memory");
        FBAR();
        // ph3
        if (s2) stageB(i2 + 2, 1);
        FBAR();
        domfma(1, 0, bf0);
        FBAR();
        // ph4
        if (s2) {
            stageA(i2 + 2, 1);
            asm volatile("s_waitcnt vmcnt(6)" ::: "memory");
        } else {
            asm volatile("s_waitcnt vmcnt(0)" ::: "memory");
        }
        FBAR();
        readA(A1, 0); readB(B1, 0, bf0);
        domfma(0, 0, bf0);
        asm volatile("s_waitcnt lgkmcnt(0)" ::: "memory");
        FBAR();
        // ph5
        if (s2) stageB(i2 + 2, 0);
        FBAR();
        readB(B1, 1, bf1);
        domfma(0, 1, bf1);
        asm volatile("s_waitcnt lgkmcnt(0)" ::: "memory");
        FBAR();
        // ph6
        if (s3) stageA(i2 + 3, 0);
        FBAR();
        readA(A1, 1);
        domfma(1, 1, bf1);
        asm volatile("s_waitcnt lgkmcnt(0)" ::: "memory");
        FBAR();
        // ph7
        if (s3) stageB(i2 + 3, 1);
        FBAR();
        domfma(1, 0, bf0);
        FBAR();
    }

    const int crow0 = arow0 + wm, ccol0 = brow0 + wn;
#pragma unroll
    for (int m = 0; m < 8; m++)
#pragma unroll
        for (int n = 0; n < 4; n++) {
            int col = ccol0 + n * 16 + (lane & 15);
#pragma unroll
            for (int q = 0; q < 4; q++) {
                int row = crow0 + m * 16 + (lane >> 4) * 4 + q;
                epi_store<EPI>(acc[m][n][q], row, col, N, ep);
            }
        }
}

// ============ mix5: fused five mix GEMMs (K=32), x/DX read once ============
struct Mix5P {
    const float* vec[5];
    unsigned short* out[5];
};

__global__ __launch_bounds__(256) void mix5(
    const unsigned short* __restrict__ MP,   // MIXPRE [BTc][160]
    const unsigned short* __restrict__ W2T,  // [Dc][160]
    const float* __restrict__ x,
    const unsigned short* __restrict__ DXb,
    Mix5P p)
{
    __shared__ unsigned short lA[64 * 32];    // 4 KB
    __shared__ unsigned short lB[128 * 32];   // 8 KB
    const int tid = threadIdx.x, lane = tid & 63, w = tid >> 6;
    const int mt = blockIdx.y, nt = blockIdx.x;   // grid (16, 128)
    const int wm = (w >> 1) * 32, wn = (w & 1) * 64;
    const int frow = lane & 15, fk = (lane >> 4) * 8;
    const int row0 = mt * 64, col0 = nt * 128;

    float xr[8][4], dxr[8][4];
#pragma unroll
    for (int mi = 0; mi < 2; mi++)
#pragma unroll
        for (int q = 0; q < 4; q++) {
            int rl = wm + mi * 16 + (lane >> 4) * 4 + q;
            size_t rb = (size_t)(row0 + rl) * Dc + col0;
#pragma unroll
            for (int ni = 0; ni < 4; ni++) {
                int cl = wn + ni * 16 + (lane & 15);
                xr[mi * 4 + q][ni]  = x[rb + cl];
                dxr[mi * 4 + q][ni] = bf2f(DXb[rb + cl]);
            }
        }

    for (int f = 0; f < 5; f++) {
        __syncthreads();
        {
            int row = tid >> 2, ch = tid & 3;
            cp16_async(MP + (size_t)(row0 + row) * 160 + f * 32 + ch * 8, &lA[(row * 4 + ch) * 8]);
        }
#pragma unroll
        for (int p2 = 0; p2 < 2; p2++) {
            int idx = p2 * 256 + tid;
            int row = idx >> 2, ch = idx & 3;
            cp16_async(W2T + (size_t)(col0 + row) * 160 + f * 32 + ch * 8, &lB[(row * 4 + ch) * 8]);
        }
        __syncthreads();

        vshort8 af[2], bfr[4];
#pragma unroll
        for (int mi = 0; mi < 2; mi++) af[mi]  = *(const vshort8*)&lA[(wm + mi * 16 + frow) * 32 + fk];
#pragma unroll
        for (int ni = 0; ni < 4; ni++) bfr[ni] = *(const vshort8*)&lB[(wn + ni * 16 + frow) * 32 + fk];

        vfloat4 acc[2][4];
#pragma unroll
        for (int mi = 0; mi < 2; mi++)
#pragma unroll
            for (int ni = 0; ni < 4; ni++) {
                acc[mi][ni] = vfloat4{0.f, 0.f, 0.f, 0.f};
                acc[mi][ni] = __builtin_amdgcn_mfma_f32_16x16x32_bf16(af[mi], bfr[ni], acc[mi][ni], 0, 0, 0);
            }

        const float* vec = p.vec[f];
        unsigned short* ob = p.out[f];
        float vc[4];
#pragma unroll
        for (int ni = 0; ni < 4; ni++) vc[ni] = vec[col0 + wn + ni * 16 + (lane & 15)];
#pragma unroll
        for (int mi = 0; mi < 2; mi++)
#pragma unroll
            for (int q = 0; q < 4; q++) {
                int rl = wm + mi * 16 + (lane >> 4) * 4 + q;
                size_t rb = (size_t)(row0 + rl) * Dc + col0;
#pragma unroll
                for (int ni = 0; ni < 4; ni++) {
                    int cl = wn + ni * 16 + (lane & 15);
                    ob[rb + cl] = f2bf(xr[mi * 4 + q][ni] + dxr[mi * 4 + q][ni] * (vc[ni] + acc[mi][ni][q]));
                }
            }
    }
}

// ---------------- prep: xxx = x + dx*time_maa_x, dx = xprev - x  -> bf16 ----------------
__global__ __launch_bounds__(256) void prep_xxx(
    const float* __restrict__ x, const float* __restrict__ shift_in,
    const float* __restrict__ tmx, unsigned short* __restrict__ xxx,
    unsigned short* __restrict__ dxb)
{
    int row = blockIdx.x, tid = threadIdx.x;
    int t = row & (Tc - 1), b = row >> 11;
    size_t base = (size_t)row * Dc + tid * 8;
    const float* xp = t ? x + base - Dc : shift_in + (size_t)b * Dc + tid * 8;
    vushort8 o, dxo;
#pragma unroll
    for (int j = 0; j < 8; j++) {
        float xv = x[base + j];
        float dx = xp[j] - xv;
        o[j]   = f2bf(xv + dx * tmx[tid * 8 + j]);
        dxo[j] = f2bf(dx);
    }
    *(vushort8*)(xxx + base) = o;
    *(vushort8*)(dxb + base) = dxo;
}

__global__ __launch_bounds__(256) void shift_copy(const float* __restrict__ x, float* __restrict__ out)
{
    int i = blockIdx.x * 256 + threadIdx.x;   // B*D = 8192
    int b = i >> 11, d = i & (Dc - 1);
    out[i] = x[((size_t)b * Tc + (Tc - 1)) * Dc + d];
}

// ---------------- transpose + cast f32 -> bf16 : out[C][R] = in[R][C] ----------------
__global__ __launch_bounds__(256) void transpose_cast(
    const float* __restrict__ in, unsigned short* __restrict__ out, int R, int C)
{
    __shared__ float tile[32][33];
    int ct = blockIdx.x, rt = blockIdx.y;
    int lx = threadIdx.x & 31, ly = threadIdx.x >> 5;
#pragma unroll
    for (int i = 0; i < 4; i++)
        tile[ly + i * 8][lx] = in[(size_t)(rt * 32 + ly + i * 8) * C + ct * 32 + lx];
    __syncthreads();
#pragma unroll
    for (int i = 0; i < 4; i++)
        out[(size_t)(ct * 32 + ly + i * 8) * R + rt * 32 + lx] = f2bf(tile[lx][ly + i * 8]);
}

// merged 4x DxD transpose (blockIdx.z selects tensor)
struct T4 { const float* in[4]; unsigned short* out[4]; };
__global__ __launch_bounds__(256) void transpose_cast4(T4 t4)
{
    __shared__ float tile[32][33];
    const float* in = t4.in[blockIdx.z];
    unsigned short* out = t4.out[blockIdx.z];
    int ct = blockIdx.x, rt = blockIdx.y;
    int lx = threadIdx.x & 31, ly = threadIdx.x >> 5;
#pragma unroll
    for (int i = 0; i < 4; i++)
        tile[ly + i * 8][lx] = in[(size_t)(rt * 32 + ly + i * 8) * Dc + ct * 32 + lx];
    __syncthreads();
#pragma unroll
    for (int i = 0; i < 4; i++)
        out[(size_t)(ct * 32 + ly + i * 8) * Dc + rt * 32 + lx] = f2bf(tile[lx][ly + i * 8]);
}

// =========== WKV chunked scan as chunked linear attention (MFMA) ===========
__global__ __launch_bounds__(256) void wkv_summary(
    const unsigned short* __restrict__ kd, const unsigned short* __restrict__ vv,
    const float* __restrict__ dec, float* __restrict__ P, float* __restrict__ aL)
{
    __shared__ unsigned short kb2T[64][LP];
    __shared__ unsigned short vT[64][LP];
    __shared__ float gp[4][64];
    const int blk = blockIdx.x;
    const int c = blk & 31, bh = blk >> 5, b = bh >> 5, h = bh & 31;
    const int tid = threadIdx.x;
    const size_t rowbase = ((size_t)(b * Tc + c * 64)) * Dc + h * 64;

    {
        int t = tid >> 2, q = tid & 3;
        const unsigned short* src = vv + rowbase + (size_t)t * Dc + q * 16;
        vushort8 a = *(const vushort8*)src;
        vushort8 b2 = *(const vushort8*)(src + 8);
#pragma unroll
        for (int j = 0; j < 8; j++) vT[q * 16 + j][t] = a[j];
#pragma unroll
        for (int j = 0; j < 8; j++) vT[q * 16 + 8 + j][t] = b2[j];
    }

    const int k = tid & 63, grp = tid >> 6;
    const float* decp = dec + rowbase + k;
    const unsigned short* kp = kd + rowbase + k;
    float suf_local[16];
    float pgrp = 1.f;
#pragma unroll
    for (int i = 15; i >= 0; i--) {
        int t = grp * 16 + i;
        float d = decp[(size_t)t * Dc];
        suf_local[i] = pgrp;
        pgrp *= d;
    }
    gp[grp][k] = pgrp;
    __syncthreads();
    float suff = 1.f;
#pragma unroll
    for (int g2 = 0; g2 < 4; g2++) if (g2 > grp) suff *= gp[g2][k];
    if (grp == 0) aL[(size_t)blk * 64 + k] = pgrp * suff;
    {
        vushort8 p0, p1;
#pragma unroll
        for (int i = 0; i < 8; i++) {
            int t = grp * 16 + i;
            p0[i] = f2bf(bf2f(kp[(size_t)t * Dc]) * (suf_local[i] * suff));
        }
#pragma unroll
        for (int i = 0; i < 8; i++) {
            int t = grp * 16 + 8 + i;
            p1[i] = f2bf(bf2f(kp[(size_t)t * Dc]) * (suf_local[8 + i] * suff));
        }
        *(vushort8*)&kb2T[k][grp * 16] = p0;
        *(vushort8*)&kb2T[k][grp * 16 + 8] = p1;
    }
    __syncthreads();

    const int lane = tid & 63, w = tid >> 6;
    const int wm = (w >> 1) * 32, wn = (w & 1) * 32;
    const int frow = lane & 15, fk = (lane >> 4) * 8;
    vfloat4 acc[2][2];
#pragma unroll
    for (int m = 0; m < 2; m++)
#pragma unroll
        for (int n = 0; n < 2; n++) acc[m][n] = vfloat4{0.f, 0.f, 0.f, 0.f};
#pragma unroll
    for (int kk = 0; kk < 2; kk++) {
        vshort8 af[2], bfr[2];
#pragma unroll
        for (int m = 0; m < 2; m++) af[m]  = *(const vshort8*)&kb2T[wm + m * 16 + frow][kk * 32 + fk];
#pragma unroll
        for (int n = 0; n < 2; n++) bfr[n] = *(const vshort8*)&vT[wn + n * 16 + frow][kk * 32 + fk];
#pragma unroll
        for (int m = 0; m < 2; m++)
#pragma unroll
            for (int n = 0; n < 2; n++)
                acc[m][n] = __builtin_amdgcn_mfma_f32_16x16x32_bf16(af[m], bfr[n], acc[m][n], 0, 0, 0);
    }
    float* Pp = P + (size_t)blk * 4096;
#pragma unroll
    for (int m = 0; m < 2; m++)
#pragma unroll
        for (int n = 0; n < 2; n++) {
            int col = wn + n * 16 + (lane & 15);
#pragma unroll
            for (int q = 0; q < 4; q++) {
                int row = wm + m * 16 + (lane >> 4) * 4 + q;
                Pp[row * 64 + col] = acc[m][n][q];
            }
        }
}

__global__ __launch_bounds__(256) void wkv_states(
    const float* __restrict__ wkv_in, float* __restrict__ P /* -> Sb */,
    const float* __restrict__ aL, float* __restrict__ wkv_out)
{
    int idx = blockIdx.x * 256 + threadIdx.x;   // 524288
    int bh = idx >> 12, kv = idx & 4095, k = kv >> 6;
    float S = wkv_in[idx];
    for (int c = 0; c < 32; c++) {
        size_t off = (size_t)bh * 32 + c;
        float p = P[off * 4096 + kv];
        float a = aL[off * 64 + k];
        P[off * 4096 + kv] = S;   // Sb[c]
        S = S * a + p;
    }
    wkv_out[idx] = S;
}

__global__ __launch_bounds__(256) void wkv_y(
    const unsigned short* __restrict__ rr, const unsigned short* __restrict__ kd,
    const unsigned short* __restrict__ vv, const float* __restrict__ dec,
    const float* __restrict__ Sb, unsigned short* __restrict__ ya)
{
    __shared__ unsigned short rA[64][LP];
    __shared__ unsigned short kbL[64][LP];
    __shared__ unsigned short vT[64][LP];
    __shared__ unsigned short SbT[64][LP];
    __shared__ unsigned short QiM[64][LP];
    __shared__ float gp[4][64];
    const int blk = blockIdx.x;
    const int c = blk & 31, bh = blk >> 5, b = bh >> 5, h = bh & 31;
    const int tid = threadIdx.x;
    const size_t rowbase = ((size_t)(b * Tc + c * 64)) * Dc + h * 64;

    {
        int t = tid >> 2, q = tid & 3;
        const unsigned short* src = vv + rowbase + (size_t)t * Dc + q * 16;
        vushort8 a = *(const vushort8*)src;
        vushort8 b2 = *(const vushort8*)(src + 8);
#pragma unroll
        for (int j = 0; j < 8; j++) vT[q * 16 + j][t] = a[j];
#pragma unroll
        for (int j = 0; j < 8; j++) vT[q * 16 + 8 + j][t] = b2[j];
        const float* sp = Sb + (size_t)blk * 4096 + t * 64 + q * 16;
#pragma unroll
        for (int j = 0; j < 16; j++) SbT[q * 16 + j][t] = f2bf(sp[j]);
    }

    const int k = tid & 63, grp = tid >> 6;
    const float* decp = dec + rowbase + k;
    const unsigned short* rp = rr + rowbase + k;
    const unsigned short* kp = kd + rowbase + k;
    float pref_local[16];
    float pgrp = 1.f;
#pragma unroll
    for (int i = 0; i < 16; i++) {
        int t = grp * 16 + i;
        float d = decp[(size_t)t * Dc];
        pref_local[i] = pgrp;
        pgrp *= d;
    }
    gp[grp][k] = pgrp;
    __syncthreads();
    float pref = 1.f;
#pragma unroll
    for (int g2 = 0; g2 < 4; g2++) if (g2 < grp) pref *= gp[g2][k];
#pragma unroll
    for (int i = 0; i < 16; i++) {
        int t = grp * 16 + i;
        float Aex  = pref * pref_local[i];
        float Ainc = pref * (i < 15 ? pref_local[i + 1] : pgrp);
        rA[t][k]  = f2bf(bf2f(rp[(size_t)t * Dc]) * Aex);
        kbL[t][k] = f2bf(bf2f(kp[(size_t)t * Dc]) / Ainc);
    }
    __syncthreads();

    const int lane = tid & 63, w = tid >> 6;
    const int wm = (w >> 1) * 32, wn = (w & 1) * 32;
    const int frow = lane & 15, fk = (lane >> 4) * 8;

    vfloat4 acc[2][2];
#pragma unroll
    for (int m = 0; m < 2; m++)
#pragma unroll
        for (int n = 0; n < 2; n++) acc[m][n] = vfloat4{0.f, 0.f, 0.f, 0.f};
#pragma unroll
    for (int kk = 0; kk < 2; kk++) {
        vshort8 af[2], bfr[2];
#pragma unroll
        for (int m = 0; m < 2; m++) af[m]  = *(const vshort8*)&rA[wm + m * 16 + frow][kk * 32 + fk];
#pragma unroll
        for (int n = 0; n < 2; n++) bfr[n] = *(const vshort8*)&kbL[wn + n * 16 + frow][kk * 32 + fk];
#pragma unroll
        for (int m = 0; m < 2; m++)
#pragma unroll
            for (int n = 0; n < 2; n++)
                acc[m][n] = __builtin_amdgcn_mfma_f32_16x16x32_bf16(af[m], bfr[n], acc[m][n], 0, 0, 0);
    }
#pragma unroll
    for (int m = 0; m < 2; m++)
#pragma unroll
        for (int n = 0; n < 2; n++) {
            int s = wn + n * 16 + (lane & 15);
#pragma unroll
            for (int q = 0; q < 4; q++) {
                int t = wm + m * 16 + (lane >> 4) * 4 + q;
                QiM[t][s] = f2bf(s < t ? acc[m][n][q] : 0.f);
            }
        }
    __syncthreads();

#pragma unroll
    for (int m = 0; m < 2; m++)
#pragma unroll
        for (int n = 0; n < 2; n++) acc[m][n] = vfloat4{0.f, 0.f, 0.f, 0.f};
#pragma unroll
    for (int kk = 0; kk < 2; kk++) {
        vshort8 af[2], bfr[2];
#pragma unroll
        for (int m = 0; m < 2; m++) af[m]  = *(const vshort8*)&QiM[wm + m * 16 + frow][kk * 32 + fk];
#pragma unroll
        for (int n = 0; n < 2; n++) bfr[n] = *(const vshort8*)&vT[wn + n * 16 + frow][kk * 32 + fk];
#pragma unroll
        for (int m = 0; m < 2; m++)
#pragma unroll
            for (int n = 0; n < 2; n++)
                acc[m][n] = __builtin_amdgcn_mfma_f32_16x16x32_bf16(af[m], bfr[n], acc[m][n], 0, 0, 0);
    }
#pragma unroll
    for (int kk = 0; kk < 2; kk++) {
        vshort8 af[2], bfr[2];
#pragma unroll
        for (int m = 0; m < 2; m++) af[m]  = *(const vshort8*)&rA[wm + m * 16 + frow][kk * 32 + fk];
#pragma unroll
        for (int n = 0; n < 2; n++) bfr[n] = *(const vshort8*)&SbT[wn + n * 16 + frow][kk * 32 + fk];
#pragma unroll
        for (int m = 0; m < 2; m++)
#pragma unroll
            for (int n = 0; n < 2; n++)
                acc[m][n] = __builtin_amdgcn_mfma_f32_16x16x32_bf16(af[m], bfr[n], acc[m][n], 0, 0, 0);
    }
#pragma unroll
    for (int m = 0; m < 2; m++)
#pragma unroll
        for (int n = 0; n < 2; n++) {
            int col = wn + n * 16 + (lane & 15);
#pragma unroll
            for (int q = 0; q < 4; q++) {
                int t = wm + m * 16 + (lane >> 4) * 4 + q;
                ya[rowbase + (size_t)t * Dc + col] = f2bf(acc[m][n][q]);
            }
        }
}

// ---------------- LayerNorm(ya + v2) -> bf16 ----------------
__global__ __launch_bounds__(256) void ln_fuse(
    const unsigned short* __restrict__ ya, const unsigned short* __restrict__ v2,
    const float* __restrict__ lnw, const float* __restrict__ lnb,
    unsigned short* __restrict__ out)
{
    int row = blockIdx.x, tid = threadIdx.x;
    size_t base = (size_t)row * Dc + tid * 8;
    vushort8 a = *(const vushort8*)(ya + base);
    vushort8 b = *(const vushort8*)(v2 + base);
    float v[8]; float s = 0.f, s2 = 0.f;
#pragma unroll
    for (int j = 0; j < 8; j++) { float t = bf2f(a[j]) + bf2f(b[j]); v[j] = t; s += t; s2 += t * t; }
#pragma unroll
    for (int o = 32; o; o >>= 1) { s += __shfl_xor(s, o); s2 += __shfl_xor(s2, o); }
    __shared__ float rs[8];
    int w = tid >> 6;
    if ((tid & 63) == 0) { rs[w] = s; rs[w + 4] = s2; }
    __syncthreads();
    s  = rs[0] + rs[1] + rs[2] + rs[3];
    s2 = rs[4] + rs[5] + rs[6] + rs[7];
    float mu = s * (1.f / Dc);
    float var = s2 * (1.f / Dc) - mu * mu;
    float inv = rsqrtf(var + 1e-5f);
#pragma unroll
    for (int j = 0; j < 8; j++) {
        int d = tid * 8 + j;
        out[base + j] = f2bf((v[j] - mu) * inv * lnw[d] + lnb[d]);
    }
}

// ---------------- host ----------------
static inline void launch_gemm(int epi, const unsigned short* A, int lda,
                               const unsigned short* BT, int ldbt,
                               int M, int N, int K, EpiP ep, hipStream_t s)
{
    if ((M & 255) == 0 && (N & 255) == 0) {
        if ((K & 127) == 0 && K >= 128 && (epi == 0 || epi == 1 || epi == 4)) {
            dim3 g(N / 256, M / 256), b(512);
            switch (epi) {
                case 0: gemm256p8<0><<<g, b, 0, s>>>(A, lda, BT, ldbt, M, N, K, ep); break;
                case 1: gemm256p8<1><<<g, b, 0, s>>>(A, lda, BT, ldbt, M, N, K, ep); break;
                case 4: gemm256p8<4><<<g, b, 0, s>>>(A, lda, BT, ldbt, M, N, K, ep); break;
            }
            return;
        }
        if ((K & 31) == 0) {
            dim3 g(N / 256, M / 256), b(512);
            switch (epi) {
                case 0: gemm256s<0><<<g, b, 0, s>>>(A, lda, BT, ldbt, M, N, K, ep); break;
                case 1: gemm256s<1><<<g, b, 0, s>>>(A, lda, BT, ldbt, M, N, K, ep); break;
                case 2: gemm256s<2><<<g, b, 0, s>>>(A, lda, BT, ldbt, M, N, K, ep); break;
                case 4: gemm256s<4><<<g, b, 0, s>>>(A, lda, BT, ldbt, M, N, K, ep); break;
                case 5: gemm256s<5><<<g, b, 0, s>>>(A, lda, BT, ldbt, M, N, K, ep); break;
                case 6: gemm256s<6><<<g, b, 0, s>>>(A, lda, BT, ldbt, M, N, K, ep); break;
            }
            return;
        }
    }
    dim3 g((N + 127) / 128, M / 128), b(256);
    switch (epi) {
        case 0: gemm_bt<0><<<g, b, 0, s>>>(A, lda, BT, ldbt, M, N, K, ep); break;
        case 1: gemm_bt<1><<<g, b, 0, s>>>(A, lda, BT, ldbt, M, N, K, ep); break;
        case 2: gemm_bt<2><<<g, b, 0, s>>>(A, lda, BT, ldbt, M, N, K, ep); break;
        case 4: gemm_bt<4><<<g, b, 0, s>>>(A, lda, BT, ldbt, M, N, K, ep); break;
        case 5: gemm_bt<5><<<g, b, 0, s>>>(A, lda, BT, ldbt, M, N, K, ep); break;
        case 6: gemm_bt<6><<<g, b, 0, s>>>(A, lda, BT, ldbt, M, N, K, ep); break;
    }
}

extern "C" void kernel_launch(void* const* d_in, const int* in_sizes, int n_in,
                              void* d_out, int out_size, void* d_ws, size_t ws_size,
                              hipStream_t stream)
{
    (void)in_sizes; (void)n_in; (void)out_size; (void)ws_size;
    const float* x      = (const float*)d_in[0];
    const float* shift  = (const float*)d_in[1];
    const float* wkv_in = (const float*)d_in[2];
    const float* tmx    = (const float*)d_in[3];
    const float* tmr    = (const float*)d_in[4];
    const float* tmk    = (const float*)d_in[5];
    const float* tmv    = (const float*)d_in[6];
    const float* tmw    = (const float*)d_in[7];
    const float* tmv2   = (const float*)d_in[8];
    const float* w1     = (const float*)d_in[9];
    const float* w2     = (const float*)d_in[10];
    const float* tdecay = (const float*)d_in[11];
    const float* tdw1   = (const float*)d_in[12];
    const float* tdw2   = (const float*)d_in[13];
    const float* tv2w1  = (const float*)d_in[14];
    const float* tv2w2  = (const float*)d_in[15];
    const float* Wr     = (const float*)d_in[16];
    const float* Wk     = (const float*)d_in[17];
    const float* Wv     = (const float*)d_in[18];
    const float* Wo     = (const float*)d_in[19];
    const float* lnw    = (const float*)d_in[20];
    const float* lnb    = (const float*)d_in[21];

    // ---- workspace layout (lifetimes aliased; 5 big slots S0..S4) ----
    char* ws = (char*)d_ws;
    const size_t BF = 2 * BTDc;
    size_t o = 0;
    auto take = [&](size_t bytes) { size_t r = o; o += (bytes + 255) & ~(size_t)255; return r; };
    unsigned short* WrT    = (unsigned short*)(ws + take((size_t)Dc * Dc * 2));
    unsigned short* WkT    = (unsigned short*)(ws + take((size_t)Dc * Dc * 2));
    unsigned short* WvT    = (unsigned short*)(ws + take((size_t)Dc * Dc * 2));
    unsigned short* WoT    = (unsigned short*)(ws + take((size_t)Dc * Dc * 2));
    unsigned short* w1T    = (unsigned short*)(ws + take((size_t)160 * Dc * 2));
    unsigned short* w2T    = (unsigned short*)(ws + take((size_t)Dc * 160 * 2));
    unsigned short* tdw1T  = (unsigned short*)(ws + take((size_t)64 * Dc * 2));
    unsigned short* tdw2T  = (unsigned short*)(ws + take((size_t)Dc * 64 * 2));
    unsigned short* tv2w1T = (unsigned short*)(ws + take((size_t)64 * Dc * 2));
    unsigned short* tv2w2T = (unsigned short*)(ws + take((size_t)Dc * 64 * 2));
    take(1 << 18);
    unsigned short* S0     = (unsigned short*)(ws + take(BF));   // XXX -> XR -> YA
    unsigned short* MIXPRE = (unsigned short*)(ws + take((size_t)BTc * 160 * 2));
    unsigned short* S1     = (unsigned short*)(ws + take(BF));   // XK -> Vb -> YLN
    unsigned short* WT     = (unsigned short*)(ws + take((size_t)BTc * 64 * 2));
    unsigned short* T1     = (unsigned short*)(ws + take((size_t)BTc * 64 * 2));
    unsigned short* S2     = (unsigned short*)(ws + take(BF));   // XV -> Rb
    unsigned short* S3     = (unsigned short*)(ws + take(BF));   // XW -> KDb -> V2
    unsigned short* S4     = (unsigned short*)(ws + take(BF));   // DX -> XV2 (in-place)
    float*          Pb     = (float*)(ws + take((size_t)128 * 32 * 4096 * 4));
    float*          ALb    = (float*)(ws + take((size_t)128 * 32 * 64 * 4));

    float* out_f     = (float*)d_out;
    float* shift_out = out_f + BTDc;
    float* wkv_out   = shift_out + (size_t)Bc * Dc;
    float* DEC       = out_f;   // f32 decay in d_out region (dead before final GEMM)
    float* PART      = Pb;      // split-K partials alias Pb

    unsigned short* XXX = S0;
    unsigned short* DX  = S4;
    unsigned short* XR  = S0;
    unsigned short* XK  = S1;
    unsigned short* XV  = S2;
    unsigned short* XW  = S3;
    unsigned short* XV2 = S4;
    unsigned short* KDb = S3;   // after WT gemm (XW dead)
    unsigned short* Vb  = S1;   // after KDb gemm (XK dead)
    unsigned short* Rb  = S2;   // after Vb gemm (XV dead)
    unsigned short* YA  = S0;   // after Rb gemm + wkv (XR dead)
    unsigned short* V2  = S3;   // after wkv (KDb dead)
    unsigned short* YLN = S1;   // after wkv (Vb dead)

    dim3 tb(256);
    {
        T4 t4;
        t4.in[0] = Wr; t4.in[1] = Wk; t4.in[2] = Wv; t4.in[3] = Wo;
        t4.out[0] = WrT; t4.out[1] = WkT; t4.out[2] = WvT; t4.out[3] = WoT;
        transpose_cast4<<<dim3(64, 64, 4), tb, 0, stream>>>(t4);
    }
    transpose_cast<<<dim3(5, 64),  tb, 0, stream>>>(w1, w1T, Dc, 160);
    transpose_cast<<<dim3(64, 5),  tb, 0, stream>>>(w2, w2T, 160, Dc);
    transpose_cast<<<dim3(2, 64),  tb, 0, stream>>>(tdw1, tdw1T, Dc, 64);
    transpose_cast<<<dim3(64, 2),  tb, 0, stream>>>(tdw2, tdw2T, 64, Dc);
    transpose_cast<<<dim3(2, 64),  tb, 0, stream>>>(tv2w1, tv2w1T, Dc, 64);
    transpose_cast<<<dim3(64, 2),  tb, 0, stream>>>(tv2w2, tv2w2T, 64, Dc);

    prep_xxx<<<BTc, tb, 0, stream>>>(x, shift, tmx, XXX, DX);
    shift_copy<<<32, tb, 0, stream>>>(x, shift_out);

    EpiP ep{};
    // mixpre = tanh(xxx @ w1)  — split-K (KS=4), partials in PART (=Pb)
    gemm_splitk<<<dim3(2 * 4, 64), tb, 0, stream>>>(XXX, Dc, w1T, Dc, BTc, 160, 4, 512, PART);
    splitk_reduce_tanh<<<(BTc * 160 + 255) / 256, tb, 0, stream>>>(PART, 4, (size_t)BTc * 160, MIXPRE);

    // fused five mix GEMMs
    {
        Mix5P mp;
        mp.vec[0] = tmr; mp.vec[1] = tmk; mp.vec[2] = tmv; mp.vec[3] = tmw; mp.vec[4] = tmv2;
        mp.out[0] = XR;  mp.out[1] = XK;  mp.out[2] = XV;  mp.out[3] = XW;  mp.out[4] = XV2;
        mix5<<<dim3(16, 128), tb, 0, stream>>>(MIXPRE, w2T, x, DX, mp);
    }

    // decay path: WT = tanh(XW @ tdw1T) — split-K (KS=8)
    gemm_splitk<<<dim3(8, 64), tb, 0, stream>>>(XW, Dc, tdw1T, Dc, BTc, 64, 8, 256, PART);
    splitk_reduce_tanh<<<(BTc * 64 + 255) / 256, tb, 0, stream>>>(PART, 8, (size_t)BTc * 64, WT);
    ep = EpiP{}; ep.of = DEC; ep.vec = tdecay;
    launch_gemm(5, WT, 64, tdw2T, 64, BTc, Dc, 64, ep, stream);
    // k*(1-decay): XK -> KDb (S3; XW dead)
    ep = EpiP{}; ep.ob = KDb; ep.a0 = DEC;
    launch_gemm(4, XK, Dc, WkT, Dc, BTc, Dc, Dc, ep, stream);
    // v: XV -> Vb (S1; XK dead)
    ep = EpiP{}; ep.ob = Vb;
    launch_gemm(1, XV, Dc, WvT, Dc, BTc, Dc, Dc, ep, stream);
    // r: XR -> Rb (S2; XV dead)
    ep = EpiP{}; ep.ob = Rb;
    launch_gemm(1, XR, Dc, WrT, Dc, BTc, Dc, Dc, ep, stream);

    // chunked WKV scan (MFMA)
    wkv_summary<<<4096, tb, 0, stream>>>(KDb, Vb, DEC, Pb, ALb);
    wkv_states<<<2048, tb, 0, stream>>>(wkv_in, Pb, ALb, wkv_out);
    wkv_y<<<4096, tb, 0, stream>>>(Rb, KDb, Vb, DEC, Pb, YA);   // YA = S0 (XR dead)

    // v2 path: XV2 (S4) still live
    ep = EpiP{}; ep.ob = V2;                                     // V2 = S3 (KDb dead)
    launch_gemm(1, XV2, Dc, WvT, Dc, BTc, Dc, Dc, ep, stream);
    // T1 = tanh(XV2 @ tv2w1T) — split-K (KS=8), Pb dead after wkv_y
    gemm_splitk<<<dim3(8, 64), tb, 0, stream>>>(XV2, Dc, tv2w1T, Dc, BTc, 64, 8, 256, PART);
    splitk_reduce_tanh<<<(BTc * 64 + 255) / 256, tb, 0, stream>>>(PART, 8, (size_t)BTc * 64, T1);
    ep = EpiP{}; ep.ob = V2; ep.ab = V2;                         // in-place add
    launch_gemm(6, T1, 64, tv2w2T, 64, BTc, Dc, 64, ep, stream);

    // layernorm + output projection
    ln_fuse<<<BTc, tb, 0, stream>>>(YA, V2, lnw, lnb, YLN);      // YLN = S1 (Vb dead)
    ep = EpiP{}; ep.of = out_f;
    launch_gemm(0, YLN, Dc, WoT, Dc, BTc, Dc, Dc, ep, stream);
}

// Round 15
// 681.121 us; speedup vs baseline: 1.3441x; 1.0192x over previous
//
#include <hip/hip_runtime.h>
#include <hip/hip_bf16.h>

// ---------------- types / helpers ----------------
typedef __attribute__((ext_vector_type(8))) short   vshort8;   // 8 x bf16 bits (4 VGPRs)
typedef __attribute__((ext_vector_type(8))) unsigned short vushort8;
typedef __attribute__((ext_vector_type(4))) float   vfloat4;
typedef __attribute__((ext_vector_type(2))) float   vfloat2;

__device__ __forceinline__ float bf2f(unsigned short h) {
    union { unsigned u; float f; } x; x.u = ((unsigned)h) << 16; return x.f;
}
__device__ __forceinline__ unsigned short f2bf(float f) {
    union { float f; unsigned u; } x; x.f = f;
    unsigned r = x.u + 0x7fffu + ((x.u >> 16) & 1u);
    return (unsigned short)(r >> 16);
}
__device__ __forceinline__ void cp16_async(const void* g, void* l) {
    __builtin_amdgcn_global_load_lds(
        (const __attribute__((address_space(1))) unsigned int*)g,
        (__attribute__((address_space(3))) unsigned int*)l, 16, 0, 0);
}

#define FBAR() do { asm volatile("" ::: "memory"); __builtin_amdgcn_s_barrier(); asm volatile("" ::: "memory"); } while (0)

// ---------------- constants ----------------
#define Bc 4
#define Tc 2048
#define Dc 2048
#define Hc 32
#define KHc 64
#define BTc (Bc*Tc)              // 8192
#define BTDc ((size_t)BTc*Dc)    // 16,777,216
#define LP 72                    // LDS row stride (shorts) for scan kernels

struct EpiP {
    float* of;                 // f32 out
    unsigned short* ob;        // bf16 out
    const float* a0;           // aux f32 (decay)
    const float* a1;           // aux f32 (unused)
    const unsigned short* ab;  // aux bf16 (v2 partial)
    const float* vec;          // per-col vector (time_decay)
};

template<int EPI>
__device__ __forceinline__ void epi_store(float a, int row, int col, int N, const EpiP& ep)
{
    size_t o = (size_t)row * N + col;
    if (EPI == 0) {
        ep.of[o] = a;
    } else if (EPI == 1) {
        ep.ob[o] = f2bf(a);
    } else if (EPI == 2) {
        ep.ob[o] = f2bf(tanhf(a));
    } else if (EPI == 4) {                // KD: acc * (1 - decay)
        ep.ob[o] = f2bf(a * (1.f - ep.a0[o]));
    } else if (EPI == 5) {                // DECAY: exp(-exp(vec[col]+acc)) f32
        ep.of[o] = expf(-expf(ep.vec[col] + a));
    } else if (EPI == 6) {                // ADDB: acc + bf16 aux -> bf16
        ep.ob[o] = f2bf(a + bf2f(ep.ab[o]));
    }
}

// ============ GEMM-128 (m97-style, fully-drained), fallback for odd shapes ============
template<int EPI>
__global__ __launch_bounds__(256) void gemm_bt(
    const unsigned short* __restrict__ A, int lda,
    const unsigned short* __restrict__ BT, int ldbt,
    int M, int N, int K, EpiP ep)
{
    __shared__ unsigned short lA[128 * 32];
    __shared__ unsigned short lB[128 * 32];
    const int tid  = threadIdx.x;
    const int lane = tid & 63;
    const int w    = tid >> 6;
    const int mt   = blockIdx.y, nt = blockIdx.x;
    const int wm = (w >> 1) * 64, wn = (w & 1) * 64;
    const int frow = lane & 15, fk = (lane >> 4) * 8;

    vfloat4 acc[4][4];
#pragma unroll
    for (int i = 0; i < 4; i++)
#pragma unroll
        for (int j = 0; j < 4; j++) acc[i][j] = vfloat4{0.f, 0.f, 0.f, 0.f};

    for (int k0 = 0; k0 < K; k0 += 32) {
        __syncthreads();
#pragma unroll
        for (int p = 0; p < 2; p++) {
            int idx = p * 256 + tid;
            int row = idx >> 2, colh = (idx & 3) * 8;
            cp16_async(A + (size_t)(mt * 128 + row) * lda + k0 + colh, &lA[idx * 8]);
        }
#pragma unroll
        for (int p = 0; p < 2; p++) {
            int idx = p * 256 + tid;
            int row = idx >> 2, colh = (idx & 3) * 8;
            cp16_async(BT + (size_t)(nt * 128 + row) * ldbt + k0 + colh, &lB[idx * 8]);
        }
        __syncthreads();

        vshort8 af[4], bfr[4];
#pragma unroll
        for (int m = 0; m < 4; m++) af[m]  = *(const vshort8*)&lA[(wm + m * 16 + frow) * 32 + fk];
#pragma unroll
        for (int n = 0; n < 4; n++) bfr[n] = *(const vshort8*)&lB[(wn + n * 16 + frow) * 32 + fk];
#pragma unroll
        for (int m = 0; m < 4; m++)
#pragma unroll
            for (int n = 0; n < 4; n++)
                acc[m][n] = __builtin_amdgcn_mfma_f32_16x16x32_bf16(af[m], bfr[n], acc[m][n], 0, 0, 0);
    }

    const int crow0 = mt * 128 + wm, ccol0 = nt * 128 + wn;
#pragma unroll
    for (int m = 0; m < 4; m++)
#pragma unroll
        for (int n = 0; n < 4; n++) {
            int col = ccol0 + n * 16 + (lane & 15);
            if (col >= N) continue;
#pragma unroll
            for (int q = 0; q < 4; q++) {
                int row = crow0 + m * 16 + (lane >> 4) * 4 + q;
                epi_store<EPI>(acc[m][n][q], row, col, N, ep);
            }
        }
}

// ============ split-K tall-skinny GEMM: f32 partials, grid (ntN*KS, M/128) ============
__global__ __launch_bounds__(256) void gemm_splitk(
    const unsigned short* __restrict__ A, int lda,
    const unsigned short* __restrict__ BT, int ldbt,
    int M, int N, int KS, int Ksl, float* __restrict__ part)
{
    __shared__ unsigned short lA[128 * 32];
    __shared__ unsigned short lB[128 * 32];
    const int tid  = threadIdx.x;
    const int lane = tid & 63;
    const int w    = tid >> 6;
    const int nt = blockIdx.x / KS, ks = blockIdx.x % KS;
    const int mt = blockIdx.y;
    const int wm = (w >> 1) * 64, wn = (w & 1) * 64;
    const int frow = lane & 15, fk = (lane >> 4) * 8;

    vfloat4 acc[4][4];
#pragma unroll
    for (int i = 0; i < 4; i++)
#pragma unroll
        for (int j = 0; j < 4; j++) acc[i][j] = vfloat4{0.f, 0.f, 0.f, 0.f};

    const int kend = ks * Ksl + Ksl;
    for (int k0 = ks * Ksl; k0 < kend; k0 += 32) {
        __syncthreads();
#pragma unroll
        for (int p = 0; p < 2; p++) {
            int idx = p * 256 + tid;
            int row = idx >> 2, colh = (idx & 3) * 8;
            cp16_async(A + (size_t)(mt * 128 + row) * lda + k0 + colh, &lA[idx * 8]);
        }
#pragma unroll
        for (int p = 0; p < 2; p++) {
            int idx = p * 256 + tid;
            int row = idx >> 2, colh = (idx & 3) * 8;
            cp16_async(BT + (size_t)(nt * 128 + row) * ldbt + k0 + colh, &lB[idx * 8]);
        }
        __syncthreads();

        vshort8 af[4], bfr[4];
#pragma unroll
        for (int m = 0; m < 4; m++) af[m]  = *(const vshort8*)&lA[(wm + m * 16 + frow) * 32 + fk];
#pragma unroll
        for (int n = 0; n < 4; n++) bfr[n] = *(const vshort8*)&lB[(wn + n * 16 + frow) * 32 + fk];
#pragma unroll
        for (int m = 0; m < 4; m++)
#pragma unroll
            for (int n = 0; n < 4; n++)
                acc[m][n] = __builtin_amdgcn_mfma_f32_16x16x32_bf16(af[m], bfr[n], acc[m][n], 0, 0, 0);
    }

    const int crow0 = mt * 128 + wm, ccol0 = nt * 128 + wn;
    float* pbase = part + (size_t)ks * M * N;
#pragma unroll
    for (int m = 0; m < 4; m++)
#pragma unroll
        for (int n = 0; n < 4; n++) {
            int col = ccol0 + n * 16 + (lane & 15);
            if (col >= N) continue;
#pragma unroll
            for (int q = 0; q < 4; q++) {
                int row = crow0 + m * 16 + (lane >> 4) * 4 + q;
                pbase[(size_t)row * N + col] = acc[m][n][q];
            }
        }
}

__global__ __launch_bounds__(256) void splitk_reduce_tanh(
    const float* __restrict__ part, int KS, size_t MN, unsigned short* __restrict__ out)
{
    size_t i = (size_t)blockIdx.x * 256 + threadIdx.x;
    if (i >= MN) return;
    float s = 0.f;
    for (int k = 0; k < KS; k++) s += part[(size_t)k * MN + i];
    out[i] = f2bf(tanhf(s));
}

// ============ GEMM-256s: 256x256, BK=32, triple-buffer (for small K: 32/64) ============
template<int EPI>
__global__ __launch_bounds__(512, 1) void gemm256s(
    const unsigned short* __restrict__ A, int lda,
    const unsigned short* __restrict__ BT, int ldbt,
    int M, int N, int K, EpiP ep)
{
    __shared__ unsigned short sh[3 * 16384];   // 96 KB
    const int tid  = threadIdx.x;
    const int lane = tid & 63;
    const int w    = tid >> 6;

    int bid = blockIdx.y * gridDim.x + blockIdx.x;
    {
        int nwg = gridDim.x * gridDim.y;
        if ((nwg & 7) == 0) bid = (bid & 7) * (nwg >> 3) + (bid >> 3);
    }
    const int mt = bid / gridDim.x, nt = bid % gridDim.x;

    const int wm = (w >> 2) * 128, wn = (w & 3) * 64;
    const int frow = lane & 15;
    const int cswz = ((lane >> 4) ^ ((frow >> 1) & 3)) * 8;
    const int arow0 = mt * 256, brow0 = nt * 256;

    vfloat4 acc[8][4];
#pragma unroll
    for (int i = 0; i < 8; i++)
#pragma unroll
        for (int j = 0; j < 4; j++) acc[i][j] = vfloat4{0.f, 0.f, 0.f, 0.f};

    const int NT = K >> 5;

    auto stage = [&](int kt, int sbuf) {
        int k0 = kt << 5;
        unsigned short* dst = &sh[sbuf * 16384];
#pragma unroll
        for (int i = 0; i < 2; i++) {
            int idx = i * 512 + tid;
            int row = idx >> 2;
            int ch  = (idx & 3) ^ ((row >> 1) & 3);
            cp16_async(A + (size_t)(arow0 + row) * lda + k0 + ch * 8, dst + idx * 8);
        }
#pragma unroll
        for (int i = 0; i < 2; i++) {
            int idx = i * 512 + tid;
            int row = idx >> 2;
            int ch  = (idx & 3) ^ ((row >> 1) & 3);
            cp16_async(BT + (size_t)(brow0 + row) * ldbt + k0 + ch * 8, dst + 8192 + idx * 8);
        }
    };

    stage(0, 0);
    if (NT > 1) {
        stage(1, 1);
        asm volatile("s_waitcnt vmcnt(4)" ::: "memory");
    } else {
        asm volatile("s_waitcnt vmcnt(0)" ::: "memory");
    }
    __builtin_amdgcn_s_barrier();

    int buf = 0, sb = 2;
    for (int kt = 0; kt < NT; kt++) {
        if (kt + 2 < NT) stage(kt + 2, sb);
        const unsigned short* Ab = &sh[buf * 16384];
        const unsigned short* Bb = Ab + 8192;

        vshort8 af[8], bfv[4];
#pragma unroll
        for (int m = 0; m < 8; m++)
            af[m] = *(const vshort8*)&Ab[(wm + m * 16 + frow) * 32 + cswz];
#pragma unroll
        for (int n = 0; n < 4; n++)
            bfv[n] = *(const vshort8*)&Bb[(wn + n * 16 + frow) * 32 + cswz];

        __builtin_amdgcn_s_setprio(1);
#pragma unroll
        for (int m = 0; m < 8; m++)
#pragma unroll
            for (int n = 0; n < 4; n++)
                acc[m][n] = __builtin_amdgcn_mfma_f32_16x16x32_bf16(af[m], bfv[n], acc[m][n], 0, 0, 0);
        __builtin_amdgcn_s_setprio(0);

        if (kt + 1 < NT) {
            if (kt + 2 < NT) asm volatile("s_waitcnt vmcnt(4)" ::: "memory");
            else             asm volatile("s_waitcnt vmcnt(0)" ::: "memory");
            asm volatile("s_waitcnt lgkmcnt(0)" ::: "memory");
            __builtin_amdgcn_s_barrier();
        }
        buf = (buf == 2) ? 0 : buf + 1;
        sb  = (sb  == 2) ? 0 : sb  + 1;
    }

    const int crow0 = arow0 + wm, ccol0 = brow0 + wn;
#pragma unroll
    for (int m = 0; m < 8; m++)
#pragma unroll
        for (int n = 0; n < 4; n++) {
            int col = ccol0 + n * 16 + (lane & 15);
#pragma unroll
            for (int q = 0; q < 4; q++) {
                int row = crow0 + m * 16 + (lane >> 4) * 4 + q;
                epi_store<EPI>(acc[m][n][q], row, col, N, ep);
            }
        }
}

// ============ GEMM-256p8: 256x256, BK=64, 8-phase schedule, counted vmcnt(6) ============
// (round-9/12 variant — best measured: ~85 us/dispatch; FROZEN)
template<int EPI>
__global__ __launch_bounds__(512, 1) void gemm256p8(
    const unsigned short* __restrict__ A, int lda,
    const unsigned short* __restrict__ BT, int ldbt,
    int M, int N, int K, EpiP ep)
{
    __shared__ unsigned short sh[65536];   // 128 KB
    const int tid  = threadIdx.x;
    const int lane = tid & 63;
    const int w    = tid >> 6;

    int bid = blockIdx.y * gridDim.x + blockIdx.x;
    {
        int nwg = gridDim.x * gridDim.y;
        if ((nwg & 7) == 0) bid = (bid & 7) * (nwg >> 3) + (bid >> 3);
    }
    const int mt = bid / gridDim.x, nt = bid % gridDim.x;

    const int wm = (w >> 2) * 128, wn = (w & 3) * 64;
    const int frow = lane & 15;
    const int g    = lane >> 4;
    const int arow0 = mt * 256, brow0 = nt * 256;

    vfloat4 acc[8][4];
#pragma unroll
    for (int i = 0; i < 8; i++)
#pragma unroll
        for (int j = 0; j < 4; j++) acc[i][j] = vfloat4{0.f, 0.f, 0.f, 0.f};

    const int NT = K >> 6;   // even, >= 2 (router guarantees K % 128 == 0)

    auto stageA = [&](int kt, int p) {
        int k0 = kt << 6;
        unsigned short* dst = &sh[(kt & 1) * 32768];
#pragma unroll
        for (int l = 0; l < 2; l++) {
            int idx  = l * 512 + tid;
            int rl   = idx >> 3, slot = idx & 7;
            int rg   = (rl & 63) + p * 64 + ((rl >> 6) << 7);
            int ch   = slot ^ (rg & 7);
            cp16_async(A + (size_t)(arow0 + rg) * lda + k0 + ch * 8, dst + rg * 64 + slot * 8);
        }
    };
    auto stageB = [&](int kt, int p) {
        int k0 = kt << 6;
        unsigned short* dst = &sh[(kt & 1) * 32768 + 16384];
#pragma unroll
        for (int l = 0; l < 2; l++) {
            int idx  = l * 512 + tid;
            int rl   = idx >> 3, slot = idx & 7;
            int rg   = (rl & 31) + p * 32 + ((rl >> 5) << 6);
            int ch   = slot ^ (rg & 7);
            cp16_async(BT + (size_t)(brow0 + rg) * ldbt + k0 + ch * 8, dst + rg * 64 + slot * 8);
        }
    };

    vshort8 af[4][2], bf0[2][2], bf1[2][2];

    auto readA = [&](const unsigned short* Ab, int mh) {
#pragma unroll
        for (int mi = 0; mi < 4; mi++) {
            int r = wm + mh * 64 + mi * 16 + frow;
#pragma unroll
            for (int kk = 0; kk < 2; kk++)
                af[mi][kk] = *(const vshort8*)&Ab[r * 64 + (((kk * 4 + g) ^ (r & 7)) * 8)];
        }
    };
    auto readB = [&](const unsigned short* Bb, int nh, vshort8 (&bfr)[2][2]) {
#pragma unroll
        for (int ni = 0; ni < 2; ni++) {
            int r = wn + nh * 32 + ni * 16 + frow;
#pragma unroll
            for (int kk = 0; kk < 2; kk++)
                bfr[ni][kk] = *(const vshort8*)&Bb[r * 64 + (((kk * 4 + g) ^ (r & 7)) * 8)];
        }
    };
    auto domfma = [&](int mh, int nh, vshort8 (&bfr)[2][2]) {
        __builtin_amdgcn_s_setprio(1);
#pragma unroll
        for (int mi = 0; mi < 4; mi++)
#pragma unroll
            for (int ni = 0; ni < 2; ni++)
#pragma unroll
                for (int kk = 0; kk < 2; kk++)
                    acc[mh * 4 + mi][nh * 2 + ni] = __builtin_amdgcn_mfma_f32_16x16x32_bf16(
                        af[mi][kk], bfr[ni][kk], acc[mh * 4 + mi][nh * 2 + ni], 0, 0, 0);
        __builtin_amdgcn_s_setprio(0);
    };

    // prologue: T0 full + T1.Am0, T1.Bn1  (6 halves = 12 loads in flight)
    stageA(0, 0); stageB(0, 1); stageA(0, 1); stageB(0, 0);
    stageA(1, 0); stageB(1, 1);

    const unsigned short* A0 = sh;
    const unsigned short* B0 = sh + 16384;
    const unsigned short* A1 = sh + 32768;
    const unsigned short* B1 = sh + 49152;

    for (int i2 = 0; i2 < NT; i2 += 2) {
        const bool s2 = (i2 + 2 < NT), s3 = (i2 + 3 < NT);
        // ph0
        stageA(i2 + 1, 1);
        asm volatile("s_waitcnt vmcnt(6)" ::: "memory");
        FBAR();
        readA(A0, 0); readB(B0, 0, bf0);
        domfma(0, 0, bf0);
        asm volatile("s_waitcnt lgkmcnt(0)" ::: "memory");
        FBAR();
        // ph1
        stageB(i2 + 1, 0);
        FBAR();
        readB(B0, 1, bf1);
        domfma(0, 1, bf1);
        asm volatile("s_waitcnt lgkmcnt(0)" ::: "memory");
        FBAR();
        // ph2
        if (s2) stageA(i2 + 2, 0);
        FBAR();
        readA(A0, 1);
        domfma(1, 1, bf1);
        asm volatile("s_waitcnt lgkmcnt(0)" ::: "memory");
        FBAR();
        // ph3
        if (s2) stageB(i2 + 2, 1);
        FBAR();
        domfma(1, 0, bf0);
        FBAR();
        // ph4
        if (s2) {
            stageA(i2 + 2, 1);
            asm volatile("s_waitcnt vmcnt(6)" ::: "memory");
        } else {
            asm volatile("s_waitcnt vmcnt(0)" ::: "memory");
        }
        FBAR();
        readA(A1, 0); readB(B1, 0, bf0);
        domfma(0, 0, bf0);
        asm volatile("s_waitcnt lgkmcnt(0)" ::: "memory");
        FBAR();
        // ph5
        if (s2) stageB(i2 + 2, 0);
        FBAR();
        readB(B1, 1, bf1);
        domfma(0, 1, bf1);
        asm volatile("s_waitcnt lgkmcnt(0)" ::: "memory");
        FBAR();
        // ph6
        if (s3) stageA(i2 + 3, 0);
        FBAR();
        readA(A1, 1);
        domfma(1, 1, bf1);
        asm volatile("s_waitcnt lgkmcnt(0)" ::: "memory");
        FBAR();
        // ph7
        if (s3) stageB(i2 + 3, 1);
        FBAR();
        domfma(1, 0, bf0);
        FBAR();
    }

    const int crow0 = arow0 + wm, ccol0 = brow0 + wn;
#pragma unroll
    for (int m = 0; m < 8; m++)
#pragma unroll
        for (int n = 0; n < 4; n++) {
            int col = ccol0 + n * 16 + (lane & 15);
#pragma unroll
            for (int q = 0; q < 4; q++) {
                int row = crow0 + m * 16 + (lane >> 4) * 4 + q;
                epi_store<EPI>(acc[m][n][q], row, col, N, ep);
            }
        }
}

// ============ mix5: fused five mix GEMMs (K=32), x/DX read once ============
struct Mix5P {
    const float* vec[5];
    unsigned short* out[5];
};

__global__ __launch_bounds__(256) void mix5(
    const unsigned short* __restrict__ MP,   // MIXPRE [BTc][160]
    const unsigned short* __restrict__ W2T,  // [Dc][160]
    const float* __restrict__ x,
    const unsigned short* __restrict__ DXb,
    Mix5P p)
{
    __shared__ unsigned short lA[64 * 32];    // 4 KB
    __shared__ unsigned short lB[128 * 32];   // 8 KB
    const int tid = threadIdx.x, lane = tid & 63, w = tid >> 6;
    const int mt = blockIdx.y, nt = blockIdx.x;   // grid (16, 128)
    const int wm = (w >> 1) * 32, wn = (w & 1) * 64;
    const int frow = lane & 15, fk = (lane >> 4) * 8;
    const int row0 = mt * 64, col0 = nt * 128;

    float xr[8][4], dxr[8][4];
#pragma unroll
    for (int mi = 0; mi < 2; mi++)
#pragma unroll
        for (int q = 0; q < 4; q++) {
            int rl = wm + mi * 16 + (lane >> 4) * 4 + q;
            size_t rb = (size_t)(row0 + rl) * Dc + col0;
#pragma unroll
            for (int ni = 0; ni < 4; ni++) {
                int cl = wn + ni * 16 + (lane & 15);
                xr[mi * 4 + q][ni]  = x[rb + cl];
                dxr[mi * 4 + q][ni] = bf2f(DXb[rb + cl]);
            }
        }

    for (int f = 0; f < 5; f++) {
        __syncthreads();
        {
            int row = tid >> 2, ch = tid & 3;
            cp16_async(MP + (size_t)(row0 + row) * 160 + f * 32 + ch * 8, &lA[(row * 4 + ch) * 8]);
        }
#pragma unroll
        for (int p2 = 0; p2 < 2; p2++) {
            int idx = p2 * 256 + tid;
            int row = idx >> 2, ch = idx & 3;
            cp16_async(W2T + (size_t)(col0 + row) * 160 + f * 32 + ch * 8, &lB[(row * 4 + ch) * 8]);
        }
        __syncthreads();

        vshort8 af[2], bfr[4];
#pragma unroll
        for (int mi = 0; mi < 2; mi++) af[mi]  = *(const vshort8*)&lA[(wm + mi * 16 + frow) * 32 + fk];
#pragma unroll
        for (int ni = 0; ni < 4; ni++) bfr[ni] = *(const vshort8*)&lB[(wn + ni * 16 + frow) * 32 + fk];

        vfloat4 acc[2][4];
#pragma unroll
        for (int mi = 0; mi < 2; mi++)
#pragma unroll
            for (int ni = 0; ni < 4; ni++) {
                acc[mi][ni] = vfloat4{0.f, 0.f, 0.f, 0.f};
                acc[mi][ni] = __builtin_amdgcn_mfma_f32_16x16x32_bf16(af[mi], bfr[ni], acc[mi][ni], 0, 0, 0);
            }

        const float* vec = p.vec[f];
        unsigned short* ob = p.out[f];
        float vc[4];
#pragma unroll
        for (int ni = 0; ni < 4; ni++) vc[ni] = vec[col0 + wn + ni * 16 + (lane & 15)];
#pragma unroll
        for (int mi = 0; mi < 2; mi++)
#pragma unroll
            for (int q = 0; q < 4; q++) {
                int rl = wm + mi * 16 + (lane >> 4) * 4 + q;
                size_t rb = (size_t)(row0 + rl) * Dc + col0;
#pragma unroll
                for (int ni = 0; ni < 4; ni++) {
                    int cl = wn + ni * 16 + (lane & 15);
                    ob[rb + cl] = f2bf(xr[mi * 4 + q][ni] + dxr[mi * 4 + q][ni] * (vc[ni] + acc[mi][ni][q]));
                }
            }
    }
}

// ---------------- prep: xxx = x + dx*time_maa_x, dx = xprev - x  -> bf16 ----------------
// rows with t == Tc-1 also emit shift_state_out (f32) — replaces shift_copy kernel.
__global__ __launch_bounds__(256) void prep_xxx(
    const float* __restrict__ x, const float* __restrict__ shift_in,
    const float* __restrict__ tmx, unsigned short* __restrict__ xxx,
    unsigned short* __restrict__ dxb, float* __restrict__ shift_out)
{
    int row = blockIdx.x, tid = threadIdx.x;
    int t = row & (Tc - 1), b = row >> 11;
    size_t base = (size_t)row * Dc + tid * 8;
    const float* xp = t ? x + base - Dc : shift_in + (size_t)b * Dc + tid * 8;
    vushort8 o, dxo;
    float xv8[8];
#pragma unroll
    for (int j = 0; j < 8; j++) {
        float xv = x[base + j];
        xv8[j] = xv;
        float dx = xp[j] - xv;
        o[j]   = f2bf(xv + dx * tmx[tid * 8 + j]);
        dxo[j] = f2bf(dx);
    }
    *(vushort8*)(xxx + base) = o;
    *(vushort8*)(dxb + base) = dxo;
    if (t == Tc - 1) {
#pragma unroll
        for (int j = 0; j < 8; j++) shift_out[(size_t)b * Dc + tid * 8 + j] = xv8[j];
    }
}

// ---------------- merged 4x DxD transpose (blockIdx.z selects tensor) ----------------
struct T4 { const float* in[4]; unsigned short* out[4]; };
__global__ __launch_bounds__(256) void transpose_cast4(T4 t4)
{
    __shared__ float tile[32][33];
    const float* in = t4.in[blockIdx.z];
    unsigned short* out = t4.out[blockIdx.z];
    int ct = blockIdx.x, rt = blockIdx.y;
    int lx = threadIdx.x & 31, ly = threadIdx.x >> 5;
#pragma unroll
    for (int i = 0; i < 4; i++)
        tile[ly + i * 8][lx] = in[(size_t)(rt * 32 + ly + i * 8) * Dc + ct * 32 + lx];
    __syncthreads();
#pragma unroll
    for (int i = 0; i < 4; i++)
        out[(size_t)(ct * 32 + ly + i * 8) * Dc + rt * 32 + lx] = f2bf(tile[lx][ly + i * 8]);
}

// ---------------- merged small transposes: out[C][R] = in[R][C], 6 tensors ----------------
struct TM { const float* in[6]; unsigned short* out[6]; int R[6], C[6]; };
__global__ __launch_bounds__(256) void transpose_multi(TM p)
{
    __shared__ float tile[32][33];
    const int z = blockIdx.y;
    const int R = p.R[z], C = p.C[z];
    const int ctiles = C >> 5;
    const int ct = blockIdx.x % ctiles, rt = blockIdx.x / ctiles;
    if (rt >= (R >> 5)) return;
    const float* in = p.in[z];
    unsigned short* out = p.out[z];
    int lx = threadIdx.x & 31, ly = threadIdx.x >> 5;
#pragma unroll
    for (int i = 0; i < 4; i++)
        tile[ly + i * 8][lx] = in[(size_t)(rt * 32 + ly + i * 8) * C + ct * 32 + lx];
    __syncthreads();
#pragma unroll
    for (int i = 0; i < 4; i++)
        out[(size_t)(ct * 32 + ly + i * 8) * R + rt * 32 + lx] = f2bf(tile[lx][ly + i * 8]);
}

// =========== WKV chunked scan as chunked linear attention (MFMA) ===========
__global__ __launch_bounds__(256) void wkv_summary(
    const unsigned short* __restrict__ kd, const unsigned short* __restrict__ vv,
    const float* __restrict__ dec, float* __restrict__ P, float* __restrict__ aL)
{
    __shared__ unsigned short kb2T[64][LP];
    __shared__ unsigned short vT[64][LP];
    __shared__ float gp[4][64];
    const int blk = blockIdx.x;
    const int c = blk & 31, bh = blk >> 5, b = bh >> 5, h = bh & 31;
    const int tid = threadIdx.x;
    const size_t rowbase = ((size_t)(b * Tc + c * 64)) * Dc + h * 64;

    {
        int t = tid >> 2, q = tid & 3;
        const unsigned short* src = vv + rowbase + (size_t)t * Dc + q * 16;
        vushort8 a = *(const vushort8*)src;
        vushort8 b2 = *(const vushort8*)(src + 8);
#pragma unroll
        for (int j = 0; j < 8; j++) vT[q * 16 + j][t] = a[j];
#pragma unroll
        for (int j = 0; j < 8; j++) vT[q * 16 + 8 + j][t] = b2[j];
    }

    const int k = tid & 63, grp = tid >> 6;
    const float* decp = dec + rowbase + k;
    const unsigned short* kp = kd + rowbase + k;
    float suf_local[16];
    float pgrp = 1.f;
#pragma unroll
    for (int i = 15; i >= 0; i--) {
        int t = grp * 16 + i;
        float d = decp[(size_t)t * Dc];
        suf_local[i] = pgrp;
        pgrp *= d;
    }
    gp[grp][k] = pgrp;
    __syncthreads();
    float suff = 1.f;
#pragma unroll
    for (int g2 = 0; g2 < 4; g2++) if (g2 > grp) suff *= gp[g2][k];
    if (grp == 0) aL[(size_t)blk * 64 + k] = pgrp * suff;
    {
        vushort8 p0, p1;
#pragma unroll
        for (int i = 0; i < 8; i++) {
            int t = grp * 16 + i;
            p0[i] = f2bf(bf2f(kp[(size_t)t * Dc]) * (suf_local[i] * suff));
        }
#pragma unroll
        for (int i = 0; i < 8; i++) {
            int t = grp * 16 + 8 + i;
            p1[i] = f2bf(bf2f(kp[(size_t)t * Dc]) * (suf_local[8 + i] * suff));
        }
        *(vushort8*)&kb2T[k][grp * 16] = p0;
        *(vushort8*)&kb2T[k][grp * 16 + 8] = p1;
    }
    __syncthreads();

    const int lane = tid & 63, w = tid >> 6;
    const int wm = (w >> 1) * 32, wn = (w & 1) * 32;
    const int frow = lane & 15, fk = (lane >> 4) * 8;
    vfloat4 acc[2][2];
#pragma unroll
    for (int m = 0; m < 2; m++)
#pragma unroll
        for (int n = 0; n < 2; n++) acc[m][n] = vfloat4{0.f, 0.f, 0.f, 0.f};
#pragma unroll
    for (int kk = 0; kk < 2; kk++) {
        vshort8 af[2], bfr[2];
#pragma unroll
        for (int m = 0; m < 2; m++) af[m]  = *(const vshort8*)&kb2T[wm + m * 16 + frow][kk * 32 + fk];
#pragma unroll
        for (int n = 0; n < 2; n++) bfr[n] = *(const vshort8*)&vT[wn + n * 16 + frow][kk * 32 + fk];
#pragma unroll
        for (int m = 0; m < 2; m++)
#pragma unroll
            for (int n = 0; n < 2; n++)
                acc[m][n] = __builtin_amdgcn_mfma_f32_16x16x32_bf16(af[m], bfr[n], acc[m][n], 0, 0, 0);
    }
    float* Pp = P + (size_t)blk * 4096;
#pragma unroll
    for (int m = 0; m < 2; m++)
#pragma unroll
        for (int n = 0; n < 2; n++) {
            int col = wn + n * 16 + (lane & 15);
#pragma unroll
            for (int q = 0; q < 4; q++) {
                int row = wm + m * 16 + (lane >> 4) * 4 + q;
                Pp[row * 64 + col] = acc[m][n][q];
            }
        }
}

__global__ __launch_bounds__(256) void wkv_states(
    const float* __restrict__ wkv_in, float* __restrict__ P /* -> Sb */,
    const float* __restrict__ aL, float* __restrict__ wkv_out)
{
    int idx = blockIdx.x * 256 + threadIdx.x;   // 524288
    int bh = idx >> 12, kv = idx & 4095, k = kv >> 6;
    float S = wkv_in[idx];
    for (int c = 0; c < 32; c++) {
        size_t off = (size_t)bh * 32 + c;
        float p = P[off * 4096 + kv];
        float a = aL[off * 64 + k];
        P[off * 4096 + kv] = S;   // Sb[c]
        S = S * a + p;
    }
    wkv_out[idx] = S;
}

__global__ __launch_bounds__(256) void wkv_y(
    const unsigned short* __restrict__ rr, const unsigned short* __restrict__ kd,
    const unsigned short* __restrict__ vv, const float* __restrict__ dec,
    const float* __restrict__ Sb, unsigned short* __restrict__ ya)
{
    __shared__ unsigned short rA[64][LP];
    __shared__ unsigned short kbL[64][LP];
    __shared__ unsigned short vT[64][LP];
    __shared__ unsigned short SbT[64][LP];
    __shared__ unsigned short QiM[64][LP];
    __shared__ float gp[4][64];
    const int blk = blockIdx.x;
    const int c = blk & 31, bh = blk >> 5, b = bh >> 5, h = bh & 31;
    const int tid = threadIdx.x;
    const size_t rowbase = ((size_t)(b * Tc + c * 64)) * Dc + h * 64;

    {
        int t = tid >> 2, q = tid & 3;
        const unsigned short* src = vv + rowbase + (size_t)t * Dc + q * 16;
        vushort8 a = *(const vushort8*)src;
        vushort8 b2 = *(const vushort8*)(src + 8);
#pragma unroll
        for (int j = 0; j < 8; j++) vT[q * 16 + j][t] = a[j];
#pragma unroll
        for (int j = 0; j < 8; j++) vT[q * 16 + 8 + j][t] = b2[j];
        const float* sp = Sb + (size_t)blk * 4096 + t * 64 + q * 16;
#pragma unroll
        for (int j = 0; j < 16; j++) SbT[q * 16 + j][t] = f2bf(sp[j]);
    }

    const int k = tid & 63, grp = tid >> 6;
    const float* decp = dec + rowbase + k;
    const unsigned short* rp = rr + rowbase + k;
    const unsigned short* kp = kd + rowbase + k;
    float pref_local[16];
    float pgrp = 1.f;
#pragma unroll
    for (int i = 0; i < 16; i++) {
        int t = grp * 16 + i;
        float d = decp[(size_t)t * Dc];
        pref_local[i] = pgrp;
        pgrp *= d;
    }
    gp[grp][k] = pgrp;
    __syncthreads();
    float pref = 1.f;
#pragma unroll
    for (int g2 = 0; g2 < 4; g2++) if (g2 < grp) pref *= gp[g2][k];
#pragma unroll
    for (int i = 0; i < 16; i++) {
        int t = grp * 16 + i;
        float Aex  = pref * pref_local[i];
        float Ainc = pref * (i < 15 ? pref_local[i + 1] : pgrp);
        rA[t][k]  = f2bf(bf2f(rp[(size_t)t * Dc]) * Aex);
        kbL[t][k] = f2bf(bf2f(kp[(size_t)t * Dc]) / Ainc);
    }
    __syncthreads();

    const int lane = tid & 63, w = tid >> 6;
    const int wm = (w >> 1) * 32, wn = (w & 1) * 32;
    const int frow = lane & 15, fk = (lane >> 4) * 8;

    vfloat4 acc[2][2];
#pragma unroll
    for (int m = 0; m < 2; m++)
#pragma unroll
        for (int n = 0; n < 2; n++) acc[m][n] = vfloat4{0.f, 0.f, 0.f, 0.f};
#pragma unroll
    for (int kk = 0; kk < 2; kk++) {
        vshort8 af[2], bfr[2];
#pragma unroll
        for (int m = 0; m < 2; m++) af[m]  = *(const vshort8*)&rA[wm + m * 16 + frow][kk * 32 + fk];
#pragma unroll
        for (int n = 0; n < 2; n++) bfr[n] = *(const vshort8*)&kbL[wn + n * 16 + frow][kk * 32 + fk];
#pragma unroll
        for (int m = 0; m < 2; m++)
#pragma unroll
            for (int n = 0; n < 2; n++)
                acc[m][n] = __builtin_amdgcn_mfma_f32_16x16x32_bf16(af[m], bfr[n], acc[m][n], 0, 0, 0);
    }
#pragma unroll
    for (int m = 0; m < 2; m++)
#pragma unroll
        for (int n = 0; n < 2; n++) {
            int s = wn + n * 16 + (lane & 15);
#pragma unroll
            for (int q = 0; q < 4; q++) {
                int t = wm + m * 16 + (lane >> 4) * 4 + q;
                QiM[t][s] = f2bf(s < t ? acc[m][n][q] : 0.f);
            }
        }
    __syncthreads();

#pragma unroll
    for (int m = 0; m < 2; m++)
#pragma unroll
        for (int n = 0; n < 2; n++) acc[m][n] = vfloat4{0.f, 0.f, 0.f, 0.f};
#pragma unroll
    for (int kk = 0; kk < 2; kk++) {
        vshort8 af[2], bfr[2];
#pragma unroll
        for (int m = 0; m < 2; m++) af[m]  = *(const vshort8*)&QiM[wm + m * 16 + frow][kk * 32 + fk];
#pragma unroll
        for (int n = 0; n < 2; n++) bfr[n] = *(const vshort8*)&vT[wn + n * 16 + frow][kk * 32 + fk];
#pragma unroll
        for (int m = 0; m < 2; m++)
#pragma unroll
            for (int n = 0; n < 2; n++)
                acc[m][n] = __builtin_amdgcn_mfma_f32_16x16x32_bf16(af[m], bfr[n], acc[m][n], 0, 0, 0);
    }
#pragma unroll
    for (int kk = 0; kk < 2; kk++) {
        vshort8 af[2], bfr[2];
#pragma unroll
        for (int m = 0; m < 2; m++) af[m]  = *(const vshort8*)&rA[wm + m * 16 + frow][kk * 32 + fk];
#pragma unroll
        for (int n = 0; n < 2; n++) bfr[n] = *(const vshort8*)&SbT[wn + n * 16 + frow][kk * 32 + fk];
#pragma unroll
        for (int m = 0; m < 2; m++)
#pragma unroll
            for (int n = 0; n < 2; n++)
                acc[m][n] = __builtin_amdgcn_mfma_f32_16x16x32_bf16(af[m], bfr[n], acc[m][n], 0, 0, 0);
    }
#pragma unroll
    for (int m = 0; m < 2; m++)
#pragma unroll
        for (int n = 0; n < 2; n++) {
            int col = wn + n * 16 + (lane & 15);
#pragma unroll
            for (int q = 0; q < 4; q++) {
                int t = wm + m * 16 + (lane >> 4) * 4 + q;
                ya[rowbase + (size_t)t * Dc + col] = f2bf(acc[m][n][q]);
            }
        }
}

// ---------------- LayerNorm(ya + v2) -> bf16 ----------------
__global__ __launch_bounds__(256) void ln_fuse(
    const unsigned short* __restrict__ ya, const unsigned short* __restrict__ v2,
    const float* __restrict__ lnw, const float* __restrict__ lnb,
    unsigned short* __restrict__ out)
{
    int row = blockIdx.x, tid = threadIdx.x;
    size_t base = (size_t)row * Dc + tid * 8;
    vushort8 a = *(const vushort8*)(ya + base);
    vushort8 b = *(const vushort8*)(v2 + base);
    float v[8]; float s = 0.f, s2 = 0.f;
#pragma unroll
    for (int j = 0; j < 8; j++) { float t = bf2f(a[j]) + bf2f(b[j]); v[j] = t; s += t; s2 += t * t; }
#pragma unroll
    for (int o = 32; o; o >>= 1) { s += __shfl_xor(s, o); s2 += __shfl_xor(s2, o); }
    __shared__ float rs[8];
    int w = tid >> 6;
    if ((tid & 63) == 0) { rs[w] = s; rs[w + 4] = s2; }
    __syncthreads();
    s  = rs[0] + rs[1] + rs[2] + rs[3];
    s2 = rs[4] + rs[5] + rs[6] + rs[7];
    float mu = s * (1.f / Dc);
    float var = s2 * (1.f / Dc) - mu * mu;
    float inv = rsqrtf(var + 1e-5f);
#pragma unroll
    for (int j = 0; j < 8; j++) {
        int d = tid * 8 + j;
        out[base + j] = f2bf((v[j] - mu) * inv * lnw[d] + lnb[d]);
    }
}

// ---------------- host ----------------
static inline void launch_gemm(int epi, const unsigned short* A, int lda,
                               const unsigned short* BT, int ldbt,
                               int M, int N, int K, EpiP ep, hipStream_t s)
{
    if ((M & 255) == 0 && (N & 255) == 0) {
        if ((K & 127) == 0 && K >= 128 && (epi == 0 || epi == 1 || epi == 4)) {
            dim3 g(N / 256, M / 256), b(512);
            switch (epi) {
                case 0: gemm256p8<0><<<g, b, 0, s>>>(A, lda, BT, ldbt, M, N, K, ep); break;
                case 1: gemm256p8<1><<<g, b, 0, s>>>(A, lda, BT, ldbt, M, N, K, ep); break;
                case 4: gemm256p8<4><<<g, b, 0, s>>>(A, lda, BT, ldbt, M, N, K, ep); break;
            }
            return;
        }
        if ((K & 31) == 0) {
            dim3 g(N / 256, M / 256), b(512);
            switch (epi) {
                case 0: gemm256s<0><<<g, b, 0, s>>>(A, lda, BT, ldbt, M, N, K, ep); break;
                case 1: gemm256s<1><<<g, b, 0, s>>>(A, lda, BT, ldbt, M, N, K, ep); break;
                case 2: gemm256s<2><<<g, b, 0, s>>>(A, lda, BT, ldbt, M, N, K, ep); break;
                case 4: gemm256s<4><<<g, b, 0, s>>>(A, lda, BT, ldbt, M, N, K, ep); break;
                case 5: gemm256s<5><<<g, b, 0, s>>>(A, lda, BT, ldbt, M, N, K, ep); break;
                case 6: gemm256s<6><<<g, b, 0, s>>>(A, lda, BT, ldbt, M, N, K, ep); break;
            }
            return;
        }
    }
    dim3 g((N + 127) / 128, M / 128), b(256);
    switch (epi) {
        case 0: gemm_bt<0><<<g, b, 0, s>>>(A, lda, BT, ldbt, M, N, K, ep); break;
        case 1: gemm_bt<1><<<g, b, 0, s>>>(A, lda, BT, ldbt, M, N, K, ep); break;
        case 2: gemm_bt<2><<<g, b, 0, s>>>(A, lda, BT, ldbt, M, N, K, ep); break;
        case 4: gemm_bt<4><<<g, b, 0, s>>>(A, lda, BT, ldbt, M, N, K, ep); break;
        case 5: gemm_bt<5><<<g, b, 0, s>>>(A, lda, BT, ldbt, M, N, K, ep); break;
        case 6: gemm_bt<6><<<g, b, 0, s>>>(A, lda, BT, ldbt, M, N, K, ep); break;
    }
}

extern "C" void kernel_launch(void* const* d_in, const int* in_sizes, int n_in,
                              void* d_out, int out_size, void* d_ws, size_t ws_size,
                              hipStream_t stream)
{
    (void)in_sizes; (void)n_in; (void)out_size; (void)ws_size;
    const float* x      = (const float*)d_in[0];
    const float* shift  = (const float*)d_in[1];
    const float* wkv_in = (const float*)d_in[2];
    const float* tmx    = (const float*)d_in[3];
    const float* tmr    = (const float*)d_in[4];
    const float* tmk    = (const float*)d_in[5];
    const float* tmv    = (const float*)d_in[6];
    const float* tmw    = (const float*)d_in[7];
    const float* tmv2   = (const float*)d_in[8];
    const float* w1     = (const float*)d_in[9];
    const float* w2     = (const float*)d_in[10];
    const float* tdecay = (const float*)d_in[11];
    const float* tdw1   = (const float*)d_in[12];
    const float* tdw2   = (const float*)d_in[13];
    const float* tv2w1  = (const float*)d_in[14];
    const float* tv2w2  = (const float*)d_in[15];
    const float* Wr     = (const float*)d_in[16];
    const float* Wk     = (const float*)d_in[17];
    const float* Wv     = (const float*)d_in[18];
    const float* Wo     = (const float*)d_in[19];
    const float* lnw    = (const float*)d_in[20];
    const float* lnb    = (const float*)d_in[21];

    // ---- workspace layout (lifetimes aliased; 5 big slots S0..S4) ----
    char* ws = (char*)d_ws;
    const size_t BF = 2 * BTDc;
    size_t o = 0;
    auto take = [&](size_t bytes) { size_t r = o; o += (bytes + 255) & ~(size_t)255; return r; };
    unsigned short* WrT    = (unsigned short*)(ws + take((size_t)Dc * Dc * 2));
    unsigned short* WkT    = (unsigned short*)(ws + take((size_t)Dc * Dc * 2));
    unsigned short* WvT    = (unsigned short*)(ws + take((size_t)Dc * Dc * 2));
    unsigned short* WoT    = (unsigned short*)(ws + take((size_t)Dc * Dc * 2));
    unsigned short* w1T    = (unsigned short*)(ws + take((size_t)160 * Dc * 2));
    unsigned short* w2T    = (unsigned short*)(ws + take((size_t)Dc * 160 * 2));
    unsigned short* tdw1T  = (unsigned short*)(ws + take((size_t)64 * Dc * 2));
    unsigned short* tdw2T  = (unsigned short*)(ws + take((size_t)Dc * 64 * 2));
    unsigned short* tv2w1T = (unsigned short*)(ws + take((size_t)64 * Dc * 2));
    unsigned short* tv2w2T = (unsigned short*)(ws + take((size_t)Dc * 64 * 2));
    take(1 << 18);
    unsigned short* S0     = (unsigned short*)(ws + take(BF));   // XXX -> XR -> YA
    unsigned short* MIXPRE = (unsigned short*)(ws + take((size_t)BTc * 160 * 2));
    unsigned short* S1     = (unsigned short*)(ws + take(BF));   // XK -> Vb -> YLN
    unsigned short* WT     = (unsigned short*)(ws + take((size_t)BTc * 64 * 2));
    unsigned short* T1     = (unsigned short*)(ws + take((size_t)BTc * 64 * 2));
    unsigned short* S2     = (unsigned short*)(ws + take(BF));   // XV -> Rb
    unsigned short* S3     = (unsigned short*)(ws + take(BF));   // XW -> KDb -> V2
    unsigned short* S4     = (unsigned short*)(ws + take(BF));   // DX -> XV2 (in-place)
    float*          Pb     = (float*)(ws + take((size_t)128 * 32 * 4096 * 4));
    float*          ALb    = (float*)(ws + take((size_t)128 * 32 * 64 * 4));

    float* out_f     = (float*)d_out;
    float* shift_out = out_f + BTDc;
    float* wkv_out   = shift_out + (size_t)Bc * Dc;
    float* DEC       = out_f;   // f32 decay in d_out region (dead before final GEMM)
    float* PART      = Pb;      // split-K partials alias Pb

    unsigned short* XXX = S0;
    unsigned short* DX  = S4;
    unsigned short* XR  = S0;
    unsigned short* XK  = S1;
    unsigned short* XV  = S2;
    unsigned short* XW  = S3;
    unsigned short* XV2 = S4;
    unsigned short* KDb = S3;   // after WT gemm (XW dead)
    unsigned short* Vb  = S1;   // after KDb gemm (XK dead)
    unsigned short* Rb  = S2;   // after Vb gemm (XV dead)
    unsigned short* YA  = S0;   // after Rb gemm + wkv (XR dead)
    unsigned short* V2  = S3;   // after wkv (KDb dead)
    unsigned short* YLN = S1;   // after wkv (Vb dead)

    dim3 tb(256);
    {
        T4 t4;
        t4.in[0] = Wr; t4.in[1] = Wk; t4.in[2] = Wv; t4.in[3] = Wo;
        t4.out[0] = WrT; t4.out[1] = WkT; t4.out[2] = WvT; t4.out[3] = WoT;
        transpose_cast4<<<dim3(64, 64, 4), tb, 0, stream>>>(t4);
    }
    {
        TM tm;
        tm.in[0] = w1;    tm.out[0] = w1T;    tm.R[0] = Dc;  tm.C[0] = 160;
        tm.in[1] = w2;    tm.out[1] = w2T;    tm.R[1] = 160; tm.C[1] = Dc;
        tm.in[2] = tdw1;  tm.out[2] = tdw1T;  tm.R[2] = Dc;  tm.C[2] = 64;
        tm.in[3] = tdw2;  tm.out[3] = tdw2T;  tm.R[3] = 64;  tm.C[3] = Dc;
        tm.in[4] = tv2w1; tm.out[4] = tv2w1T; tm.R[4] = Dc;  tm.C[4] = 64;
        tm.in[5] = tv2w2; tm.out[5] = tv2w2T; tm.R[5] = 64;  tm.C[5] = Dc;
        transpose_multi<<<dim3(320, 6), tb, 0, stream>>>(tm);
    }

    prep_xxx<<<BTc, tb, 0, stream>>>(x, shift, tmx, XXX, DX, shift_out);

    EpiP ep{};
    // mixpre = tanh(xxx @ w1)  — split-K (KS=4), partials in PART (=Pb)
    gemm_splitk<<<dim3(2 * 4, 64), tb, 0, stream>>>(XXX, Dc, w1T, Dc, BTc, 160, 4, 512, PART);
    splitk_reduce_tanh<<<(BTc * 160 + 255) / 256, tb, 0, stream>>>(PART, 4, (size_t)BTc * 160, MIXPRE);

    // fused five mix GEMMs
    {
        Mix5P mp;
        mp.vec[0] = tmr; mp.vec[1] = tmk; mp.vec[2] = tmv; mp.vec[3] = tmw; mp.vec[4] = tmv2;
        mp.out[0] = XR;  mp.out[1] = XK;  mp.out[2] = XV;  mp.out[3] = XW;  mp.out[4] = XV2;
        mix5<<<dim3(16, 128), tb, 0, stream>>>(MIXPRE, w2T, x, DX, mp);
    }

    // decay path: WT = tanh(XW @ tdw1T) — split-K (KS=8)
    gemm_splitk<<<dim3(8, 64), tb, 0, stream>>>(XW, Dc, tdw1T, Dc, BTc, 64, 8, 256, PART);
    splitk_reduce_tanh<<<(BTc * 64 + 255) / 256, tb, 0, stream>>>(PART, 8, (size_t)BTc * 64, WT);
    ep = EpiP{}; ep.of = DEC; ep.vec = tdecay;
    launch_gemm(5, WT, 64, tdw2T, 64, BTc, Dc, 64, ep, stream);
    // k*(1-decay): XK -> KDb (S3; XW dead)
    ep = EpiP{}; ep.ob = KDb; ep.a0 = DEC;
    launch_gemm(4, XK, Dc, WkT, Dc, BTc, Dc, Dc, ep, stream);
    // v: XV -> Vb (S1; XK dead)
    ep = EpiP{}; ep.ob = Vb;
    launch_gemm(1, XV, Dc, WvT, Dc, BTc, Dc, Dc, ep, stream);
    // r: XR -> Rb (S2; XV dead)
    ep = EpiP{}; ep.ob = Rb;
    launch_gemm(1, XR, Dc, WrT, Dc, BTc, Dc, Dc, ep, stream);

    // chunked WKV scan (MFMA)
    wkv_summary<<<4096, tb, 0, stream>>>(KDb, Vb, DEC, Pb, ALb);
    wkv_states<<<2048, tb, 0, stream>>>(wkv_in, Pb, ALb, wkv_out);
    wkv_y<<<4096, tb, 0, stream>>>(Rb, KDb, Vb, DEC, Pb, YA);   // YA = S0 (XR dead)

    // v2 path: XV2 (S4) still live
    ep = EpiP{}; ep.ob = V2;                                     // V2 = S3 (KDb dead)
    launch_gemm(1, XV2, Dc, WvT, Dc, BTc, Dc, Dc, ep, stream);
    // T1 = tanh(XV2 @ tv2w1T) — split-K (KS=8), Pb dead after wkv_y
    gemm_splitk<<<dim3(8, 64), tb, 0, stream>>>(XV2, Dc, tv2w1T, Dc, BTc, 64, 8, 256, PART);
    splitk_reduce_tanh<<<(BTc * 64 + 255) / 256, tb, 0, stream>>>(PART, 8, (size_t)BTc * 64, T1);
    ep = EpiP{}; ep.ob = V2; ep.ab = V2;                         // in-place add
    launch_gemm(6, T1, 64, tv2w2T, 64, BTc, Dc, 64, ep, stream);

    // layernorm + output projection
    ln_fuse<<<BTc, tb, 0, stream>>>(YA, V2, lnw, lnb, YLN);      // YLN = S1 (Vb dead)
    ep = EpiP{}; ep.of = out_f;
    launch_gemm(0, YLN, Dc, WoT, Dc, BTc, Dc, Dc, ep, stream);
}